// Round 5
// baseline (837.949 us; speedup 1.0000x reference)
//
#include <hip/hip_runtime.h>
#include <math.h>

#define N_NODES 50000
#define N_EDGES 1600000
#define SCAN_BS 256
#define N_SCAN_BLOCKS ((N_NODES + SCAN_BS - 1) / SCAN_BS)   // 196

// ---------------- node inverse L2 norm (input layer only) ----------------
template<int F, int TPN>
__global__ void norm_kernel(const float* __restrict__ x, float* __restrict__ nrminv) {
    int gid = blockIdx.x * blockDim.x + threadIdx.x;
    int node = gid / TPN;
    int t = gid % TPN;
    if (node >= N_NODES) return;
    const float* row = x + (size_t)node * F;
    float s = 0.f;
    constexpr int CHUNKS = F / (TPN * 4);
    #pragma unroll
    for (int c = 0; c < CHUNKS; c++) {
        float4 v = *(const float4*)(row + c * TPN * 4 + t * 4);
        s += v.x*v.x + v.y*v.y + v.z*v.z + v.w*v.w;
    }
    #pragma unroll
    for (int m = TPN/2; m >= 1; m >>= 1) s += __shfl_xor(s, m);
    if (t == 0) {
        float n = sqrtf(s);
        nrminv[node] = (n == 0.f) ? 1.f : 1.f / n;
    }
}

// =================== CSR-by-dst build (once per call) ===================
__global__ void hist_kernel(const int* __restrict__ dst, int* __restrict__ cnt) {
    int e = blockIdx.x * blockDim.x + threadIdx.x;
    if (e < N_EDGES) atomicAdd(&cnt[dst[e]], 1);
}

__global__ void scan1_kernel(const int* __restrict__ cnt, int* __restrict__ partial,
                             int* __restrict__ blocksum) {
    __shared__ int lds[SCAN_BS];
    int i = blockIdx.x * SCAN_BS + threadIdx.x;
    int v = (i < N_NODES) ? cnt[i] : 0;
    lds[threadIdx.x] = v;
    __syncthreads();
    for (int off = 1; off < SCAN_BS; off <<= 1) {
        int add = (threadIdx.x >= off) ? lds[threadIdx.x - off] : 0;
        __syncthreads();
        lds[threadIdx.x] += add;
        __syncthreads();
    }
    if (i < N_NODES) partial[i] = lds[threadIdx.x] - v;        // exclusive
    if (threadIdx.x == SCAN_BS - 1) blocksum[blockIdx.x] = lds[threadIdx.x];
}

__global__ void scan2_kernel(int* __restrict__ blocksum) {
    __shared__ int lds[SCAN_BS];
    int v = (threadIdx.x < N_SCAN_BLOCKS) ? blocksum[threadIdx.x] : 0;
    lds[threadIdx.x] = v;
    __syncthreads();
    for (int off = 1; off < SCAN_BS; off <<= 1) {
        int add = (threadIdx.x >= off) ? lds[threadIdx.x - off] : 0;
        __syncthreads();
        lds[threadIdx.x] += add;
        __syncthreads();
    }
    if (threadIdx.x < N_SCAN_BLOCKS) blocksum[threadIdx.x] = lds[threadIdx.x] - v;  // exclusive
}

__global__ void scan3_kernel(const int* __restrict__ partial, const int* __restrict__ blocksum,
                             int* __restrict__ row_start, int* __restrict__ cursor) {
    int i = blockIdx.x * blockDim.x + threadIdx.x;
    if (i < N_NODES) {
        int rs = partial[i] + blocksum[i / SCAN_BS];
        row_start[i] = rs;
        cursor[i] = rs;
    }
    if (i == N_NODES) row_start[N_NODES] = N_EDGES;
}

// fill: scatter ONLY src (dst is implicit in CSR row index)
__global__ void fill_kernel(const int* __restrict__ src, const int* __restrict__ dst,
                            int* __restrict__ cursor, int* __restrict__ src_csr) {
    int e = blockIdx.x * blockDim.x + threadIdx.x;
    if (e < N_EDGES) {
        int pos = atomicAdd(&cursor[dst[e]], 1);
        src_csr[pos] = src[e];
    }
}

// ------------- node-major cosine sim: x[dst] register-resident, gather only x[src].
//               TPN lanes/node, VPL=F/TPN floats/lane; 2-edge unroll for MLP. -------------
template<int F, int TPN>
__global__ void sim_node_kernel(const float* __restrict__ x,
                                const float* __restrict__ nrminv,
                                const int* __restrict__ row_start,
                                const int* __restrict__ src_csr,
                                float* __restrict__ w_csr,
                                float* __restrict__ rowsum, float* __restrict__ degcnt) {
    constexpr int VPL = F / TPN;
    int gid = blockIdx.x * blockDim.x + threadIdx.x;
    int node = gid / TPN;
    int t = gid % TPN;
    if (node >= N_NODES) return;
    const float* rowd = x + (size_t)node * F;
    float nd = nrminv[node];
    float xd[VPL];
    #pragma unroll
    for (int k = 0; k < VPL; k++) xd[k] = rowd[t * VPL + k] * nd;   // fold nrminv[d]

    int beg = row_start[node], end = row_start[node + 1];
    int i = beg;
    for (; i + 1 < end; i += 2) {
        int s0 = src_csr[i], s1 = src_csr[i + 1];
        const float* r0 = x + (size_t)s0 * F;
        const float* r1 = x + (size_t)s1 * F;
        float a0 = 0.f, a1 = 0.f;
        #pragma unroll
        for (int k = 0; k < VPL; k++) {
            a0 += xd[k] * r0[t * VPL + k];
            a1 += xd[k] * r1[t * VPL + k];
        }
        #pragma unroll
        for (int m = TPN / 2; m >= 1; m >>= 1) {
            a0 += __shfl_xor(a0, m);
            a1 += __shfl_xor(a1, m);
        }
        if (t == 0) {
            float sim0 = a0 * nrminv[s0];
            float sim1 = a1 * nrminv[s1];
            float w0 = (s0 != node && sim0 >= 0.5f) ? sim0 : 0.f;
            float w1 = (s1 != node && sim1 >= 0.5f) ? sim1 : 0.f;
            w_csr[i] = w0;
            w_csr[i + 1] = w1;
            if (w0 != 0.f) { atomicAdd(&rowsum[s0], w0); atomicAdd(&degcnt[s0], 1.f); }
            if (w1 != 0.f) { atomicAdd(&rowsum[s1], w1); atomicAdd(&degcnt[s1], 1.f); }
        }
    }
    if (i < end) {
        int s0 = src_csr[i];
        const float* r0 = x + (size_t)s0 * F;
        float a0 = 0.f;
        #pragma unroll
        for (int k = 0; k < VPL; k++) a0 += xd[k] * r0[t * VPL + k];
        #pragma unroll
        for (int m = TPN / 2; m >= 1; m >>= 1) a0 += __shfl_xor(a0, m);
        if (t == 0) {
            float sim0 = a0 * nrminv[s0];
            float w0 = (s0 != node && sim0 >= 0.5f) ? sim0 : 0.f;
            w_csr[i] = w0;
            if (w0 != 0.f) { atomicAdd(&rowsum[s0], w0); atomicAdd(&degcnt[s0], 1.f); }
        }
    }
}

// ------------- per node: L1-normalize row weights, dinv, selfw*dinv^2 -------------
template<int TPN>
__global__ void row_finalize_kernel(const int* __restrict__ row_start,
                                    const int* __restrict__ src_csr,
                                    const float* __restrict__ rowsum,
                                    const float* __restrict__ degcnt,
                                    float* __restrict__ w_csr,
                                    float* __restrict__ dinv, float* __restrict__ swd2) {
    int gid = blockIdx.x * blockDim.x + threadIdx.x;
    int node = gid / TPN;
    int t = gid % TPN;
    if (node >= N_NODES) return;
    int beg = row_start[node], end = row_start[node + 1];
    float sum = 0.f;
    for (int i = beg + t; i < end; i += TPN) {
        float w = w_csr[i];
        if (w != 0.f) {
            float wn = w / rowsum[src_csr[i]];   // rowsum >= w > 0 here
            w_csr[i] = wn;
            sum += wn;
        }
    }
    #pragma unroll
    for (int m = TPN/2; m >= 1; m >>= 1) sum += __shfl_xor(sum, m);
    if (t == 0) {
        float sw = 1.f / (degcnt[node] + 1.f);
        float dv = rsqrtf(sw + sum);             // deg2 = selfw + sum > 0 always
        dinv[node] = dv;
        swd2[node] = sw * dv * dv;
    }
}

// ------------- tiled fp32 GEMM: h = x @ W -------------
template<int FIN, int FOUT, int TM, int KC, int RPT, int CPT>
__global__ __launch_bounds__(256) void gemm_tiled(const float* __restrict__ x,
                                                  const float* __restrict__ W,
                                                  float* __restrict__ h) {
    constexpr int COLG = FOUT / CPT;
    static_assert(COLG * (TM / RPT) == 256, "thread mapping");
    __shared__ float xT[KC][TM];
    __shared__ float Wl[KC][FOUT];
    int tid = threadIdx.x;
    int row0 = blockIdx.x * TM;
    int c0 = (tid % COLG) * CPT;
    int r0 = (tid / COLG) * RPT;
    float acc[RPT][CPT];
    #pragma unroll
    for (int r = 0; r < RPT; r++)
        #pragma unroll
        for (int c = 0; c < CPT; c++) acc[r][c] = 0.f;

    for (int kc = 0; kc < FIN; kc += KC) {
        constexpr int SLOTS_PER_ROW = KC / 4;
        constexpr int XQ = TM * KC / (256 * 4);
        #pragma unroll
        for (int j = 0; j < XQ; j++) {
            int idx = tid + j * 256;
            int tr = idx / SLOTS_PER_ROW;
            int tk = (idx % SLOTS_PER_ROW) * 4;
            int grow = row0 + tr;
            float4 v = make_float4(0.f, 0.f, 0.f, 0.f);
            if (grow < N_NODES) v = *(const float4*)(x + (size_t)grow * FIN + kc + tk);
            xT[tk + 0][tr] = v.x; xT[tk + 1][tr] = v.y;
            xT[tk + 2][tr] = v.z; xT[tk + 3][tr] = v.w;
        }
        if constexpr (KC * FOUT >= 1024) {
            constexpr int WQ = KC * FOUT / (256 * 4);
            #pragma unroll
            for (int j = 0; j < WQ; j++) {
                int idx = tid + j * 256;
                int wk = idx / (FOUT / 4);
                int wc = (idx % (FOUT / 4)) * 4;
                *(float4*)&Wl[wk][wc] = *(const float4*)(W + (size_t)(kc + wk) * FOUT + wc);
            }
        } else {
            Wl[tid / FOUT][tid % FOUT] = W[(size_t)(kc + tid / FOUT) * FOUT + tid % FOUT];
        }
        __syncthreads();

        #pragma unroll
        for (int k = 0; k < KC; k++) {
            float a[RPT];
            #pragma unroll
            for (int rr = 0; rr < RPT; rr += 4) {
                float4 xv = *(const float4*)&xT[k][r0 + rr];
                a[rr] = xv.x; a[rr+1] = xv.y; a[rr+2] = xv.z; a[rr+3] = xv.w;
            }
            if constexpr (CPT == 4) {
                float4 wv = *(const float4*)&Wl[k][c0];
                #pragma unroll
                for (int rr = 0; rr < RPT; rr++) {
                    acc[rr][0] += a[rr] * wv.x; acc[rr][1] += a[rr] * wv.y;
                    acc[rr][2] += a[rr] * wv.z; acc[rr][3] += a[rr] * wv.w;
                }
            } else {
                float wv = Wl[k][c0];
                #pragma unroll
                for (int rr = 0; rr < RPT; rr++) acc[rr][0] += a[rr] * wv;
            }
        }
        __syncthreads();
    }

    #pragma unroll
    for (int rr = 0; rr < RPT; rr++) {
        int grow = row0 + r0 + rr;
        if (grow < N_NODES) {
            if constexpr (CPT == 4) {
                float4 o = make_float4(acc[rr][0], acc[rr][1], acc[rr][2], acc[rr][3]);
                *(float4*)(h + (size_t)grow * FOUT + c0) = o;
            } else {
                h[(size_t)grow * FOUT + c0] = acc[rr][0];
            }
        }
    }
}

// ------------- gather conv FOUT=128; dinv[src] folded at metadata load;
//               optionally writes next layer's nrminv -------------
template<bool RELU, bool WNORM>
__global__ void conv_gather128_kernel(const int* __restrict__ row_start,
                                      const int* __restrict__ src_csr,
                                      const float* __restrict__ w_csr,
                                      const float* __restrict__ dinv,
                                      const float* __restrict__ swd2,
                                      const float* __restrict__ h,
                                      const float* __restrict__ b,
                                      float* __restrict__ out,
                                      float* __restrict__ nrminv_out) {
    constexpr int TPN = 32;
    int gid = blockIdx.x * blockDim.x + threadIdx.x;
    int node = gid / TPN;
    int t = gid % TPN;
    if (node >= N_NODES) return;
    int beg = row_start[node], end = row_start[node + 1];
    float dv = dinv[node];
    float4 acc = make_float4(0.f, 0.f, 0.f, 0.f);
    for (int base = beg; base < end; base += TPN) {
        int i = base + t;
        float wv = 0.f; int sv = 0;
        if (i < end) {
            wv = w_csr[i];
            sv = src_csr[i];
            if (wv != 0.f) wv *= dinv[sv];       // fold dinv[src]
        }
        int cnt = end - base; if (cnt > TPN) cnt = TPN;
        #pragma unroll
        for (int j = 0; j < TPN; j++) {
            if (j >= cnt) break;
            float w = __shfl(wv, j, TPN);
            int   s = __shfl(sv, j, TPN);
            if (w != 0.f) {
                float coeff = w * dv;
                float4 hv = *(const float4*)(h + (size_t)s * 128 + t * 4);
                acc.x += coeff * hv.x; acc.y += coeff * hv.y;
                acc.z += coeff * hv.z; acc.w += coeff * hv.w;
            }
        }
    }
    float sd = swd2[node];
    float4 hv = *(const float4*)(h + (size_t)node * 128 + t * 4);
    float4 bv = *(const float4*)(b + t * 4);
    acc.x += sd * hv.x + bv.x; acc.y += sd * hv.y + bv.y;
    acc.z += sd * hv.z + bv.z; acc.w += sd * hv.w + bv.w;
    if (RELU) {
        acc.x = fmaxf(acc.x, 0.f); acc.y = fmaxf(acc.y, 0.f);
        acc.z = fmaxf(acc.z, 0.f); acc.w = fmaxf(acc.w, 0.f);
    }
    *(float4*)(out + (size_t)node * 128 + t * 4) = acc;
    if (WNORM) {
        float ss = acc.x*acc.x + acc.y*acc.y + acc.z*acc.z + acc.w*acc.w;
        #pragma unroll
        for (int m = TPN/2; m >= 1; m >>= 1) ss += __shfl_xor(ss, m);
        if (t == 0) {
            float n = sqrtf(ss);
            nrminv_out[node] = (n == 0.f) ? 1.f : 1.f / n;
        }
    }
}

// ------------- gather conv F=16; same folding/fusion -------------
template<bool BIAS_RELU, bool WNORM>
__global__ void conv_gather16_kernel(const int* __restrict__ row_start,
                                     const int* __restrict__ src_csr,
                                     const float* __restrict__ w_csr,
                                     const float* __restrict__ dinv,
                                     const float* __restrict__ swd2,
                                     const float* __restrict__ h,
                                     const float* __restrict__ b,
                                     float* __restrict__ out,
                                     float* __restrict__ nrminv_out) {
    constexpr int TPN = 16;
    int gid = blockIdx.x * blockDim.x + threadIdx.x;
    int node = gid / TPN;
    int t = gid % TPN;
    if (node >= N_NODES) return;
    int beg = row_start[node], end = row_start[node + 1];
    float dv = dinv[node];
    float acc = 0.f;
    for (int base = beg; base < end; base += TPN) {
        int i = base + t;
        float wv = 0.f; int sv = 0;
        if (i < end) {
            wv = w_csr[i];
            sv = src_csr[i];
            if (wv != 0.f) wv *= dinv[sv];
        }
        int cnt = end - base; if (cnt > TPN) cnt = TPN;
        #pragma unroll
        for (int j = 0; j < TPN; j++) {
            if (j >= cnt) break;
            float w = __shfl(wv, j, TPN);
            int   s = __shfl(sv, j, TPN);
            if (w != 0.f) acc += (w * dv) * h[(size_t)s * 16 + t];
        }
    }
    float v = acc + swd2[node] * h[(size_t)node * 16 + t];
    if (BIAS_RELU) v = fmaxf(v + b[t], 0.f);
    out[(size_t)node * 16 + t] = v;
    if (WNORM) {
        float ss = v * v;
        #pragma unroll
        for (int m = TPN/2; m >= 1; m >>= 1) ss += __shfl_xor(ss, m);
        if (t == 0) {
            float n = sqrtf(ss);
            nrminv_out[node] = (n == 0.f) ? 1.f : 1.f / n;
        }
    }
}

// ------------- fused: out40 = agg16 @ W3 + b3, then log_softmax. One wave/node. -------------
__global__ void final_kernel(const float* __restrict__ agg16,
                             const float* __restrict__ W3, const float* __restrict__ b3,
                             float* __restrict__ out) {
    __shared__ float Wl[16 * 40];
    __shared__ float bl[40];
    for (int i = threadIdx.x; i < 16 * 40; i += blockDim.x) Wl[i] = W3[i];
    if (threadIdx.x < 40) bl[threadIdx.x] = b3[threadIdx.x];
    __syncthreads();
    int wid = threadIdx.x / 64;
    int lane = threadIdx.x % 64;
    int v = blockIdx.x * 4 + wid;
    if (v >= N_NODES) return;
    const float* ar = agg16 + (size_t)v * 16;
    float o = -INFINITY;
    if (lane < 40) {
        o = bl[lane];
        #pragma unroll
        for (int k = 0; k < 16; k++) o += ar[k] * Wl[k * 40 + lane];
    }
    float m = o;
    #pragma unroll
    for (int s = 32; s >= 1; s >>= 1) m = fmaxf(m, __shfl_xor(m, s));
    float ex = (lane < 40) ? expf(o - m) : 0.f;
    float sum = ex;
    #pragma unroll
    for (int s = 32; s >= 1; s >>= 1) sum += __shfl_xor(sum, s);
    float lse = m + logf(sum);
    if (lane < 40) out[(size_t)v * 40 + lane] = o - lse;
}

// =================== host orchestration ===================
extern "C" void kernel_launch(void* const* d_in, const int* in_sizes, int n_in,
                              void* d_out, int out_size, void* d_ws, size_t ws_size,
                              hipStream_t stream) {
    const float* x0 = (const float*)d_in[0];
    const int* ei   = (const int*)d_in[1];
    const int* src  = ei;
    const int* dst  = ei + N_EDGES;
    const float* W1 = (const float*)d_in[2];
    const float* b1 = (const float*)d_in[3];
    const float* W2 = (const float*)d_in[4];
    const float* b2 = (const float*)d_in[5];
    const float* W3 = (const float*)d_in[6];
    const float* b3 = (const float*)d_in[7];
    float* out = (float*)d_out;

    float* ws     = (float*)d_ws;
    float* xbuf1  = ws;                        // 6,400,000 (layer-0 out, 50000x128)
    float* h      = xbuf1 + 6400000;           // 6,400,000 (h scratch; agg16 aliases front)
    float* w_csr  = h + 6400000;               // 1,600,000
    float* xbuf2  = w_csr + 1600000;           // 800,000 (layer-1 out, 50000x16)
    float* nrminv = xbuf2 + 800000;            // 50,000
    float* rowsum = nrminv + 50000;            // 50,000  (rowsum+degcnt = one memset)
    float* degcnt = rowsum + 50000;            // 50,000
    float* dinv   = degcnt + 50000;
    float* swd2   = dinv + 50000;
    int* iws       = (int*)(swd2 + 50000);
    int* row_start = iws;                      // 50,001
    int* cursor    = row_start + 50001;        // 50,000 (doubles as cnt)
    int* partial   = cursor + 50000;           // 50,000
    int* blocksum  = partial + 50000;          // 256
    int* src_csr   = blocksum + 256;           // 1,600,000
    float* agg16   = h;                        // alias (50000x16)

    const int BS = 256;

    // ---- build CSR by dst (reused by all 3 layers) ----
    hipMemsetAsync(cursor, 0, N_NODES * sizeof(int), stream);
    hist_kernel<<<(N_EDGES + BS - 1) / BS, BS, 0, stream>>>(dst, cursor);
    scan1_kernel<<<N_SCAN_BLOCKS, SCAN_BS, 0, stream>>>(cursor, partial, blocksum);
    scan2_kernel<<<1, SCAN_BS, 0, stream>>>(blocksum);
    scan3_kernel<<<(N_NODES + 1 + BS - 1) / BS, BS, 0, stream>>>(partial, blocksum, row_start, cursor);
    fill_kernel<<<(N_EDGES + BS - 1) / BS, BS, 0, stream>>>(src, dst, cursor, src_csr);

    // ================= Layer 0: 128 -> 128, ReLU =================
    hipMemsetAsync(rowsum, 0, 2 * N_NODES * sizeof(float), stream);   // rowsum+degcnt
    norm_kernel<128, 16><<<(N_NODES * 16 + BS - 1) / BS, BS, 0, stream>>>(x0, nrminv);
    sim_node_kernel<128, 32><<<(N_NODES * 32 + BS - 1) / BS, BS, 0, stream>>>(
        x0, nrminv, row_start, src_csr, w_csr, rowsum, degcnt);
    row_finalize_kernel<16><<<(N_NODES * 16 + BS - 1) / BS, BS, 0, stream>>>(
        row_start, src_csr, rowsum, degcnt, w_csr, dinv, swd2);
    gemm_tiled<128, 128, 64, 16, 8, 4><<<(N_NODES + 63) / 64, BS, 0, stream>>>(x0, W1, h);
    conv_gather128_kernel<true, true><<<(N_NODES * 32 + BS - 1) / BS, BS, 0, stream>>>(
        row_start, src_csr, w_csr, dinv, swd2, h, b1, xbuf1, nrminv);

    // ================= Layer 1: 128 -> 16, ReLU =================
    hipMemsetAsync(rowsum, 0, 2 * N_NODES * sizeof(float), stream);
    sim_node_kernel<128, 32><<<(N_NODES * 32 + BS - 1) / BS, BS, 0, stream>>>(
        xbuf1, nrminv, row_start, src_csr, w_csr, rowsum, degcnt);
    row_finalize_kernel<16><<<(N_NODES * 16 + BS - 1) / BS, BS, 0, stream>>>(
        row_start, src_csr, rowsum, degcnt, w_csr, dinv, swd2);
    gemm_tiled<128, 16, 128, 16, 8, 1><<<(N_NODES + 127) / 128, BS, 0, stream>>>(xbuf1, W2, h);
    conv_gather16_kernel<true, true><<<(N_NODES * 16 + BS - 1) / BS, BS, 0, stream>>>(
        row_start, src_csr, w_csr, dinv, swd2, h, b2, xbuf2, nrminv);

    // ========== Layer 2: 16 -> 40 (aggregate in x-space, then fused GEMM+LSM) ==========
    hipMemsetAsync(rowsum, 0, 2 * N_NODES * sizeof(float), stream);
    sim_node_kernel<16, 16><<<(N_NODES * 16 + BS - 1) / BS, BS, 0, stream>>>(
        xbuf2, nrminv, row_start, src_csr, w_csr, rowsum, degcnt);
    row_finalize_kernel<16><<<(N_NODES * 16 + BS - 1) / BS, BS, 0, stream>>>(
        row_start, src_csr, rowsum, degcnt, w_csr, dinv, swd2);
    conv_gather16_kernel<false, false><<<(N_NODES * 16 + BS - 1) / BS, BS, 0, stream>>>(
        row_start, src_csr, w_csr, dinv, swd2, xbuf2, b3 /*unused*/, agg16, nullptr);
    final_kernel<<<(N_NODES + 3) / 4, BS, 0, stream>>>(agg16, W3, b3, out);
}

// Round 7
// 712.746 us; speedup vs baseline: 1.1757x; 1.1757x over previous
//
#include <hip/hip_runtime.h>
#include <math.h>

#define N_NODES 50000
#define N_EDGES 1600000
#define SCAN_BS 256
#define N_SCAN_BLOCKS ((N_NODES + SCAN_BS - 1) / SCAN_BS)   // 196

// ---------- bf16 helpers (high 16 bits of fp32, RNE pack) ----------
__device__ __forceinline__ float bflo(unsigned u) { return __uint_as_float(u << 16); }
__device__ __forceinline__ float bfhi(unsigned u) { return __uint_as_float(u & 0xFFFF0000u); }
__device__ __forceinline__ unsigned short f2bf(float f) {
    unsigned u = __float_as_uint(f);
    u += 0x7FFFu + ((u >> 16) & 1u);          // round-to-nearest-even
    return (unsigned short)(u >> 16);
}

// ---------------- norm + pack normalized bf16 row (F=128) ----------------
// 16 lanes/node, lane t covers elems [t*8, t*8+8)
__global__ void norm_pack_kernel(const float* __restrict__ x, float* __restrict__ nrminv,
                                 uint4* __restrict__ xnb4) {
    int gid = blockIdx.x * blockDim.x + threadIdx.x;
    int node = gid / 16;
    int t = gid % 16;
    if (node >= N_NODES) return;
    const float4* xr = (const float4*)(x + (size_t)node * 128) + t * 2;
    float4 v0 = xr[0], v1 = xr[1];
    float ss = v0.x*v0.x + v0.y*v0.y + v0.z*v0.z + v0.w*v0.w
             + v1.x*v1.x + v1.y*v1.y + v1.z*v1.z + v1.w*v1.w;
    #pragma unroll
    for (int m = 8; m >= 1; m >>= 1) ss += __shfl_xor(ss, m);
    float n = sqrtf(ss);
    float ni = (n == 0.f) ? 1.f : 1.f / n;
    if (t == 0) nrminv[node] = ni;
    uint4 p;
    p.x = (unsigned)f2bf(v0.x * ni) | ((unsigned)f2bf(v0.y * ni) << 16);
    p.y = (unsigned)f2bf(v0.z * ni) | ((unsigned)f2bf(v0.w * ni) << 16);
    p.z = (unsigned)f2bf(v1.x * ni) | ((unsigned)f2bf(v1.y * ni) << 16);
    p.w = (unsigned)f2bf(v1.z * ni) | ((unsigned)f2bf(v1.w * ni) << 16);
    xnb4[(size_t)node * 16 + t] = p;
}

// =================== CSR-by-dst build (once per call) ===================
__global__ void hist_kernel(const int* __restrict__ dst, int* __restrict__ cnt) {
    int e = blockIdx.x * blockDim.x + threadIdx.x;
    if (e < N_EDGES) atomicAdd(&cnt[dst[e]], 1);
}

__global__ void scan1_kernel(const int* __restrict__ cnt, int* __restrict__ partial,
                             int* __restrict__ blocksum) {
    __shared__ int lds[SCAN_BS];
    int i = blockIdx.x * SCAN_BS + threadIdx.x;
    int v = (i < N_NODES) ? cnt[i] : 0;
    lds[threadIdx.x] = v;
    __syncthreads();
    for (int off = 1; off < SCAN_BS; off <<= 1) {
        int add = (threadIdx.x >= off) ? lds[threadIdx.x - off] : 0;
        __syncthreads();
        lds[threadIdx.x] += add;
        __syncthreads();
    }
    if (i < N_NODES) partial[i] = lds[threadIdx.x] - v;        // exclusive
    if (threadIdx.x == SCAN_BS - 1) blocksum[blockIdx.x] = lds[threadIdx.x];
}

__global__ void scan2_kernel(int* __restrict__ blocksum) {
    __shared__ int lds[SCAN_BS];
    int v = (threadIdx.x < N_SCAN_BLOCKS) ? blocksum[threadIdx.x] : 0;
    lds[threadIdx.x] = v;
    __syncthreads();
    for (int off = 1; off < SCAN_BS; off <<= 1) {
        int add = (threadIdx.x >= off) ? lds[threadIdx.x - off] : 0;
        __syncthreads();
        lds[threadIdx.x] += add;
        __syncthreads();
    }
    if (threadIdx.x < N_SCAN_BLOCKS) blocksum[threadIdx.x] = lds[threadIdx.x] - v;  // exclusive
}

__global__ void scan3_kernel(const int* __restrict__ partial, const int* __restrict__ blocksum,
                             int* __restrict__ row_start, int* __restrict__ cursor) {
    int i = blockIdx.x * blockDim.x + threadIdx.x;
    if (i < N_NODES) {
        int rs = partial[i] + blocksum[i / SCAN_BS];
        row_start[i] = rs;
        cursor[i] = rs;
    }
    if (i == N_NODES) row_start[N_NODES] = N_EDGES;
}

__global__ void fill_kernel(const int* __restrict__ src, const int* __restrict__ dst,
                            int* __restrict__ cursor, int* __restrict__ src_csr) {
    int e = blockIdx.x * blockDim.x + threadIdx.x;
    if (e < N_EDGES) {
        int pos = atomicAdd(&cursor[dst[e]], 1);
        __builtin_nontemporal_store(src[e], &src_csr[pos]);
    }
}

// ------------- two-phase sim, F=128: bf16 gathers as FILTER (sim>=0.49 -> exact fp32
//               recompute supplies the weight). bf16-dot err <= 2^-9 << 0.01 margin,
//               so the accepted set == exact fp32 accepted set; weights fully fp32. -------------
__global__ void sim128_kernel(const float* __restrict__ x, const float* __restrict__ nrminv,
                              const uint4* __restrict__ xnb4,
                              const int* __restrict__ row_start, const int* __restrict__ src_csr,
                              float* __restrict__ w_csr,
                              float* __restrict__ rowsum, float* __restrict__ degcnt) {
    int gid = blockIdx.x * blockDim.x + threadIdx.x;
    int node = gid / 16;
    int t = gid % 16;
    if (node >= N_NODES) return;
    float xd[8];
    {
        const float4* xr = (const float4*)(x + (size_t)node * 128) + t * 2;
        float4 v0 = xr[0], v1 = xr[1];
        float nd = nrminv[node];
        xd[0]=v0.x*nd; xd[1]=v0.y*nd; xd[2]=v0.z*nd; xd[3]=v0.w*nd;
        xd[4]=v1.x*nd; xd[5]=v1.y*nd; xd[6]=v1.z*nd; xd[7]=v1.w*nd;
    }
    int beg = row_start[node], end = row_start[node + 1];

    auto dot8 = [&](uint4 a) -> float {
        float r = xd[0]*bflo(a.x) + xd[1]*bfhi(a.x);
        r += xd[2]*bflo(a.y) + xd[3]*bfhi(a.y);
        r += xd[4]*bflo(a.z) + xd[5]*bfhi(a.z);
        r += xd[6]*bflo(a.w) + xd[7]*bfhi(a.w);
        return r;
    };
    auto exact = [&](int s) -> float {          // group-uniform call (a,s uniform after reduce)
        const float4* xs = (const float4*)(x + (size_t)s * 128) + t * 2;
        float4 u0 = xs[0], u1 = xs[1];
        float r = xd[0]*u0.x + xd[1]*u0.y + xd[2]*u0.z + xd[3]*u0.w
                + xd[4]*u1.x + xd[5]*u1.y + xd[6]*u1.z + xd[7]*u1.w;
        #pragma unroll
        for (int m = 8; m >= 1; m >>= 1) r += __shfl_xor(r, m);
        return r * nrminv[s];
    };

    int i = beg;
    for (; i + 1 < end; i += 2) {
        int s0 = src_csr[i], s1 = src_csr[i + 1];
        uint4 a = xnb4[(size_t)s0 * 16 + t];
        uint4 b = xnb4[(size_t)s1 * 16 + t];
        float a0 = dot8(a), a1 = dot8(b);
        #pragma unroll
        for (int m = 8; m >= 1; m >>= 1) { a0 += __shfl_xor(a0, m); a1 += __shfl_xor(a1, m); }
        float w0 = 0.f, w1 = 0.f;
        if (s0 != node && a0 >= 0.49f) { float e0 = exact(s0); if (e0 >= 0.5f) w0 = e0; }
        if (s1 != node && a1 >= 0.49f) { float e1 = exact(s1); if (e1 >= 0.5f) w1 = e1; }
        if (t == 0) {
            w_csr[i] = w0; w_csr[i + 1] = w1;
            if (w0 != 0.f) { atomicAdd(&rowsum[s0], w0); atomicAdd(&degcnt[s0], 1.f); }
            if (w1 != 0.f) { atomicAdd(&rowsum[s1], w1); atomicAdd(&degcnt[s1], 1.f); }
        }
    }
    if (i < end) {
        int s0 = src_csr[i];
        uint4 a = xnb4[(size_t)s0 * 16 + t];
        float a0 = dot8(a);
        #pragma unroll
        for (int m = 8; m >= 1; m >>= 1) a0 += __shfl_xor(a0, m);
        float w0 = 0.f;
        if (s0 != node && a0 >= 0.49f) { float e0 = exact(s0); if (e0 >= 0.5f) w0 = e0; }
        if (t == 0) {
            w_csr[i] = w0;
            if (w0 != 0.f) { atomicAdd(&rowsum[s0], w0); atomicAdd(&degcnt[s0], 1.f); }
        }
    }
}

// ------------- sim F=16 on fp32 pre-normalized rows (exact) -------------
__global__ void sim16_kernel(const float* __restrict__ xn2,
                             const int* __restrict__ row_start, const int* __restrict__ src_csr,
                             float* __restrict__ w_csr,
                             float* __restrict__ rowsum, float* __restrict__ degcnt) {
    int gid = blockIdx.x * blockDim.x + threadIdx.x;
    int node = gid / 16;
    int t = gid % 16;
    if (node >= N_NODES) return;
    float xd = xn2[(size_t)node * 16 + t];
    int beg = row_start[node], end = row_start[node + 1];
    int i = beg;
    for (; i + 1 < end; i += 2) {
        int s0 = src_csr[i], s1 = src_csr[i + 1];
        float a0 = xd * xn2[(size_t)s0 * 16 + t];
        float a1 = xd * xn2[(size_t)s1 * 16 + t];
        #pragma unroll
        for (int m = 8; m >= 1; m >>= 1) { a0 += __shfl_xor(a0, m); a1 += __shfl_xor(a1, m); }
        float w0 = (s0 != node && a0 >= 0.5f) ? a0 : 0.f;
        float w1 = (s1 != node && a1 >= 0.5f) ? a1 : 0.f;
        if (t == 0) {
            w_csr[i] = w0; w_csr[i + 1] = w1;
            if (w0 != 0.f) { atomicAdd(&rowsum[s0], w0); atomicAdd(&degcnt[s0], 1.f); }
            if (w1 != 0.f) { atomicAdd(&rowsum[s1], w1); atomicAdd(&degcnt[s1], 1.f); }
        }
    }
    if (i < end) {
        int s0 = src_csr[i];
        float a0 = xd * xn2[(size_t)s0 * 16 + t];
        #pragma unroll
        for (int m = 8; m >= 1; m >>= 1) a0 += __shfl_xor(a0, m);
        float w0 = (s0 != node && a0 >= 0.5f) ? a0 : 0.f;
        if (t == 0) {
            w_csr[i] = w0;
            if (w0 != 0.f) { atomicAdd(&rowsum[s0], w0); atomicAdd(&degcnt[s0], 1.f); }
        }
    }
}

// ------------- per node: L1-normalize row weights (fp32), dinv, selfw*dinv^2 -------------
__global__ void row_finalize_kernel(const int* __restrict__ row_start,
                                    const int* __restrict__ src_csr,
                                    const float* __restrict__ rowsum,
                                    const float* __restrict__ degcnt,
                                    float* __restrict__ w_csr,
                                    float* __restrict__ dinv, float* __restrict__ swd2) {
    int gid = blockIdx.x * blockDim.x + threadIdx.x;
    int node = gid / 16;
    int t = gid % 16;
    if (node >= N_NODES) return;
    int beg = row_start[node], end = row_start[node + 1];
    float sum = 0.f;
    for (int i = beg + t; i < end; i += 16) {
        float w = w_csr[i];
        if (w != 0.f) {
            float wn = w / rowsum[src_csr[i]];   // rowsum >= w > 0 here
            w_csr[i] = wn;
            sum += wn;
        }
    }
    #pragma unroll
    for (int m = 8; m >= 1; m >>= 1) sum += __shfl_xor(sum, m);
    if (t == 0) {
        float sw = 1.f / (degcnt[node] + 1.f);
        float dv = rsqrtf(sw + sum);             // deg2 = selfw + sum > 0 always
        dinv[node] = dv;
        swd2[node] = sw * dv * dv;
    }
}

// ------------- tiled fp32 GEMM: h = x @ W -------------
template<int FIN, int FOUT, int TM, int KC, int RPT, int CPT>
__global__ __launch_bounds__(256) void gemm_tiled(const float* __restrict__ x,
                                                  const float* __restrict__ W,
                                                  float* __restrict__ h) {
    constexpr int COLG = FOUT / CPT;
    static_assert(COLG * (TM / RPT) == 256, "thread mapping");
    __shared__ float xT[KC][TM];
    __shared__ float Wl[KC][FOUT];
    int tid = threadIdx.x;
    int row0 = blockIdx.x * TM;
    int c0 = (tid % COLG) * CPT;
    int r0 = (tid / COLG) * RPT;
    float acc[RPT][CPT];
    #pragma unroll
    for (int r = 0; r < RPT; r++)
        #pragma unroll
        for (int c = 0; c < CPT; c++) acc[r][c] = 0.f;

    for (int kc = 0; kc < FIN; kc += KC) {
        constexpr int SLOTS_PER_ROW = KC / 4;
        constexpr int XQ = TM * KC / (256 * 4);
        #pragma unroll
        for (int j = 0; j < XQ; j++) {
            int idx = tid + j * 256;
            int tr = idx / SLOTS_PER_ROW;
            int tk = (idx % SLOTS_PER_ROW) * 4;
            int grow = row0 + tr;
            float4 v = make_float4(0.f, 0.f, 0.f, 0.f);
            if (grow < N_NODES) v = *(const float4*)(x + (size_t)grow * FIN + kc + tk);
            xT[tk + 0][tr] = v.x; xT[tk + 1][tr] = v.y;
            xT[tk + 2][tr] = v.z; xT[tk + 3][tr] = v.w;
        }
        if constexpr (KC * FOUT >= 1024) {
            constexpr int WQ = KC * FOUT / (256 * 4);
            #pragma unroll
            for (int j = 0; j < WQ; j++) {
                int idx = tid + j * 256;
                int wk = idx / (FOUT / 4);
                int wc = (idx % (FOUT / 4)) * 4;
                *(float4*)&Wl[wk][wc] = *(const float4*)(W + (size_t)(kc + wk) * FOUT + wc);
            }
        } else {
            Wl[tid / FOUT][tid % FOUT] = W[(size_t)(kc + tid / FOUT) * FOUT + tid % FOUT];
        }
        __syncthreads();

        #pragma unroll
        for (int k = 0; k < KC; k++) {
            float a[RPT];
            #pragma unroll
            for (int rr = 0; rr < RPT; rr += 4) {
                float4 xv = *(const float4*)&xT[k][r0 + rr];
                a[rr] = xv.x; a[rr+1] = xv.y; a[rr+2] = xv.z; a[rr+3] = xv.w;
            }
            if constexpr (CPT == 4) {
                float4 wv = *(const float4*)&Wl[k][c0];
                #pragma unroll
                for (int rr = 0; rr < RPT; rr++) {
                    acc[rr][0] += a[rr] * wv.x; acc[rr][1] += a[rr] * wv.y;
                    acc[rr][2] += a[rr] * wv.z; acc[rr][3] += a[rr] * wv.w;
                }
            } else {
                float wv = Wl[k][c0];
                #pragma unroll
                for (int rr = 0; rr < RPT; rr++) acc[rr][0] += a[rr] * wv;
            }
        }
        __syncthreads();
    }

    #pragma unroll
    for (int rr = 0; rr < RPT; rr++) {
        int grow = row0 + r0 + rr;
        if (grow < N_NODES) {
            if constexpr (CPT == 4) {
                float4 o = make_float4(acc[rr][0], acc[rr][1], acc[rr][2], acc[rr][3]);
                *(float4*)(h + (size_t)grow * FOUT + c0) = o;
            } else {
                h[(size_t)grow * FOUT + c0] = acc[rr][0];
            }
        }
    }
}

// ------------- gather conv FOUT=128 (fp32 w); ReLU+bias fused -------------
__global__ void conv_gather128_kernel(const int* __restrict__ row_start,
                                      const int* __restrict__ src_csr,
                                      const float* __restrict__ w_csr,
                                      const float* __restrict__ dinv,
                                      const float* __restrict__ swd2,
                                      const float* __restrict__ h,
                                      const float* __restrict__ b,
                                      float* __restrict__ out) {
    constexpr int TPN = 32;
    int gid = blockIdx.x * blockDim.x + threadIdx.x;
    int node = gid / TPN;
    int t = gid % TPN;
    if (node >= N_NODES) return;
    int beg = row_start[node], end = row_start[node + 1];
    float dv = dinv[node];
    float4 acc = make_float4(0.f, 0.f, 0.f, 0.f);
    for (int base = beg; base < end; base += TPN) {
        int i = base + t;
        float wv = 0.f; int sv = 0;
        if (i < end) {
            wv = w_csr[i];
            sv = src_csr[i];
            if (wv != 0.f) wv *= dinv[sv];       // fold dinv[src]
        }
        int cnt = end - base; if (cnt > TPN) cnt = TPN;
        #pragma unroll
        for (int j = 0; j < TPN; j++) {
            if (j >= cnt) break;
            float w = __shfl(wv, j, TPN);
            int   s = __shfl(sv, j, TPN);
            if (w != 0.f) {
                float coeff = w * dv;
                float4 hv = *(const float4*)(h + (size_t)s * 128 + t * 4);
                acc.x += coeff * hv.x; acc.y += coeff * hv.y;
                acc.z += coeff * hv.z; acc.w += coeff * hv.w;
            }
        }
    }
    float sd = swd2[node];
    float4 hv = *(const float4*)(h + (size_t)node * 128 + t * 4);
    float4 bv = *(const float4*)(b + t * 4);
    acc.x = fmaxf(acc.x + sd * hv.x + bv.x, 0.f);
    acc.y = fmaxf(acc.y + sd * hv.y + bv.y, 0.f);
    acc.z = fmaxf(acc.z + sd * hv.z + bv.z, 0.f);
    acc.w = fmaxf(acc.w + sd * hv.w + bv.w, 0.f);
    *(float4*)(out + (size_t)node * 128 + t * 4) = acc;
}

// ------------- gather conv F=16 (fp32 w); optional bias/relu + normalized fp32 row out -------------
template<bool BIAS_RELU, bool WNORM>
__global__ void conv_gather16_kernel(const int* __restrict__ row_start,
                                     const int* __restrict__ src_csr,
                                     const float* __restrict__ w_csr,
                                     const float* __restrict__ dinv,
                                     const float* __restrict__ swd2,
                                     const float* __restrict__ h,
                                     const float* __restrict__ b,
                                     float* __restrict__ out,
                                     float* __restrict__ xn_out) {
    constexpr int TPN = 16;
    int gid = blockIdx.x * blockDim.x + threadIdx.x;
    int node = gid / TPN;
    int t = gid % TPN;
    if (node >= N_NODES) return;
    int beg = row_start[node], end = row_start[node + 1];
    float dv = dinv[node];
    float acc = 0.f;
    for (int base = beg; base < end; base += TPN) {
        int i = base + t;
        float wv = 0.f; int sv = 0;
        if (i < end) {
            wv = w_csr[i];
            sv = src_csr[i];
            if (wv != 0.f) wv *= dinv[sv];
        }
        int cnt = end - base; if (cnt > TPN) cnt = TPN;
        #pragma unroll
        for (int j = 0; j < TPN; j++) {
            if (j >= cnt) break;
            float w = __shfl(wv, j, TPN);
            int   s = __shfl(sv, j, TPN);
            if (w != 0.f) acc += (w * dv) * h[(size_t)s * 16 + t];
        }
    }
    float v = acc + swd2[node] * h[(size_t)node * 16 + t];
    if (BIAS_RELU) v = fmaxf(v + b[t], 0.f);
    out[(size_t)node * 16 + t] = v;
    if (WNORM) {
        float ss = v * v;
        #pragma unroll
        for (int m = TPN/2; m >= 1; m >>= 1) ss += __shfl_xor(ss, m);
        float n = sqrtf(ss);
        float ni = (n == 0.f) ? 1.f : 1.f / n;
        xn_out[(size_t)node * 16 + t] = v * ni;
    }
}

// ------------- fused: out40 = agg16 @ W3 + b3, then log_softmax. One wave/node. -------------
__global__ void final_kernel(const float* __restrict__ agg16,
                             const float* __restrict__ W3, const float* __restrict__ b3,
                             float* __restrict__ out) {
    __shared__ float Wl[16 * 40];
    __shared__ float bl[40];
    for (int i = threadIdx.x; i < 16 * 40; i += blockDim.x) Wl[i] = W3[i];
    if (threadIdx.x < 40) bl[threadIdx.x] = b3[threadIdx.x];
    __syncthreads();
    int wid = threadIdx.x / 64;
    int lane = threadIdx.x % 64;
    int v = blockIdx.x * 4 + wid;
    if (v >= N_NODES) return;
    const float* ar = agg16 + (size_t)v * 16;
    float o = -INFINITY;
    if (lane < 40) {
        o = bl[lane];
        #pragma unroll
        for (int k = 0; k < 16; k++) o += ar[k] * Wl[k * 40 + lane];
    }
    float m = o;
    #pragma unroll
    for (int s = 32; s >= 1; s >>= 1) m = fmaxf(m, __shfl_xor(m, s));
    float ex = (lane < 40) ? expf(o - m) : 0.f;
    float sum = ex;
    #pragma unroll
    for (int s = 32; s >= 1; s >>= 1) sum += __shfl_xor(sum, s);
    float lse = m + logf(sum);
    if (lane < 40) out[(size_t)v * 40 + lane] = o - lse;
}

// =================== host orchestration ===================
extern "C" void kernel_launch(void* const* d_in, const int* in_sizes, int n_in,
                              void* d_out, int out_size, void* d_ws, size_t ws_size,
                              hipStream_t stream) {
    const float* x0 = (const float*)d_in[0];
    const int* ei   = (const int*)d_in[1];
    const int* src  = ei;
    const int* dst  = ei + N_EDGES;
    const float* W1 = (const float*)d_in[2];
    const float* b1 = (const float*)d_in[3];
    const float* W2 = (const float*)d_in[4];
    const float* b2 = (const float*)d_in[5];
    const float* W3 = (const float*)d_in[6];
    const float* b3 = (const float*)d_in[7];
    float* out = (float*)d_out;

    // workspace layout: ~16.6M 4B-slots = 66.4 MB
    // xnb (bf16 pack, 3.2M slots), xn2, xbuf2, agg16 all alias inside h with
    // disjoint lifetimes (xnb dies before each gemm writes h; see timeline notes).
    float* ws     = (float*)d_ws;
    float* xbuf1  = ws;                        // 6,400,000
    float* h      = xbuf1 + 6400000;           // 6,400,000
    uint4* xnb4   = (uint4*)h;                 // alias: h[0..3.2M slots) as bf16 rows
    float* agg16  = h;                         // alias: h[0..800K)
    float* xn2    = h + 800000;                // alias: h[800K..1.6M)
    float* xbuf2  = h + 1600000;               // alias: h[1.6M..2.4M)
    float* w_csr  = h + 6400000;               // 1,600,000 (fp32)
    float* nrminv = w_csr + 1600000;           // 50,000
    float* dinv   = nrminv + 50000;            // 50,000
    float* swd2   = dinv + 50000;              // 50,000
    int* zr        = (int*)(swd2 + 50000);     // zero region: cursor + 3x(rowsum,degcnt)
    int* cursor    = zr;                       // 50,000
    float* rs0     = (float*)(zr + 50000);
    float* dc0     = rs0 + 50000;
    float* rs1     = dc0 + 50000;
    float* dc1     = rs1 + 50000;
    float* rs2     = dc1 + 50000;
    float* dc2     = rs2 + 50000;
    int* row_start = (int*)(dc2 + 50000);      // 50,001
    int* partial   = row_start + 50001;        // 50,000
    int* blocksum  = partial + 50000;          // 256
    int* src_csr   = blocksum + 256;           // 1,600,000

    const int BS = 256;

    // ---- one memset zeroes cursor + all rowsum/degcnt pairs ----
    hipMemsetAsync(zr, 0, 350000 * sizeof(int), stream);

    // ---- build CSR by dst (reused by all 3 layers) ----
    hist_kernel<<<(N_EDGES + BS - 1) / BS, BS, 0, stream>>>(dst, cursor);
    scan1_kernel<<<N_SCAN_BLOCKS, SCAN_BS, 0, stream>>>(cursor, partial, blocksum);
    scan2_kernel<<<1, SCAN_BS, 0, stream>>>(blocksum);
    scan3_kernel<<<(N_NODES + 1 + BS - 1) / BS, BS, 0, stream>>>(partial, blocksum, row_start, cursor);
    fill_kernel<<<(N_EDGES + BS - 1) / BS, BS, 0, stream>>>(src, dst, cursor, src_csr);

    // ================= Layer 0: 128 -> 128, ReLU =================
    norm_pack_kernel<<<(N_NODES * 16 + BS - 1) / BS, BS, 0, stream>>>(x0, nrminv, xnb4);
    sim128_kernel<<<(N_NODES * 16 + BS - 1) / BS, BS, 0, stream>>>(
        x0, nrminv, xnb4, row_start, src_csr, w_csr, rs0, dc0);
    row_finalize_kernel<<<(N_NODES * 16 + BS - 1) / BS, BS, 0, stream>>>(
        row_start, src_csr, rs0, dc0, w_csr, dinv, swd2);
    gemm_tiled<128, 128, 64, 16, 8, 4><<<(N_NODES + 63) / 64, BS, 0, stream>>>(x0, W1, h);
    conv_gather128_kernel<<<(N_NODES * 32 + BS - 1) / BS, BS, 0, stream>>>(
        row_start, src_csr, w_csr, dinv, swd2, h, b1, xbuf1);

    // ================= Layer 1: 128 -> 16, ReLU =================
    norm_pack_kernel<<<(N_NODES * 16 + BS - 1) / BS, BS, 0, stream>>>(xbuf1, nrminv, xnb4);
    sim128_kernel<<<(N_NODES * 16 + BS - 1) / BS, BS, 0, stream>>>(
        xbuf1, nrminv, xnb4, row_start, src_csr, w_csr, rs1, dc1);
    row_finalize_kernel<<<(N_NODES * 16 + BS - 1) / BS, BS, 0, stream>>>(
        row_start, src_csr, rs1, dc1, w_csr, dinv, swd2);
    gemm_tiled<128, 16, 128, 16, 8, 1><<<(N_NODES + 127) / 128, BS, 0, stream>>>(xbuf1, W2, h);
    conv_gather16_kernel<true, true><<<(N_NODES * 16 + BS - 1) / BS, BS, 0, stream>>>(
        row_start, src_csr, w_csr, dinv, swd2, h, b2, xbuf2, xn2);

    // ========== Layer 2: 16 -> 40 (aggregate in x-space, then fused GEMM+LSM) ==========
    sim16_kernel<<<(N_NODES * 16 + BS - 1) / BS, BS, 0, stream>>>(
        xn2, row_start, src_csr, w_csr, rs2, dc2);
    row_finalize_kernel<<<(N_NODES * 16 + BS - 1) / BS, BS, 0, stream>>>(
        row_start, src_csr, rs2, dc2, w_csr, dinv, swd2);
    conv_gather16_kernel<false, false><<<(N_NODES * 16 + BS - 1) / BS, BS, 0, stream>>>(
        row_start, src_csr, w_csr, dinv, swd2, xbuf2, b3 /*unused*/, agg16, nullptr);
    final_kernel<<<(N_NODES + 3) / 4, BS, 0, stream>>>(agg16, W3, b3, out);
}

// Round 8
// 633.252 us; speedup vs baseline: 1.3232x; 1.1255x over previous
//
#include <hip/hip_runtime.h>
#include <math.h>

#define N_NODES 50000
#define N_EDGES 1600000
#define SCAN_BS 256
#define N_SCAN_BLOCKS ((N_NODES + SCAN_BS - 1) / SCAN_BS)   // 196
#define NBUCK ((N_NODES + 255) >> 8)                        // 196 buckets of 256 nodes

// ---------- bf16 helpers (high 16 bits of fp32, RNE pack) ----------
__device__ __forceinline__ float bflo(unsigned u) { return __uint_as_float(u << 16); }
__device__ __forceinline__ float bfhi(unsigned u) { return __uint_as_float(u & 0xFFFF0000u); }
__device__ __forceinline__ unsigned short f2bf(float f) {
    unsigned u = __float_as_uint(f);
    u += 0x7FFFu + ((u >> 16) & 1u);          // round-to-nearest-even
    return (unsigned short)(u >> 16);
}

// ---------------- norm + pack normalized bf16 row (F=128) ----------------
__global__ void norm_pack_kernel(const float* __restrict__ x, float* __restrict__ nrminv,
                                 uint4* __restrict__ xnb4) {
    int gid = blockIdx.x * blockDim.x + threadIdx.x;
    int node = gid / 16;
    int t = gid % 16;
    if (node >= N_NODES) return;
    const float4* xr = (const float4*)(x + (size_t)node * 128) + t * 2;
    float4 v0 = xr[0], v1 = xr[1];
    float ss = v0.x*v0.x + v0.y*v0.y + v0.z*v0.z + v0.w*v0.w
             + v1.x*v1.x + v1.y*v1.y + v1.z*v1.z + v1.w*v1.w;
    #pragma unroll
    for (int m = 8; m >= 1; m >>= 1) ss += __shfl_xor(ss, m);
    float n = sqrtf(ss);
    float ni = (n == 0.f) ? 1.f : 1.f / n;
    if (t == 0) nrminv[node] = ni;
    uint4 p;
    p.x = (unsigned)f2bf(v0.x * ni) | ((unsigned)f2bf(v0.y * ni) << 16);
    p.y = (unsigned)f2bf(v0.z * ni) | ((unsigned)f2bf(v0.w * ni) << 16);
    p.z = (unsigned)f2bf(v1.x * ni) | ((unsigned)f2bf(v1.y * ni) << 16);
    p.w = (unsigned)f2bf(v1.z * ni) | ((unsigned)f2bf(v1.w * ni) << 16);
    xnb4[(size_t)node * 16 + t] = p;
}

// =================== CSR-by-dst build (bucketed two-pass) ===================
__global__ void hist_kernel(const int* __restrict__ dst, int* __restrict__ cnt) {
    int e = blockIdx.x * blockDim.x + threadIdx.x;
    if (e < N_EDGES) atomicAdd(&cnt[dst[e]], 1);
}

__global__ void scan1_kernel(const int* __restrict__ cnt, int* __restrict__ partial,
                             int* __restrict__ blocksum) {
    __shared__ int lds[SCAN_BS];
    int i = blockIdx.x * SCAN_BS + threadIdx.x;
    int v = (i < N_NODES) ? cnt[i] : 0;
    lds[threadIdx.x] = v;
    __syncthreads();
    for (int off = 1; off < SCAN_BS; off <<= 1) {
        int add = (threadIdx.x >= off) ? lds[threadIdx.x - off] : 0;
        __syncthreads();
        lds[threadIdx.x] += add;
        __syncthreads();
    }
    if (i < N_NODES) partial[i] = lds[threadIdx.x] - v;        // exclusive
    if (threadIdx.x == SCAN_BS - 1) blocksum[blockIdx.x] = lds[threadIdx.x];
}

__global__ void scan2_kernel(int* __restrict__ blocksum) {
    __shared__ int lds[SCAN_BS];
    int v = (threadIdx.x < N_SCAN_BLOCKS) ? blocksum[threadIdx.x] : 0;
    lds[threadIdx.x] = v;
    __syncthreads();
    for (int off = 1; off < SCAN_BS; off <<= 1) {
        int add = (threadIdx.x >= off) ? lds[threadIdx.x - off] : 0;
        __syncthreads();
        lds[threadIdx.x] += add;
        __syncthreads();
    }
    if (threadIdx.x < N_SCAN_BLOCKS) blocksum[threadIdx.x] = lds[threadIdx.x] - v;  // exclusive
}

// row_start + bucket base cursors (bucket b starts at node b*256)
__global__ void scan3_kernel(const int* __restrict__ partial, const int* __restrict__ blocksum,
                             int* __restrict__ row_start, int* __restrict__ bucket_cursor) {
    int i = blockIdx.x * blockDim.x + threadIdx.x;
    if (i < N_NODES) {
        int rs = partial[i] + blocksum[i / SCAN_BS];
        row_start[i] = rs;
        if ((i & 255) == 0) bucket_cursor[i >> 8] = rs;
    }
    if (i == N_NODES) row_start[N_NODES] = N_EDGES;
}

// pass 1: block-aggregated partition into bucket runs; 4B packed (src | dlocal<<16)
__global__ __launch_bounds__(256) void partition_kernel(const int* __restrict__ src,
                                                        const int* __restrict__ dst,
                                                        int* __restrict__ bucket_cursor,
                                                        unsigned* __restrict__ tmp) {
    __shared__ int cnt[NBUCK];
    __shared__ int base[NBUCK];
    int e0 = blockIdx.x * 8192;
    int eend = e0 + 8192; if (eend > N_EDGES) eend = N_EDGES;
    for (int i = threadIdx.x; i < NBUCK; i += 256) cnt[i] = 0;
    __syncthreads();
    for (int e = e0 + threadIdx.x; e < eend; e += 256)
        atomicAdd(&cnt[dst[e] >> 8], 1);
    __syncthreads();
    for (int i = threadIdx.x; i < NBUCK; i += 256) {
        int c = cnt[i];
        base[i] = (c > 0) ? atomicAdd(&bucket_cursor[i], c) : 0;
    }
    __syncthreads();
    for (int e = e0 + threadIdx.x; e < eend; e += 256) {
        int d = dst[e];
        int b = d >> 8;
        int pos = atomicAdd(&base[b], 1);
        tmp[pos] = (unsigned)src[e] | ((unsigned)(d & 255) << 16);
    }
}

// pass 2: one block per bucket; LDS node cursors; scatter confined to ~32KB span
__global__ __launch_bounds__(256) void fill2_kernel(const unsigned* __restrict__ tmp,
                                                    const int* __restrict__ row_start,
                                                    int* __restrict__ src_csr) {
    __shared__ int cur[256];
    int node0 = blockIdx.x << 8;
    {
        int n = node0 + threadIdx.x;
        if (n > N_NODES) n = N_NODES;
        cur[threadIdx.x] = row_start[n];
    }
    int nend = node0 + 256; if (nend > N_NODES) nend = N_NODES;
    int beg = row_start[node0];
    int end = row_start[nend];
    __syncthreads();
    for (int j = beg + threadIdx.x; j < end; j += 256) {
        unsigned v = tmp[j];
        int dlocal = v >> 16;
        int pos = atomicAdd(&cur[dlocal], 1);
        src_csr[pos] = (int)(v & 0xFFFFu);
    }
}

// ------------- two-phase sim, F=128: bf16 gathers as FILTER; accepted edges
//               recomputed exact fp32 (flip-proof and value-exact) -------------
__global__ void sim128_kernel(const float* __restrict__ x, const float* __restrict__ nrminv,
                              const uint4* __restrict__ xnb4,
                              const int* __restrict__ row_start, const int* __restrict__ src_csr,
                              float* __restrict__ w_csr,
                              float* __restrict__ rowsum, float* __restrict__ degcnt) {
    int gid = blockIdx.x * blockDim.x + threadIdx.x;
    int node = gid / 16;
    int t = gid % 16;
    if (node >= N_NODES) return;
    float xd[8];
    {
        const float4* xr = (const float4*)(x + (size_t)node * 128) + t * 2;
        float4 v0 = xr[0], v1 = xr[1];
        float nd = nrminv[node];
        xd[0]=v0.x*nd; xd[1]=v0.y*nd; xd[2]=v0.z*nd; xd[3]=v0.w*nd;
        xd[4]=v1.x*nd; xd[5]=v1.y*nd; xd[6]=v1.z*nd; xd[7]=v1.w*nd;
    }
    int beg = row_start[node], end = row_start[node + 1];

    auto dot8 = [&](uint4 a) -> float {
        float r = xd[0]*bflo(a.x) + xd[1]*bfhi(a.x);
        r += xd[2]*bflo(a.y) + xd[3]*bfhi(a.y);
        r += xd[4]*bflo(a.z) + xd[5]*bfhi(a.z);
        r += xd[6]*bflo(a.w) + xd[7]*bfhi(a.w);
        return r;
    };
    auto exact = [&](int s) -> float {
        const float4* xs = (const float4*)(x + (size_t)s * 128) + t * 2;
        float4 u0 = xs[0], u1 = xs[1];
        float r = xd[0]*u0.x + xd[1]*u0.y + xd[2]*u0.z + xd[3]*u0.w
                + xd[4]*u1.x + xd[5]*u1.y + xd[6]*u1.z + xd[7]*u1.w;
        #pragma unroll
        for (int m = 8; m >= 1; m >>= 1) r += __shfl_xor(r, m);
        return r * nrminv[s];
    };

    int i = beg;
    for (; i + 1 < end; i += 2) {
        int s0 = src_csr[i], s1 = src_csr[i + 1];
        uint4 a = xnb4[(size_t)s0 * 16 + t];
        uint4 b = xnb4[(size_t)s1 * 16 + t];
        float a0 = dot8(a), a1 = dot8(b);
        #pragma unroll
        for (int m = 8; m >= 1; m >>= 1) { a0 += __shfl_xor(a0, m); a1 += __shfl_xor(a1, m); }
        float w0 = 0.f, w1 = 0.f;
        if (s0 != node && a0 >= 0.49f) { float e0 = exact(s0); if (e0 >= 0.5f) w0 = e0; }
        if (s1 != node && a1 >= 0.49f) { float e1 = exact(s1); if (e1 >= 0.5f) w1 = e1; }
        if (t == 0) {
            w_csr[i] = w0; w_csr[i + 1] = w1;
            if (w0 != 0.f) { atomicAdd(&rowsum[s0], w0); atomicAdd(&degcnt[s0], 1.f); }
            if (w1 != 0.f) { atomicAdd(&rowsum[s1], w1); atomicAdd(&degcnt[s1], 1.f); }
        }
    }
    if (i < end) {
        int s0 = src_csr[i];
        uint4 a = xnb4[(size_t)s0 * 16 + t];
        float a0 = dot8(a);
        #pragma unroll
        for (int m = 8; m >= 1; m >>= 1) a0 += __shfl_xor(a0, m);
        float w0 = 0.f;
        if (s0 != node && a0 >= 0.49f) { float e0 = exact(s0); if (e0 >= 0.5f) w0 = e0; }
        if (t == 0) {
            w_csr[i] = w0;
            if (w0 != 0.f) { atomicAdd(&rowsum[s0], w0); atomicAdd(&degcnt[s0], 1.f); }
        }
    }
}

// ------------- sim F=16 on fp32 pre-normalized rows (exact) -------------
__global__ void sim16_kernel(const float* __restrict__ xn2,
                             const int* __restrict__ row_start, const int* __restrict__ src_csr,
                             float* __restrict__ w_csr,
                             float* __restrict__ rowsum, float* __restrict__ degcnt) {
    int gid = blockIdx.x * blockDim.x + threadIdx.x;
    int node = gid / 16;
    int t = gid % 16;
    if (node >= N_NODES) return;
    float xd = xn2[(size_t)node * 16 + t];
    int beg = row_start[node], end = row_start[node + 1];
    int i = beg;
    for (; i + 1 < end; i += 2) {
        int s0 = src_csr[i], s1 = src_csr[i + 1];
        float a0 = xd * xn2[(size_t)s0 * 16 + t];
        float a1 = xd * xn2[(size_t)s1 * 16 + t];
        #pragma unroll
        for (int m = 8; m >= 1; m >>= 1) { a0 += __shfl_xor(a0, m); a1 += __shfl_xor(a1, m); }
        float w0 = (s0 != node && a0 >= 0.5f) ? a0 : 0.f;
        float w1 = (s1 != node && a1 >= 0.5f) ? a1 : 0.f;
        if (t == 0) {
            w_csr[i] = w0; w_csr[i + 1] = w1;
            if (w0 != 0.f) { atomicAdd(&rowsum[s0], w0); atomicAdd(&degcnt[s0], 1.f); }
            if (w1 != 0.f) { atomicAdd(&rowsum[s1], w1); atomicAdd(&degcnt[s1], 1.f); }
        }
    }
    if (i < end) {
        int s0 = src_csr[i];
        float a0 = xd * xn2[(size_t)s0 * 16 + t];
        #pragma unroll
        for (int m = 8; m >= 1; m >>= 1) a0 += __shfl_xor(a0, m);
        float w0 = (s0 != node && a0 >= 0.5f) ? a0 : 0.f;
        if (t == 0) {
            w_csr[i] = w0;
            if (w0 != 0.f) { atomicAdd(&rowsum[s0], w0); atomicAdd(&degcnt[s0], 1.f); }
        }
    }
}

// ------------- per node: L1-normalize row weights, dinv, selfw*dinv^2 -------------
__global__ void row_finalize_kernel(const int* __restrict__ row_start,
                                    const int* __restrict__ src_csr,
                                    const float* __restrict__ rowsum,
                                    const float* __restrict__ degcnt,
                                    float* __restrict__ w_csr,
                                    float* __restrict__ dinv, float* __restrict__ swd2) {
    int gid = blockIdx.x * blockDim.x + threadIdx.x;
    int node = gid / 16;
    int t = gid % 16;
    if (node >= N_NODES) return;
    int beg = row_start[node], end = row_start[node + 1];
    float sum = 0.f;
    for (int i = beg + t; i < end; i += 16) {
        float w = w_csr[i];
        if (w != 0.f) {
            float wn = w / rowsum[src_csr[i]];   // rowsum >= w > 0 here
            w_csr[i] = wn;
            sum += wn;
        }
    }
    #pragma unroll
    for (int m = 8; m >= 1; m >>= 1) sum += __shfl_xor(sum, m);
    if (t == 0) {
        float sw = 1.f / (degcnt[node] + 1.f);
        float dv = rsqrtf(sw + sum);             // deg2 = selfw + sum > 0 always
        dinv[node] = dv;
        swd2[node] = sw * dv * dv;
    }
}

// ------------- tiled fp32 GEMM: h = x @ W -------------
template<int FIN, int FOUT, int TM, int KC, int RPT, int CPT>
__global__ __launch_bounds__(256) void gemm_tiled(const float* __restrict__ x,
                                                  const float* __restrict__ W,
                                                  float* __restrict__ h) {
    constexpr int COLG = FOUT / CPT;
    static_assert(COLG * (TM / RPT) == 256, "thread mapping");
    __shared__ float xT[KC][TM];
    __shared__ float Wl[KC][FOUT];
    int tid = threadIdx.x;
    int row0 = blockIdx.x * TM;
    int c0 = (tid % COLG) * CPT;
    int r0 = (tid / COLG) * RPT;
    float acc[RPT][CPT];
    #pragma unroll
    for (int r = 0; r < RPT; r++)
        #pragma unroll
        for (int c = 0; c < CPT; c++) acc[r][c] = 0.f;

    for (int kc = 0; kc < FIN; kc += KC) {
        constexpr int SLOTS_PER_ROW = KC / 4;
        constexpr int XQ = TM * KC / (256 * 4);
        #pragma unroll
        for (int j = 0; j < XQ; j++) {
            int idx = tid + j * 256;
            int tr = idx / SLOTS_PER_ROW;
            int tk = (idx % SLOTS_PER_ROW) * 4;
            int grow = row0 + tr;
            float4 v = make_float4(0.f, 0.f, 0.f, 0.f);
            if (grow < N_NODES) v = *(const float4*)(x + (size_t)grow * FIN + kc + tk);
            xT[tk + 0][tr] = v.x; xT[tk + 1][tr] = v.y;
            xT[tk + 2][tr] = v.z; xT[tk + 3][tr] = v.w;
        }
        if constexpr (KC * FOUT >= 1024) {
            constexpr int WQ = KC * FOUT / (256 * 4);
            #pragma unroll
            for (int j = 0; j < WQ; j++) {
                int idx = tid + j * 256;
                int wk = idx / (FOUT / 4);
                int wc = (idx % (FOUT / 4)) * 4;
                *(float4*)&Wl[wk][wc] = *(const float4*)(W + (size_t)(kc + wk) * FOUT + wc);
            }
        } else {
            Wl[tid / FOUT][tid % FOUT] = W[(size_t)(kc + tid / FOUT) * FOUT + tid % FOUT];
        }
        __syncthreads();

        #pragma unroll
        for (int k = 0; k < KC; k++) {
            float a[RPT];
            #pragma unroll
            for (int rr = 0; rr < RPT; rr += 4) {
                float4 xv = *(const float4*)&xT[k][r0 + rr];
                a[rr] = xv.x; a[rr+1] = xv.y; a[rr+2] = xv.z; a[rr+3] = xv.w;
            }
            if constexpr (CPT == 4) {
                float4 wv = *(const float4*)&Wl[k][c0];
                #pragma unroll
                for (int rr = 0; rr < RPT; rr++) {
                    acc[rr][0] += a[rr] * wv.x; acc[rr][1] += a[rr] * wv.y;
                    acc[rr][2] += a[rr] * wv.z; acc[rr][3] += a[rr] * wv.w;
                }
            } else {
                float wv = Wl[k][c0];
                #pragma unroll
                for (int rr = 0; rr < RPT; rr++) acc[rr][0] += a[rr] * wv;
            }
        }
        __syncthreads();
    }

    #pragma unroll
    for (int rr = 0; rr < RPT; rr++) {
        int grow = row0 + r0 + rr;
        if (grow < N_NODES) {
            if constexpr (CPT == 4) {
                float4 o = make_float4(acc[rr][0], acc[rr][1], acc[rr][2], acc[rr][3]);
                *(float4*)(h + (size_t)grow * FOUT + c0) = o;
            } else {
                h[(size_t)grow * FOUT + c0] = acc[rr][0];
            }
        }
    }
}

// ------------- gather conv FOUT=128 (fp32 w); ReLU+bias fused -------------
__global__ void conv_gather128_kernel(const int* __restrict__ row_start,
                                      const int* __restrict__ src_csr,
                                      const float* __restrict__ w_csr,
                                      const float* __restrict__ dinv,
                                      const float* __restrict__ swd2,
                                      const float* __restrict__ h,
                                      const float* __restrict__ b,
                                      float* __restrict__ out) {
    constexpr int TPN = 32;
    int gid = blockIdx.x * blockDim.x + threadIdx.x;
    int node = gid / TPN;
    int t = gid % TPN;
    if (node >= N_NODES) return;
    int beg = row_start[node], end = row_start[node + 1];
    float dv = dinv[node];
    float4 acc = make_float4(0.f, 0.f, 0.f, 0.f);
    for (int base = beg; base < end; base += TPN) {
        int i = base + t;
        float wv = 0.f; int sv = 0;
        if (i < end) {
            wv = w_csr[i];
            sv = src_csr[i];
            if (wv != 0.f) wv *= dinv[sv];       // fold dinv[src]
        }
        int cnt = end - base; if (cnt > TPN) cnt = TPN;
        #pragma unroll
        for (int j = 0; j < TPN; j++) {
            if (j >= cnt) break;
            float w = __shfl(wv, j, TPN);
            int   s = __shfl(sv, j, TPN);
            if (w != 0.f) {
                float coeff = w * dv;
                float4 hv = *(const float4*)(h + (size_t)s * 128 + t * 4);
                acc.x += coeff * hv.x; acc.y += coeff * hv.y;
                acc.z += coeff * hv.z; acc.w += coeff * hv.w;
            }
        }
    }
    float sd = swd2[node];
    float4 hv = *(const float4*)(h + (size_t)node * 128 + t * 4);
    float4 bv = *(const float4*)(b + t * 4);
    acc.x = fmaxf(acc.x + sd * hv.x + bv.x, 0.f);
    acc.y = fmaxf(acc.y + sd * hv.y + bv.y, 0.f);
    acc.z = fmaxf(acc.z + sd * hv.z + bv.z, 0.f);
    acc.w = fmaxf(acc.w + sd * hv.w + bv.w, 0.f);
    *(float4*)(out + (size_t)node * 128 + t * 4) = acc;
}

// ------------- gather conv F=16 (fp32 w); optional bias/relu + normalized fp32 row out -------------
template<bool BIAS_RELU, bool WNORM>
__global__ void conv_gather16_kernel(const int* __restrict__ row_start,
                                     const int* __restrict__ src_csr,
                                     const float* __restrict__ w_csr,
                                     const float* __restrict__ dinv,
                                     const float* __restrict__ swd2,
                                     const float* __restrict__ h,
                                     const float* __restrict__ b,
                                     float* __restrict__ out,
                                     float* __restrict__ xn_out) {
    constexpr int TPN = 16;
    int gid = blockIdx.x * blockDim.x + threadIdx.x;
    int node = gid / TPN;
    int t = gid % TPN;
    if (node >= N_NODES) return;
    int beg = row_start[node], end = row_start[node + 1];
    float dv = dinv[node];
    float acc = 0.f;
    for (int base = beg; base < end; base += TPN) {
        int i = base + t;
        float wv = 0.f; int sv = 0;
        if (i < end) {
            wv = w_csr[i];
            sv = src_csr[i];
            if (wv != 0.f) wv *= dinv[sv];
        }
        int cnt = end - base; if (cnt > TPN) cnt = TPN;
        #pragma unroll
        for (int j = 0; j < TPN; j++) {
            if (j >= cnt) break;
            float w = __shfl(wv, j, TPN);
            int   s = __shfl(sv, j, TPN);
            if (w != 0.f) acc += (w * dv) * h[(size_t)s * 16 + t];
        }
    }
    float v = acc + swd2[node] * h[(size_t)node * 16 + t];
    if (BIAS_RELU) v = fmaxf(v + b[t], 0.f);
    out[(size_t)node * 16 + t] = v;
    if (WNORM) {
        float ss = v * v;
        #pragma unroll
        for (int m = TPN/2; m >= 1; m >>= 1) ss += __shfl_xor(ss, m);
        float n = sqrtf(ss);
        float ni = (n == 0.f) ? 1.f : 1.f / n;
        xn_out[(size_t)node * 16 + t] = v * ni;
    }
}

// ------------- fused: out40 = agg16 @ W3 + b3, then log_softmax. One wave/node. -------------
__global__ void final_kernel(const float* __restrict__ agg16,
                             const float* __restrict__ W3, const float* __restrict__ b3,
                             float* __restrict__ out) {
    __shared__ float Wl[16 * 40];
    __shared__ float bl[40];
    for (int i = threadIdx.x; i < 16 * 40; i += blockDim.x) Wl[i] = W3[i];
    if (threadIdx.x < 40) bl[threadIdx.x] = b3[threadIdx.x];
    __syncthreads();
    int wid = threadIdx.x / 64;
    int lane = threadIdx.x % 64;
    int v = blockIdx.x * 4 + wid;
    if (v >= N_NODES) return;
    const float* ar = agg16 + (size_t)v * 16;
    float o = -INFINITY;
    if (lane < 40) {
        o = bl[lane];
        #pragma unroll
        for (int k = 0; k < 16; k++) o += ar[k] * Wl[k * 40 + lane];
    }
    float m = o;
    #pragma unroll
    for (int s = 32; s >= 1; s >>= 1) m = fmaxf(m, __shfl_xor(m, s));
    float ex = (lane < 40) ? expf(o - m) : 0.f;
    float sum = ex;
    #pragma unroll
    for (int s = 32; s >= 1; s >>= 1) sum += __shfl_xor(sum, s);
    float lse = m + logf(sum);
    if (lane < 40) out[(size_t)v * 40 + lane] = o - lse;
}

// =================== host orchestration ===================
extern "C" void kernel_launch(void* const* d_in, const int* in_sizes, int n_in,
                              void* d_out, int out_size, void* d_ws, size_t ws_size,
                              hipStream_t stream) {
    const float* x0 = (const float*)d_in[0];
    const int* ei   = (const int*)d_in[1];
    const int* src  = ei;
    const int* dst  = ei + N_EDGES;
    const float* W1 = (const float*)d_in[2];
    const float* b1 = (const float*)d_in[3];
    const float* W2 = (const float*)d_in[4];
    const float* b2 = (const float*)d_in[5];
    const float* W3 = (const float*)d_in[6];
    const float* b3 = (const float*)d_in[7];
    float* out = (float*)d_out;

    // workspace ~66.4 MB. Aliases (disjoint lifetimes):
    //   tmp (partition output, 1.6M u32) aliases xbuf1 (first written by conv128, layer 0 end)
    //   xnb4/agg16/xn2/xbuf2 alias inside h (xnb dies before each gemm writes h)
    float* ws     = (float*)d_ws;
    float* xbuf1  = ws;                        // 6,400,000
    unsigned* tmp = (unsigned*)xbuf1;          // alias: 1,600,000 u32, CSR-build only
    float* h      = xbuf1 + 6400000;           // 6,400,000
    uint4* xnb4   = (uint4*)h;                 // alias
    float* agg16  = h;                         // alias
    float* xn2    = h + 800000;                // alias
    float* xbuf2  = h + 1600000;               // alias
    float* w_csr  = h + 6400000;               // 1,600,000 (fp32)
    float* nrminv = w_csr + 1600000;           // 50,000
    float* dinv   = nrminv + 50000;            // 50,000
    float* swd2   = dinv + 50000;              // 50,000
    int* zr        = (int*)(swd2 + 50000);     // zero region: cnt + 3x(rowsum,degcnt)
    int* cnt       = zr;                       // 50,000
    float* rs0     = (float*)(zr + 50000);
    float* dc0     = rs0 + 50000;
    float* rs1     = dc0 + 50000;
    float* dc1     = rs1 + 50000;
    float* rs2     = dc1 + 50000;
    float* dc2     = rs2 + 50000;
    int* row_start = (int*)(dc2 + 50000);      // 50,001
    int* partial   = row_start + 50001;        // 50,000
    int* blocksum  = partial + 50000;          // 256
    int* bucket_cursor = blocksum + 256;       // 196
    int* src_csr   = bucket_cursor + 256;      // 1,600,000

    const int BS = 256;

    // ---- one memset zeroes cnt + all rowsum/degcnt pairs ----
    hipMemsetAsync(zr, 0, 350000 * sizeof(int), stream);

    // ---- build CSR by dst: hist -> scan -> bucketed two-pass fill ----
    hist_kernel<<<(N_EDGES + BS - 1) / BS, BS, 0, stream>>>(dst, cnt);
    scan1_kernel<<<N_SCAN_BLOCKS, SCAN_BS, 0, stream>>>(cnt, partial, blocksum);
    scan2_kernel<<<1, SCAN_BS, 0, stream>>>(blocksum);
    scan3_kernel<<<(N_NODES + 1 + BS - 1) / BS, BS, 0, stream>>>(partial, blocksum,
                                                                 row_start, bucket_cursor);
    partition_kernel<<<(N_EDGES + 8191) / 8192, BS, 0, stream>>>(src, dst, bucket_cursor, tmp);
    fill2_kernel<<<NBUCK, BS, 0, stream>>>(tmp, row_start, src_csr);

    // ================= Layer 0: 128 -> 128, ReLU =================
    norm_pack_kernel<<<(N_NODES * 16 + BS - 1) / BS, BS, 0, stream>>>(x0, nrminv, xnb4);
    sim128_kernel<<<(N_NODES * 16 + BS - 1) / BS, BS, 0, stream>>>(
        x0, nrminv, xnb4, row_start, src_csr, w_csr, rs0, dc0);
    row_finalize_kernel<<<(N_NODES * 16 + BS - 1) / BS, BS, 0, stream>>>(
        row_start, src_csr, rs0, dc0, w_csr, dinv, swd2);
    gemm_tiled<128, 128, 64, 16, 8, 4><<<(N_NODES + 63) / 64, BS, 0, stream>>>(x0, W1, h);
    conv_gather128_kernel<<<(N_NODES * 32 + BS - 1) / BS, BS, 0, stream>>>(
        row_start, src_csr, w_csr, dinv, swd2, h, b1, xbuf1);

    // ================= Layer 1: 128 -> 16, ReLU =================
    norm_pack_kernel<<<(N_NODES * 16 + BS - 1) / BS, BS, 0, stream>>>(xbuf1, nrminv, xnb4);
    sim128_kernel<<<(N_NODES * 16 + BS - 1) / BS, BS, 0, stream>>>(
        xbuf1, nrminv, xnb4, row_start, src_csr, w_csr, rs1, dc1);
    row_finalize_kernel<<<(N_NODES * 16 + BS - 1) / BS, BS, 0, stream>>>(
        row_start, src_csr, rs1, dc1, w_csr, dinv, swd2);
    gemm_tiled<128, 16, 128, 16, 8, 1><<<(N_NODES + 127) / 128, BS, 0, stream>>>(xbuf1, W2, h);
    conv_gather16_kernel<true, true><<<(N_NODES * 16 + BS - 1) / BS, BS, 0, stream>>>(
        row_start, src_csr, w_csr, dinv, swd2, h, b2, xbuf2, xn2);

    // ========== Layer 2: 16 -> 40 (aggregate in x-space, then fused GEMM+LSM) ==========
    sim16_kernel<<<(N_NODES * 16 + BS - 1) / BS, BS, 0, stream>>>(
        xn2, row_start, src_csr, w_csr, rs2, dc2);
    row_finalize_kernel<<<(N_NODES * 16 + BS - 1) / BS, BS, 0, stream>>>(
        row_start, src_csr, rs2, dc2, w_csr, dinv, swd2);
    conv_gather16_kernel<false, false><<<(N_NODES * 16 + BS - 1) / BS, BS, 0, stream>>>(
        row_start, src_csr, w_csr, dinv, swd2, xbuf2, b3 /*unused*/, agg16, nullptr);
    final_kernel<<<(N_NODES + 3) / 4, BS, 0, stream>>>(agg16, W3, b3, out);
}

// Round 9
// 569.225 us; speedup vs baseline: 1.4721x; 1.1125x over previous
//
#include <hip/hip_runtime.h>
#include <math.h>

#define N_NODES 50000
#define N_EDGES 1600000
#define NBUCK ((N_NODES + 255) >> 8)   // 196 buckets of 256 nodes

// ---------- bf16 helpers (high 16 bits of fp32, RNE pack) ----------
__device__ __forceinline__ float bflo(unsigned u) { return __uint_as_float(u << 16); }
__device__ __forceinline__ float bfhi(unsigned u) { return __uint_as_float(u & 0xFFFF0000u); }
__device__ __forceinline__ unsigned short f2bf(float f) {
    unsigned u = __float_as_uint(f);
    u += 0x7FFFu + ((u >> 16) & 1u);          // round-to-nearest-even
    return (unsigned short)(u >> 16);
}

// ---------------- norm + pack normalized bf16 row (F=128) ----------------
__global__ void norm_pack_kernel(const float* __restrict__ x, float* __restrict__ nrminv,
                                 uint4* __restrict__ xnb4) {
    int gid = blockIdx.x * blockDim.x + threadIdx.x;
    int node = gid / 16;
    int t = gid % 16;
    if (node >= N_NODES) return;
    const float4* xr = (const float4*)(x + (size_t)node * 128) + t * 2;
    float4 v0 = xr[0], v1 = xr[1];
    float ss = v0.x*v0.x + v0.y*v0.y + v0.z*v0.z + v0.w*v0.w
             + v1.x*v1.x + v1.y*v1.y + v1.z*v1.z + v1.w*v1.w;
    #pragma unroll
    for (int m = 8; m >= 1; m >>= 1) ss += __shfl_xor(ss, m);
    float n = sqrtf(ss);
    float ni = (n == 0.f) ? 1.f : 1.f / n;
    if (t == 0) nrminv[node] = ni;
    uint4 p;
    p.x = (unsigned)f2bf(v0.x * ni) | ((unsigned)f2bf(v0.y * ni) << 16);
    p.y = (unsigned)f2bf(v0.z * ni) | ((unsigned)f2bf(v0.w * ni) << 16);
    p.z = (unsigned)f2bf(v1.x * ni) | ((unsigned)f2bf(v1.y * ni) << 16);
    p.w = (unsigned)f2bf(v1.z * ni) | ((unsigned)f2bf(v1.w * ni) << 16);
    xnb4[(size_t)node * 16 + t] = p;
}

// =================== CSR build, both directions, bucket radix (no per-node global atomics) ===================
// pass 1: per-block LDS bucket histograms -> global bucket counts
__global__ __launch_bounds__(256) void bucket_count_kernel(const int* __restrict__ src,
                                                           const int* __restrict__ dst,
                                                           int* __restrict__ bcnt_s,
                                                           int* __restrict__ bcnt_d) {
    __shared__ int cs[NBUCK], cd[NBUCK];
    int e0 = blockIdx.x * 8192;
    int eend = e0 + 8192; if (eend > N_EDGES) eend = N_EDGES;
    for (int i = threadIdx.x; i < NBUCK; i += 256) { cs[i] = 0; cd[i] = 0; }
    __syncthreads();
    for (int e = e0 + threadIdx.x; e < eend; e += 256) {
        atomicAdd(&cs[src[e] >> 8], 1);
        atomicAdd(&cd[dst[e] >> 8], 1);
    }
    __syncthreads();
    for (int i = threadIdx.x; i < NBUCK; i += 256) {
        if (cs[i]) atomicAdd(&bcnt_s[i], cs[i]);
        if (cd[i]) atomicAdd(&bcnt_d[i], cd[i]);
    }
}

// pass 2: scan bucket counts (one block); write bases + cursors + sentinels
__global__ void bucket_scan_kernel(const int* __restrict__ bcnt_s, const int* __restrict__ bcnt_d,
                                   int* __restrict__ bbase_s, int* __restrict__ bbase_d,
                                   int* __restrict__ bcur_s, int* __restrict__ bcur_d,
                                   int* __restrict__ row_start_s, int* __restrict__ row_start_d) {
    __shared__ int lds[256];
    int v = (threadIdx.x < NBUCK) ? bcnt_s[threadIdx.x] : 0;
    lds[threadIdx.x] = v;
    __syncthreads();
    for (int off = 1; off < 256; off <<= 1) {
        int add = (threadIdx.x >= off) ? lds[threadIdx.x - off] : 0;
        __syncthreads();
        lds[threadIdx.x] += add;
        __syncthreads();
    }
    if (threadIdx.x < NBUCK) {
        int e = lds[threadIdx.x] - v;
        bbase_s[threadIdx.x] = e; bcur_s[threadIdx.x] = e;
    }
    if (threadIdx.x == 0) { bbase_s[NBUCK] = N_EDGES; row_start_s[N_NODES] = N_EDGES; }
    __syncthreads();
    int v2 = (threadIdx.x < NBUCK) ? bcnt_d[threadIdx.x] : 0;
    lds[threadIdx.x] = v2;
    __syncthreads();
    for (int off = 1; off < 256; off <<= 1) {
        int add = (threadIdx.x >= off) ? lds[threadIdx.x - off] : 0;
        __syncthreads();
        lds[threadIdx.x] += add;
        __syncthreads();
    }
    if (threadIdx.x < NBUCK) {
        int e = lds[threadIdx.x] - v2;
        bbase_d[threadIdx.x] = e; bcur_d[threadIdx.x] = e;
    }
    if (threadIdx.x == 0) { bbase_d[NBUCK] = N_EDGES; row_start_d[N_NODES] = N_EDGES; }
}

// pass 3: partition edges into bucket runs, both directions, packed (payload16 | klocal<<16)
__global__ __launch_bounds__(256) void partition2_kernel(const int* __restrict__ src,
                                                         const int* __restrict__ dst,
                                                         int* __restrict__ bcur_s,
                                                         int* __restrict__ bcur_d,
                                                         unsigned* __restrict__ tmp_s,
                                                         unsigned* __restrict__ tmp_d) {
    __shared__ int cs[NBUCK], cd[NBUCK], bs[NBUCK], bd[NBUCK];
    int e0 = blockIdx.x * 8192;
    int eend = e0 + 8192; if (eend > N_EDGES) eend = N_EDGES;
    for (int i = threadIdx.x; i < NBUCK; i += 256) { cs[i] = 0; cd[i] = 0; }
    __syncthreads();
    for (int e = e0 + threadIdx.x; e < eend; e += 256) {
        atomicAdd(&cs[src[e] >> 8], 1);
        atomicAdd(&cd[dst[e] >> 8], 1);
    }
    __syncthreads();
    for (int i = threadIdx.x; i < NBUCK; i += 256) {
        int c = cs[i]; bs[i] = c ? atomicAdd(&bcur_s[i], c) : 0;
        c = cd[i];     bd[i] = c ? atomicAdd(&bcur_d[i], c) : 0;
    }
    __syncthreads();
    for (int e = e0 + threadIdx.x; e < eend; e += 256) {
        int s = src[e], d = dst[e];
        int ps = atomicAdd(&bs[s >> 8], 1);
        tmp_s[ps] = (unsigned)d | ((unsigned)(s & 255) << 16);
        int pd = atomicAdd(&bd[d >> 8], 1);
        tmp_d[pd] = (unsigned)s | ((unsigned)(d & 255) << 16);
    }
}

// pass 4: per bucket: LDS count+scan -> row_start; scatter payload within bucket span
__global__ __launch_bounds__(256) void csr_finalize_kernel(const unsigned* __restrict__ tmp,
                                                           const int* __restrict__ bbase,
                                                           int* __restrict__ row_start,
                                                           int* __restrict__ csr_out) {
    __shared__ int cnt[256];
    __shared__ int cur[256];
    int b = blockIdx.x;
    int beg = bbase[b], end = bbase[b + 1];
    cnt[threadIdx.x] = 0;
    __syncthreads();
    for (int j = beg + threadIdx.x; j < end; j += 256)
        atomicAdd(&cnt[tmp[j] >> 16], 1);
    __syncthreads();
    int v = cnt[threadIdx.x];
    cur[threadIdx.x] = v;
    __syncthreads();
    for (int off = 1; off < 256; off <<= 1) {
        int add = (threadIdx.x >= off) ? cur[threadIdx.x - off] : 0;
        __syncthreads();
        cur[threadIdx.x] += add;
        __syncthreads();
    }
    int excl = cur[threadIdx.x] - v;
    int node = (b << 8) + threadIdx.x;
    if (node < N_NODES) row_start[node] = beg + excl;
    __syncthreads();
    cur[threadIdx.x] = beg + excl;
    __syncthreads();
    for (int j = beg + threadIdx.x; j < end; j += 256) {
        unsigned t = tmp[j];
        int pos = atomicAdd(&cur[t >> 16], 1);
        csr_out[pos] = (int)(t & 0xFFFFu);
    }
}

// ------------- two-phase sim, F=128, dst-major: bf16 filter + exact fp32 on accepts.
//               4-edge unroll for MLP. Atomics OK: layers 0/1 have very few accepts. -------------
__global__ void sim128_kernel(const float* __restrict__ x, const float* __restrict__ nrminv,
                              const uint4* __restrict__ xnb4,
                              const int* __restrict__ row_start, const int* __restrict__ src_csr,
                              float* __restrict__ w_csr,
                              float* __restrict__ rowsum, float* __restrict__ degcnt) {
    int gid = blockIdx.x * blockDim.x + threadIdx.x;
    int node = gid / 16;
    int t = gid % 16;
    if (node >= N_NODES) return;
    float xd[8];
    {
        const float4* xr = (const float4*)(x + (size_t)node * 128) + t * 2;
        float4 v0 = xr[0], v1 = xr[1];
        float nd = nrminv[node];
        xd[0]=v0.x*nd; xd[1]=v0.y*nd; xd[2]=v0.z*nd; xd[3]=v0.w*nd;
        xd[4]=v1.x*nd; xd[5]=v1.y*nd; xd[6]=v1.z*nd; xd[7]=v1.w*nd;
    }
    int beg = row_start[node], end = row_start[node + 1];

    auto dot8 = [&](uint4 a) -> float {
        float r = xd[0]*bflo(a.x) + xd[1]*bfhi(a.x);
        r += xd[2]*bflo(a.y) + xd[3]*bfhi(a.y);
        r += xd[4]*bflo(a.z) + xd[5]*bfhi(a.z);
        r += xd[6]*bflo(a.w) + xd[7]*bfhi(a.w);
        return r;
    };
    auto exact = [&](int s) -> float {
        const float4* xs = (const float4*)(x + (size_t)s * 128) + t * 2;
        float4 u0 = xs[0], u1 = xs[1];
        float r = xd[0]*u0.x + xd[1]*u0.y + xd[2]*u0.z + xd[3]*u0.w
                + xd[4]*u1.x + xd[5]*u1.y + xd[6]*u1.z + xd[7]*u1.w;
        #pragma unroll
        for (int m = 8; m >= 1; m >>= 1) r += __shfl_xor(r, m);
        return r * nrminv[s];
    };

    int i = beg;
    for (; i + 3 < end; i += 4) {
        int ss[4]; uint4 aa[4]; float ac[4];
        #pragma unroll
        for (int k = 0; k < 4; k++) ss[k] = src_csr[i + k];
        #pragma unroll
        for (int k = 0; k < 4; k++) aa[k] = xnb4[(size_t)ss[k] * 16 + t];
        #pragma unroll
        for (int k = 0; k < 4; k++) ac[k] = dot8(aa[k]);
        #pragma unroll
        for (int m = 8; m >= 1; m >>= 1) {
            ac[0] += __shfl_xor(ac[0], m); ac[1] += __shfl_xor(ac[1], m);
            ac[2] += __shfl_xor(ac[2], m); ac[3] += __shfl_xor(ac[3], m);
        }
        float w[4];
        #pragma unroll
        for (int k = 0; k < 4; k++) {
            w[k] = 0.f;
            if (ss[k] != node && ac[k] >= 0.49f) {
                float e = exact(ss[k]);
                if (e >= 0.5f) w[k] = e;
            }
        }
        if (t == 0) {
            #pragma unroll
            for (int k = 0; k < 4; k++) {
                w_csr[i + k] = w[k];
                if (w[k] != 0.f) { atomicAdd(&rowsum[ss[k]], w[k]); atomicAdd(&degcnt[ss[k]], 1.f); }
            }
        }
    }
    for (; i < end; i++) {
        int s0 = src_csr[i];
        uint4 a = xnb4[(size_t)s0 * 16 + t];
        float a0 = dot8(a);
        #pragma unroll
        for (int m = 8; m >= 1; m >>= 1) a0 += __shfl_xor(a0, m);
        float w0 = 0.f;
        if (s0 != node && a0 >= 0.49f) { float e0 = exact(s0); if (e0 >= 0.5f) w0 = e0; }
        if (t == 0) {
            w_csr[i] = w0;
            if (w0 != 0.f) { atomicAdd(&rowsum[s0], w0); atomicAdd(&degcnt[s0], 1.f); }
        }
    }
}

// ------------- per node: L1-normalize row weights, dinv, selfw*dinv^2 (layers 0/1) -------------
__global__ void row_finalize_kernel(const int* __restrict__ row_start,
                                    const int* __restrict__ src_csr,
                                    const float* __restrict__ rowsum,
                                    const float* __restrict__ degcnt,
                                    float* __restrict__ w_csr,
                                    float* __restrict__ dinv, float* __restrict__ swd2) {
    int gid = blockIdx.x * blockDim.x + threadIdx.x;
    int node = gid / 16;
    int t = gid % 16;
    if (node >= N_NODES) return;
    int beg = row_start[node], end = row_start[node + 1];
    float sum = 0.f;
    for (int i = beg + t; i < end; i += 16) {
        float w = w_csr[i];
        if (w != 0.f) {
            float wn = w / rowsum[src_csr[i]];   // rowsum >= w > 0 here
            w_csr[i] = wn;
            sum += wn;
        }
    }
    #pragma unroll
    for (int m = 8; m >= 1; m >>= 1) sum += __shfl_xor(sum, m);
    if (t == 0) {
        float sw = 1.f / (degcnt[node] + 1.f);
        float dv = rsqrtf(sw + sum);             // deg2 = selfw + sum > 0 always
        dinv[node] = dv;
        swd2[node] = sw * dv * dv;
    }
}

// ------------- layer-2 pass A, src-major: rowsum/out-degree per src, NO atomics -------------
__global__ void simA_kernel(const float* __restrict__ xn2,
                            const int* __restrict__ row_start_s, const int* __restrict__ dstp_csr,
                            float* __restrict__ rowsum, float* __restrict__ selfw) {
    int gid = blockIdx.x * blockDim.x + threadIdx.x;
    int node = gid / 16;
    int t = gid % 16;
    if (node >= N_NODES) return;
    float xd = xn2[(size_t)node * 16 + t];
    int beg = row_start_s[node], end = row_start_s[node + 1];
    float sum = 0.f, cnt = 0.f;
    int i = beg;
    for (; i + 1 < end; i += 2) {
        int d0 = dstp_csr[i], d1 = dstp_csr[i + 1];
        float a0 = xd * xn2[(size_t)d0 * 16 + t];
        float a1 = xd * xn2[(size_t)d1 * 16 + t];
        #pragma unroll
        for (int m = 8; m >= 1; m >>= 1) { a0 += __shfl_xor(a0, m); a1 += __shfl_xor(a1, m); }
        if (d0 != node && a0 >= 0.5f) { sum += a0; cnt += 1.f; }
        if (d1 != node && a1 >= 0.5f) { sum += a1; cnt += 1.f; }
    }
    if (i < end) {
        int d0 = dstp_csr[i];
        float a0 = xd * xn2[(size_t)d0 * 16 + t];
        #pragma unroll
        for (int m = 8; m >= 1; m >>= 1) a0 += __shfl_xor(a0, m);
        if (d0 != node && a0 >= 0.5f) { sum += a0; cnt += 1.f; }
    }
    if (t == 0) {
        rowsum[node] = sum;
        selfw[node] = 1.f / (cnt + 1.f);
    }
}

// ------------- layer-2 pass B, dst-major: recompute sim, normalize, deg2/dinv/swd2, NO atomics -------------
__global__ void simB_kernel(const float* __restrict__ xn2,
                            const int* __restrict__ row_start_d, const int* __restrict__ src_csr,
                            const float* __restrict__ rowsum, const float* __restrict__ selfw,
                            float* __restrict__ w_csr,
                            float* __restrict__ dinv, float* __restrict__ swd2) {
    int gid = blockIdx.x * blockDim.x + threadIdx.x;
    int node = gid / 16;
    int t = gid % 16;
    if (node >= N_NODES) return;
    float xd = xn2[(size_t)node * 16 + t];
    int beg = row_start_d[node], end = row_start_d[node + 1];
    float deg2 = 0.f;
    int i = beg;
    for (; i + 1 < end; i += 2) {
        int s0 = src_csr[i], s1 = src_csr[i + 1];
        float a0 = xd * xn2[(size_t)s0 * 16 + t];
        float a1 = xd * xn2[(size_t)s1 * 16 + t];
        #pragma unroll
        for (int m = 8; m >= 1; m >>= 1) { a0 += __shfl_xor(a0, m); a1 += __shfl_xor(a1, m); }
        float w0 = (s0 != node && a0 >= 0.5f) ? a0 / rowsum[s0] : 0.f;
        float w1 = (s1 != node && a1 >= 0.5f) ? a1 / rowsum[s1] : 0.f;
        if (t == 0) { w_csr[i] = w0; w_csr[i + 1] = w1; }
        deg2 += w0 + w1;
    }
    if (i < end) {
        int s0 = src_csr[i];
        float a0 = xd * xn2[(size_t)s0 * 16 + t];
        #pragma unroll
        for (int m = 8; m >= 1; m >>= 1) a0 += __shfl_xor(a0, m);
        float w0 = (s0 != node && a0 >= 0.5f) ? a0 / rowsum[s0] : 0.f;
        if (t == 0) w_csr[i] = w0;
        deg2 += w0;
    }
    if (t == 0) {
        float sw = selfw[node];
        float dv = rsqrtf(deg2 + sw);
        dinv[node] = dv;
        swd2[node] = sw * dv * dv;
    }
}

// ------------- tiled fp32 GEMM: h = x @ W -------------
template<int FIN, int FOUT, int TM, int KC, int RPT, int CPT>
__global__ __launch_bounds__(256) void gemm_tiled(const float* __restrict__ x,
                                                  const float* __restrict__ W,
                                                  float* __restrict__ h) {
    constexpr int COLG = FOUT / CPT;
    static_assert(COLG * (TM / RPT) == 256, "thread mapping");
    __shared__ float xT[KC][TM];
    __shared__ float Wl[KC][FOUT];
    int tid = threadIdx.x;
    int row0 = blockIdx.x * TM;
    int c0 = (tid % COLG) * CPT;
    int r0 = (tid / COLG) * RPT;
    float acc[RPT][CPT];
    #pragma unroll
    for (int r = 0; r < RPT; r++)
        #pragma unroll
        for (int c = 0; c < CPT; c++) acc[r][c] = 0.f;

    for (int kc = 0; kc < FIN; kc += KC) {
        constexpr int SLOTS_PER_ROW = KC / 4;
        constexpr int XQ = TM * KC / (256 * 4);
        #pragma unroll
        for (int j = 0; j < XQ; j++) {
            int idx = tid + j * 256;
            int tr = idx / SLOTS_PER_ROW;
            int tk = (idx % SLOTS_PER_ROW) * 4;
            int grow = row0 + tr;
            float4 v = make_float4(0.f, 0.f, 0.f, 0.f);
            if (grow < N_NODES) v = *(const float4*)(x + (size_t)grow * FIN + kc + tk);
            xT[tk + 0][tr] = v.x; xT[tk + 1][tr] = v.y;
            xT[tk + 2][tr] = v.z; xT[tk + 3][tr] = v.w;
        }
        if constexpr (KC * FOUT >= 1024) {
            constexpr int WQ = KC * FOUT / (256 * 4);
            #pragma unroll
            for (int j = 0; j < WQ; j++) {
                int idx = tid + j * 256;
                int wk = idx / (FOUT / 4);
                int wc = (idx % (FOUT / 4)) * 4;
                *(float4*)&Wl[wk][wc] = *(const float4*)(W + (size_t)(kc + wk) * FOUT + wc);
            }
        } else {
            Wl[tid / FOUT][tid % FOUT] = W[(size_t)(kc + tid / FOUT) * FOUT + tid % FOUT];
        }
        __syncthreads();

        #pragma unroll
        for (int k = 0; k < KC; k++) {
            float a[RPT];
            #pragma unroll
            for (int rr = 0; rr < RPT; rr += 4) {
                float4 xv = *(const float4*)&xT[k][r0 + rr];
                a[rr] = xv.x; a[rr+1] = xv.y; a[rr+2] = xv.z; a[rr+3] = xv.w;
            }
            if constexpr (CPT == 4) {
                float4 wv = *(const float4*)&Wl[k][c0];
                #pragma unroll
                for (int rr = 0; rr < RPT; rr++) {
                    acc[rr][0] += a[rr] * wv.x; acc[rr][1] += a[rr] * wv.y;
                    acc[rr][2] += a[rr] * wv.z; acc[rr][3] += a[rr] * wv.w;
                }
            } else {
                float wv = Wl[k][c0];
                #pragma unroll
                for (int rr = 0; rr < RPT; rr++) acc[rr][0] += a[rr] * wv;
            }
        }
        __syncthreads();
    }

    #pragma unroll
    for (int rr = 0; rr < RPT; rr++) {
        int grow = row0 + r0 + rr;
        if (grow < N_NODES) {
            if constexpr (CPT == 4) {
                float4 o = make_float4(acc[rr][0], acc[rr][1], acc[rr][2], acc[rr][3]);
                *(float4*)(h + (size_t)grow * FOUT + c0) = o;
            } else {
                h[(size_t)grow * FOUT + c0] = acc[rr][0];
            }
        }
    }
}

// ------------- gather conv FOUT=128 (fp32 w); ReLU+bias fused -------------
__global__ void conv_gather128_kernel(const int* __restrict__ row_start,
                                      const int* __restrict__ src_csr,
                                      const float* __restrict__ w_csr,
                                      const float* __restrict__ dinv,
                                      const float* __restrict__ swd2,
                                      const float* __restrict__ h,
                                      const float* __restrict__ b,
                                      float* __restrict__ out) {
    constexpr int TPN = 32;
    int gid = blockIdx.x * blockDim.x + threadIdx.x;
    int node = gid / TPN;
    int t = gid % TPN;
    if (node >= N_NODES) return;
    int beg = row_start[node], end = row_start[node + 1];
    float dv = dinv[node];
    float4 acc = make_float4(0.f, 0.f, 0.f, 0.f);
    for (int base = beg; base < end; base += TPN) {
        int i = base + t;
        float wv = 0.f; int sv = 0;
        if (i < end) {
            wv = w_csr[i];
            sv = src_csr[i];
            if (wv != 0.f) wv *= dinv[sv];       // fold dinv[src]
        }
        int cnt = end - base; if (cnt > TPN) cnt = TPN;
        #pragma unroll
        for (int j = 0; j < TPN; j++) {
            if (j >= cnt) break;
            float w = __shfl(wv, j, TPN);
            int   s = __shfl(sv, j, TPN);
            if (w != 0.f) {
                float coeff = w * dv;
                float4 hv = *(const float4*)(h + (size_t)s * 128 + t * 4);
                acc.x += coeff * hv.x; acc.y += coeff * hv.y;
                acc.z += coeff * hv.z; acc.w += coeff * hv.w;
            }
        }
    }
    float sd = swd2[node];
    float4 hv = *(const float4*)(h + (size_t)node * 128 + t * 4);
    float4 bv = *(const float4*)(b + t * 4);
    acc.x = fmaxf(acc.x + sd * hv.x + bv.x, 0.f);
    acc.y = fmaxf(acc.y + sd * hv.y + bv.y, 0.f);
    acc.z = fmaxf(acc.z + sd * hv.z + bv.z, 0.f);
    acc.w = fmaxf(acc.w + sd * hv.w + bv.w, 0.f);
    *(float4*)(out + (size_t)node * 128 + t * 4) = acc;
}

// ------------- gather conv F=16 (fp32 w); optional bias/relu + normalized fp32 row out -------------
template<bool BIAS_RELU, bool WNORM>
__global__ void conv_gather16_kernel(const int* __restrict__ row_start,
                                     const int* __restrict__ src_csr,
                                     const float* __restrict__ w_csr,
                                     const float* __restrict__ dinv,
                                     const float* __restrict__ swd2,
                                     const float* __restrict__ h,
                                     const float* __restrict__ b,
                                     float* __restrict__ out,
                                     float* __restrict__ xn_out) {
    constexpr int TPN = 16;
    int gid = blockIdx.x * blockDim.x + threadIdx.x;
    int node = gid / TPN;
    int t = gid % TPN;
    if (node >= N_NODES) return;
    int beg = row_start[node], end = row_start[node + 1];
    float dv = dinv[node];
    float acc = 0.f;
    for (int base = beg; base < end; base += TPN) {
        int i = base + t;
        float wv = 0.f; int sv = 0;
        if (i < end) {
            wv = w_csr[i];
            sv = src_csr[i];
            if (wv != 0.f) wv *= dinv[sv];
        }
        int cnt = end - base; if (cnt > TPN) cnt = TPN;
        #pragma unroll
        for (int j = 0; j < TPN; j++) {
            if (j >= cnt) break;
            float w = __shfl(wv, j, TPN);
            int   s = __shfl(sv, j, TPN);
            if (w != 0.f) acc += (w * dv) * h[(size_t)s * 16 + t];
        }
    }
    float v = acc + swd2[node] * h[(size_t)node * 16 + t];
    if (BIAS_RELU) v = fmaxf(v + b[t], 0.f);
    out[(size_t)node * 16 + t] = v;
    if (WNORM) {
        float ss = v * v;
        #pragma unroll
        for (int m = TPN/2; m >= 1; m >>= 1) ss += __shfl_xor(ss, m);
        float n = sqrtf(ss);
        float ni = (n == 0.f) ? 1.f : 1.f / n;
        xn_out[(size_t)node * 16 + t] = v * ni;
    }
}

// ------------- fused: out40 = agg16 @ W3 + b3, then log_softmax. One wave/node. -------------
__global__ void final_kernel(const float* __restrict__ agg16,
                             const float* __restrict__ W3, const float* __restrict__ b3,
                             float* __restrict__ out) {
    __shared__ float Wl[16 * 40];
    __shared__ float bl[40];
    for (int i = threadIdx.x; i < 16 * 40; i += blockDim.x) Wl[i] = W3[i];
    if (threadIdx.x < 40) bl[threadIdx.x] = b3[threadIdx.x];
    __syncthreads();
    int wid = threadIdx.x / 64;
    int lane = threadIdx.x % 64;
    int v = blockIdx.x * 4 + wid;
    if (v >= N_NODES) return;
    const float* ar = agg16 + (size_t)v * 16;
    float o = -INFINITY;
    if (lane < 40) {
        o = bl[lane];
        #pragma unroll
        for (int k = 0; k < 16; k++) o += ar[k] * Wl[k * 40 + lane];
    }
    float m = o;
    #pragma unroll
    for (int s = 32; s >= 1; s >>= 1) m = fmaxf(m, __shfl_xor(m, s));
    float ex = (lane < 40) ? expf(o - m) : 0.f;
    float sum = ex;
    #pragma unroll
    for (int s = 32; s >= 1; s >>= 1) sum += __shfl_xor(sum, s);
    float lse = m + logf(sum);
    if (lane < 40) out[(size_t)v * 40 + lane] = o - lse;
}

// =================== host orchestration ===================
extern "C" void kernel_launch(void* const* d_in, const int* in_sizes, int n_in,
                              void* d_out, int out_size, void* d_ws, size_t ws_size,
                              hipStream_t stream) {
    const float* x0 = (const float*)d_in[0];
    const int* ei   = (const int*)d_in[1];
    const int* src  = ei;
    const int* dst  = ei + N_EDGES;
    const float* W1 = (const float*)d_in[2];
    const float* b1 = (const float*)d_in[3];
    const float* W2 = (const float*)d_in[4];
    const float* b2 = (const float*)d_in[5];
    const float* W3 = (const float*)d_in[6];
    const float* b3 = (const float*)d_in[7];
    float* out = (float*)d_out;

    // workspace ~73 MB. Aliases (disjoint lifetimes):
    //   tmp_s/tmp_d alias xbuf1[0..3.2M) (dead before conv128 writes xbuf1)
    //   xnb4/agg16/xn2/xbuf2 alias inside h
    float* ws     = (float*)d_ws;
    float* xbuf1  = ws;                        // 6,400,000
    unsigned* tmp_s = (unsigned*)xbuf1;        // alias: 1.6M
    unsigned* tmp_d = (unsigned*)xbuf1 + N_EDGES; // alias: 1.6M
    float* h      = xbuf1 + 6400000;           // 6,400,000
    uint4* xnb4   = (uint4*)h;                 // alias
    float* agg16  = h;                         // alias
    float* xn2    = h + 800000;                // alias
    float* xbuf2  = h + 1600000;               // alias
    float* w_csr  = h + 6400000;               // 1,600,000 (fp32)
    float* nrminv = w_csr + 1600000;           // 50,000
    float* dinv   = nrminv + 50000;            // 50,000
    float* swd2   = dinv + 50000;              // 50,000
    float* rowsum2 = swd2 + 50000;             // 50,000 (layer 2, written fully, no zeroing)
    float* selfw2  = rowsum2 + 50000;          // 50,000
    int* zr        = (int*)(selfw2 + 50000);   // zero region
    float* rs0     = (float*)zr;               // 50,000
    float* dc0     = rs0 + 50000;
    float* rs1     = dc0 + 50000;
    float* dc1     = rs1 + 50000;
    int* bcnt_s    = (int*)(dc1 + 50000);      // 256
    int* bcnt_d    = bcnt_s + 256;             // 256  (end of zero region)
    int* bbase_s   = bcnt_d + 256;             // 257
    int* bbase_d   = bbase_s + 257;            // 257
    int* bcur_s    = bbase_d + 257;            // 256
    int* bcur_d    = bcur_s + 256;             // 256
    int* row_start_d = bcur_d + 256;           // 50,001
    int* row_start_s = row_start_d + 50001;    // 50,001
    int* src_csr   = row_start_s + 50001;      // 1,600,000 (by-dst payload = src)
    int* dstp_csr  = src_csr + N_EDGES;        // 1,600,000 (by-src payload = dst)

    const int BS = 256;

    // ---- one memset zeroes rowsum/degcnt pairs (L0,L1) + bucket counters ----
    hipMemsetAsync(zr, 0, (200000 + 512) * sizeof(int), stream);

    // ---- CSR build, both directions ----
    bucket_count_kernel<<<(N_EDGES + 8191) / 8192, BS, 0, stream>>>(src, dst, bcnt_s, bcnt_d);
    bucket_scan_kernel<<<1, BS, 0, stream>>>(bcnt_s, bcnt_d, bbase_s, bbase_d,
                                             bcur_s, bcur_d, row_start_s, row_start_d);
    partition2_kernel<<<(N_EDGES + 8191) / 8192, BS, 0, stream>>>(src, dst, bcur_s, bcur_d,
                                                                  tmp_s, tmp_d);
    csr_finalize_kernel<<<NBUCK, BS, 0, stream>>>(tmp_d, bbase_d, row_start_d, src_csr);
    csr_finalize_kernel<<<NBUCK, BS, 0, stream>>>(tmp_s, bbase_s, row_start_s, dstp_csr);

    // ================= Layer 0: 128 -> 128, ReLU =================
    norm_pack_kernel<<<(N_NODES * 16 + BS - 1) / BS, BS, 0, stream>>>(x0, nrminv, xnb4);
    sim128_kernel<<<(N_NODES * 16 + BS - 1) / BS, BS, 0, stream>>>(
        x0, nrminv, xnb4, row_start_d, src_csr, w_csr, rs0, dc0);
    row_finalize_kernel<<<(N_NODES * 16 + BS - 1) / BS, BS, 0, stream>>>(
        row_start_d, src_csr, rs0, dc0, w_csr, dinv, swd2);
    gemm_tiled<128, 128, 64, 16, 8, 4><<<(N_NODES + 63) / 64, BS, 0, stream>>>(x0, W1, h);
    conv_gather128_kernel<<<(N_NODES * 32 + BS - 1) / BS, BS, 0, stream>>>(
        row_start_d, src_csr, w_csr, dinv, swd2, h, b1, xbuf1);

    // ================= Layer 1: 128 -> 16, ReLU =================
    norm_pack_kernel<<<(N_NODES * 16 + BS - 1) / BS, BS, 0, stream>>>(xbuf1, nrminv, xnb4);
    sim128_kernel<<<(N_NODES * 16 + BS - 1) / BS, BS, 0, stream>>>(
        xbuf1, nrminv, xnb4, row_start_d, src_csr, w_csr, rs1, dc1);
    row_finalize_kernel<<<(N_NODES * 16 + BS - 1) / BS, BS, 0, stream>>>(
        row_start_d, src_csr, rs1, dc1, w_csr, dinv, swd2);
    gemm_tiled<128, 16, 128, 16, 8, 1><<<(N_NODES + 127) / 128, BS, 0, stream>>>(xbuf1, W2, h);
    conv_gather16_kernel<true, true><<<(N_NODES * 16 + BS - 1) / BS, BS, 0, stream>>>(
        row_start_d, src_csr, w_csr, dinv, swd2, h, b2, xbuf2, xn2);

    // ========== Layer 2: 16 -> 40 (atomic-free two-pass sim, aggregate, fused GEMM+LSM) ====
    simA_kernel<<<(N_NODES * 16 + BS - 1) / BS, BS, 0, stream>>>(
        xn2, row_start_s, dstp_csr, rowsum2, selfw2);
    simB_kernel<<<(N_NODES * 16 + BS - 1) / BS, BS, 0, stream>>>(
        xn2, row_start_d, src_csr, rowsum2, selfw2, w_csr, dinv, swd2);
    conv_gather16_kernel<false, false><<<(N_NODES * 16 + BS - 1) / BS, BS, 0, stream>>>(
        row_start_d, src_csr, w_csr, dinv, swd2, xbuf2, b3 /*unused*/, agg16, nullptr);
    final_kernel<<<(N_NODES + 3) / 4, BS, 0, stream>>>(agg16, W3, b3, out);
}

// Round 10
// 527.014 us; speedup vs baseline: 1.5900x; 1.0801x over previous
//
#include <hip/hip_runtime.h>
#include <math.h>

#define N_NODES 50000
#define N_EDGES 1600000
#define NBUCK ((N_NODES + 255) >> 8)   // 196 buckets of 256 nodes

// ---------------- norm + pack normalized int8 row (F=128) ----------------
// 16 lanes/node, lane t covers elems [t*8, t*8+8); 8 int8 -> uint2 per lane.
// q = rint(127 * x/||x||), |q| <= 127. Filter error bound: sqrt(128)*0.5/127 = 0.0446.
__global__ void norm_pack_kernel(const float* __restrict__ x, float* __restrict__ nrminv,
                                 uint2* __restrict__ xq2) {
    int gid = blockIdx.x * blockDim.x + threadIdx.x;
    int node = gid / 16;
    int t = gid % 16;
    if (node >= N_NODES) return;
    const float4* xr = (const float4*)(x + (size_t)node * 128) + t * 2;
    float4 v0 = xr[0], v1 = xr[1];
    float ss = v0.x*v0.x + v0.y*v0.y + v0.z*v0.z + v0.w*v0.w
             + v1.x*v1.x + v1.y*v1.y + v1.z*v1.z + v1.w*v1.w;
    #pragma unroll
    for (int m = 8; m >= 1; m >>= 1) ss += __shfl_xor(ss, m);
    float n = sqrtf(ss);
    float ni = (n == 0.f) ? 1.f : 1.f / n;
    if (t == 0) nrminv[node] = ni;
    float sc = ni * 127.f;
    int q0 = __float2int_rn(v0.x * sc), q1 = __float2int_rn(v0.y * sc);
    int q2 = __float2int_rn(v0.z * sc), q3 = __float2int_rn(v0.w * sc);
    int q4 = __float2int_rn(v1.x * sc), q5 = __float2int_rn(v1.y * sc);
    int q6 = __float2int_rn(v1.z * sc), q7 = __float2int_rn(v1.w * sc);
    uint2 p;
    p.x = (unsigned)(q0 & 255) | ((unsigned)(q1 & 255) << 8) |
          ((unsigned)(q2 & 255) << 16) | ((unsigned)(q3 & 255) << 24);
    p.y = (unsigned)(q4 & 255) | ((unsigned)(q5 & 255) << 8) |
          ((unsigned)(q6 & 255) << 16) | ((unsigned)(q7 & 255) << 24);
    xq2[(size_t)node * 16 + t] = p;
}

// =================== CSR build, both directions, bucket radix ===================
__global__ __launch_bounds__(256) void bucket_count_kernel(const int* __restrict__ src,
                                                           const int* __restrict__ dst,
                                                           int* __restrict__ bcnt_s,
                                                           int* __restrict__ bcnt_d) {
    __shared__ int cs[NBUCK], cd[NBUCK];
    int e0 = blockIdx.x * 8192;
    int eend = e0 + 8192; if (eend > N_EDGES) eend = N_EDGES;
    for (int i = threadIdx.x; i < NBUCK; i += 256) { cs[i] = 0; cd[i] = 0; }
    __syncthreads();
    for (int e = e0 + threadIdx.x; e < eend; e += 256) {
        atomicAdd(&cs[src[e] >> 8], 1);
        atomicAdd(&cd[dst[e] >> 8], 1);
    }
    __syncthreads();
    for (int i = threadIdx.x; i < NBUCK; i += 256) {
        if (cs[i]) atomicAdd(&bcnt_s[i], cs[i]);
        if (cd[i]) atomicAdd(&bcnt_d[i], cd[i]);
    }
}

__global__ void bucket_scan_kernel(const int* __restrict__ bcnt_s, const int* __restrict__ bcnt_d,
                                   int* __restrict__ bbase_s, int* __restrict__ bbase_d,
                                   int* __restrict__ bcur_s, int* __restrict__ bcur_d,
                                   int* __restrict__ row_start_s, int* __restrict__ row_start_d) {
    __shared__ int lds[256];
    int v = (threadIdx.x < NBUCK) ? bcnt_s[threadIdx.x] : 0;
    lds[threadIdx.x] = v;
    __syncthreads();
    for (int off = 1; off < 256; off <<= 1) {
        int add = (threadIdx.x >= off) ? lds[threadIdx.x - off] : 0;
        __syncthreads();
        lds[threadIdx.x] += add;
        __syncthreads();
    }
    if (threadIdx.x < NBUCK) {
        int e = lds[threadIdx.x] - v;
        bbase_s[threadIdx.x] = e; bcur_s[threadIdx.x] = e;
    }
    if (threadIdx.x == 0) { bbase_s[NBUCK] = N_EDGES; row_start_s[N_NODES] = N_EDGES; }
    __syncthreads();
    int v2 = (threadIdx.x < NBUCK) ? bcnt_d[threadIdx.x] : 0;
    lds[threadIdx.x] = v2;
    __syncthreads();
    for (int off = 1; off < 256; off <<= 1) {
        int add = (threadIdx.x >= off) ? lds[threadIdx.x - off] : 0;
        __syncthreads();
        lds[threadIdx.x] += add;
        __syncthreads();
    }
    if (threadIdx.x < NBUCK) {
        int e = lds[threadIdx.x] - v2;
        bbase_d[threadIdx.x] = e; bcur_d[threadIdx.x] = e;
    }
    if (threadIdx.x == 0) { bbase_d[NBUCK] = N_EDGES; row_start_d[N_NODES] = N_EDGES; }
}

__global__ __launch_bounds__(256) void partition2_kernel(const int* __restrict__ src,
                                                         const int* __restrict__ dst,
                                                         int* __restrict__ bcur_s,
                                                         int* __restrict__ bcur_d,
                                                         unsigned* __restrict__ tmp_s,
                                                         unsigned* __restrict__ tmp_d) {
    __shared__ int cs[NBUCK], cd[NBUCK], bs[NBUCK], bd[NBUCK];
    int e0 = blockIdx.x * 8192;
    int eend = e0 + 8192; if (eend > N_EDGES) eend = N_EDGES;
    for (int i = threadIdx.x; i < NBUCK; i += 256) { cs[i] = 0; cd[i] = 0; }
    __syncthreads();
    for (int e = e0 + threadIdx.x; e < eend; e += 256) {
        atomicAdd(&cs[src[e] >> 8], 1);
        atomicAdd(&cd[dst[e] >> 8], 1);
    }
    __syncthreads();
    for (int i = threadIdx.x; i < NBUCK; i += 256) {
        int c = cs[i]; bs[i] = c ? atomicAdd(&bcur_s[i], c) : 0;
        c = cd[i];     bd[i] = c ? atomicAdd(&bcur_d[i], c) : 0;
    }
    __syncthreads();
    for (int e = e0 + threadIdx.x; e < eend; e += 256) {
        int s = src[e], d = dst[e];
        int ps = atomicAdd(&bs[s >> 8], 1);
        tmp_s[ps] = (unsigned)d | ((unsigned)(s & 255) << 16);
        int pd = atomicAdd(&bd[d >> 8], 1);
        tmp_d[pd] = (unsigned)s | ((unsigned)(d & 255) << 16);
    }
}

__global__ __launch_bounds__(256) void csr_finalize_kernel(const unsigned* __restrict__ tmp,
                                                           const int* __restrict__ bbase,
                                                           int* __restrict__ row_start,
                                                           int* __restrict__ csr_out) {
    __shared__ int cnt[256];
    __shared__ int cur[256];
    int b = blockIdx.x;
    int beg = bbase[b], end = bbase[b + 1];
    cnt[threadIdx.x] = 0;
    __syncthreads();
    for (int j = beg + threadIdx.x; j < end; j += 256)
        atomicAdd(&cnt[tmp[j] >> 16], 1);
    __syncthreads();
    int v = cnt[threadIdx.x];
    cur[threadIdx.x] = v;
    __syncthreads();
    for (int off = 1; off < 256; off <<= 1) {
        int add = (threadIdx.x >= off) ? cur[threadIdx.x - off] : 0;
        __syncthreads();
        cur[threadIdx.x] += add;
        __syncthreads();
    }
    int excl = cur[threadIdx.x] - v;
    int node = (b << 8) + threadIdx.x;
    if (node < N_NODES) row_start[node] = beg + excl;
    __syncthreads();
    cur[threadIdx.x] = beg + excl;
    __syncthreads();
    for (int j = beg + threadIdx.x; j < end; j += 256) {
        unsigned t = tmp[j];
        int pos = atomicAdd(&cur[t >> 16], 1);
        csr_out[pos] = (int)(t & 0xFFFFu);
    }
}

// ------------- two-phase sim, F=128, dst-major: int8 gathers as FILTER
//               (margin 0.05 > 0.0446 bound); exact fp32 recompute on accepts. -------------
__global__ void sim128_kernel(const float* __restrict__ x, const float* __restrict__ nrminv,
                              const uint2* __restrict__ xq2,
                              const int* __restrict__ row_start, const int* __restrict__ src_csr,
                              float* __restrict__ w_csr,
                              float* __restrict__ rowsum, float* __restrict__ degcnt) {
    int gid = blockIdx.x * blockDim.x + threadIdx.x;
    int node = gid / 16;
    int t = gid % 16;
    if (node >= N_NODES) return;
    float xd[8];
    {
        const float4* xr = (const float4*)(x + (size_t)node * 128) + t * 2;
        float4 v0 = xr[0], v1 = xr[1];
        float nd = nrminv[node];
        xd[0]=v0.x*nd; xd[1]=v0.y*nd; xd[2]=v0.z*nd; xd[3]=v0.w*nd;
        xd[4]=v1.x*nd; xd[5]=v1.y*nd; xd[6]=v1.z*nd; xd[7]=v1.w*nd;
    }
    int beg = row_start[node], end = row_start[node + 1];

    // filter threshold pre-scaled by 127: sim_est >= 0.45  <=>  acc >= 57.15
    const float THRQ = 57.15f;

    auto dot8q = [&](uint2 a) -> float {
        int w0 = (int)a.x, w1 = (int)a.y;
        float r;
        r  = xd[0] * (float)((w0 << 24) >> 24);
        r += xd[1] * (float)((w0 << 16) >> 24);
        r += xd[2] * (float)((w0 <<  8) >> 24);
        r += xd[3] * (float)( w0        >> 24);
        r += xd[4] * (float)((w1 << 24) >> 24);
        r += xd[5] * (float)((w1 << 16) >> 24);
        r += xd[6] * (float)((w1 <<  8) >> 24);
        r += xd[7] * (float)( w1        >> 24);
        return r;
    };
    auto exact = [&](int s) -> float {          // group-uniform call
        const float4* xs = (const float4*)(x + (size_t)s * 128) + t * 2;
        float4 u0 = xs[0], u1 = xs[1];
        float r = xd[0]*u0.x + xd[1]*u0.y + xd[2]*u0.z + xd[3]*u0.w
                + xd[4]*u1.x + xd[5]*u1.y + xd[6]*u1.z + xd[7]*u1.w;
        #pragma unroll
        for (int m = 8; m >= 1; m >>= 1) r += __shfl_xor(r, m);
        return r * nrminv[s];
    };

    int i = beg;
    for (; i + 3 < end; i += 4) {
        int ss[4]; uint2 aa[4]; float ac[4];
        #pragma unroll
        for (int k = 0; k < 4; k++) ss[k] = src_csr[i + k];
        #pragma unroll
        for (int k = 0; k < 4; k++) aa[k] = xq2[(size_t)ss[k] * 16 + t];
        #pragma unroll
        for (int k = 0; k < 4; k++) ac[k] = dot8q(aa[k]);
        #pragma unroll
        for (int m = 8; m >= 1; m >>= 1) {
            ac[0] += __shfl_xor(ac[0], m); ac[1] += __shfl_xor(ac[1], m);
            ac[2] += __shfl_xor(ac[2], m); ac[3] += __shfl_xor(ac[3], m);
        }
        float w[4];
        #pragma unroll
        for (int k = 0; k < 4; k++) {
            w[k] = 0.f;
            if (ss[k] != node && ac[k] >= THRQ) {
                float e = exact(ss[k]);
                if (e >= 0.5f) w[k] = e;
            }
        }
        if (t == 0) {
            #pragma unroll
            for (int k = 0; k < 4; k++) {
                w_csr[i + k] = w[k];
                if (w[k] != 0.f) { atomicAdd(&rowsum[ss[k]], w[k]); atomicAdd(&degcnt[ss[k]], 1.f); }
            }
        }
    }
    for (; i < end; i++) {
        int s0 = src_csr[i];
        uint2 a = xq2[(size_t)s0 * 16 + t];
        float a0 = dot8q(a);
        #pragma unroll
        for (int m = 8; m >= 1; m >>= 1) a0 += __shfl_xor(a0, m);
        float w0 = 0.f;
        if (s0 != node && a0 >= THRQ) { float e0 = exact(s0); if (e0 >= 0.5f) w0 = e0; }
        if (t == 0) {
            w_csr[i] = w0;
            if (w0 != 0.f) { atomicAdd(&rowsum[s0], w0); atomicAdd(&degcnt[s0], 1.f); }
        }
    }
}

// ------------- per node: L1-normalize row weights, dinv, selfw*dinv^2 (layers 0/1) -------------
__global__ void row_finalize_kernel(const int* __restrict__ row_start,
                                    const int* __restrict__ src_csr,
                                    const float* __restrict__ rowsum,
                                    const float* __restrict__ degcnt,
                                    float* __restrict__ w_csr,
                                    float* __restrict__ dinv, float* __restrict__ swd2) {
    int gid = blockIdx.x * blockDim.x + threadIdx.x;
    int node = gid / 16;
    int t = gid % 16;
    if (node >= N_NODES) return;
    int beg = row_start[node], end = row_start[node + 1];
    float sum = 0.f;
    for (int i = beg + t; i < end; i += 16) {
        float w = w_csr[i];
        if (w != 0.f) {
            float wn = w / rowsum[src_csr[i]];   // rowsum >= w > 0 here
            w_csr[i] = wn;
            sum += wn;
        }
    }
    #pragma unroll
    for (int m = 8; m >= 1; m >>= 1) sum += __shfl_xor(sum, m);
    if (t == 0) {
        float sw = 1.f / (degcnt[node] + 1.f);
        float dv = rsqrtf(sw + sum);             // deg2 = selfw + sum > 0 always
        dinv[node] = dv;
        swd2[node] = sw * dv * dv;
    }
}

// ------------- layer-2 pass A, src-major: rowsum/out-degree per src, NO atomics -------------
__global__ void simA_kernel(const float* __restrict__ xn2,
                            const int* __restrict__ row_start_s, const int* __restrict__ dstp_csr,
                            float* __restrict__ rowsum, float* __restrict__ selfw) {
    int gid = blockIdx.x * blockDim.x + threadIdx.x;
    int node = gid / 16;
    int t = gid % 16;
    if (node >= N_NODES) return;
    float xd = xn2[(size_t)node * 16 + t];
    int beg = row_start_s[node], end = row_start_s[node + 1];
    float sum = 0.f, cnt = 0.f;
    int i = beg;
    for (; i + 1 < end; i += 2) {
        int d0 = dstp_csr[i], d1 = dstp_csr[i + 1];
        float a0 = xd * xn2[(size_t)d0 * 16 + t];
        float a1 = xd * xn2[(size_t)d1 * 16 + t];
        #pragma unroll
        for (int m = 8; m >= 1; m >>= 1) { a0 += __shfl_xor(a0, m); a1 += __shfl_xor(a1, m); }
        if (d0 != node && a0 >= 0.5f) { sum += a0; cnt += 1.f; }
        if (d1 != node && a1 >= 0.5f) { sum += a1; cnt += 1.f; }
    }
    if (i < end) {
        int d0 = dstp_csr[i];
        float a0 = xd * xn2[(size_t)d0 * 16 + t];
        #pragma unroll
        for (int m = 8; m >= 1; m >>= 1) a0 += __shfl_xor(a0, m);
        if (d0 != node && a0 >= 0.5f) { sum += a0; cnt += 1.f; }
    }
    if (t == 0) {
        rowsum[node] = sum;
        selfw[node] = 1.f / (cnt + 1.f);
    }
}

// ------------- layer-2 pass B, dst-major: recompute sim, normalize, deg2/dinv/swd2, NO atomics -------------
__global__ void simB_kernel(const float* __restrict__ xn2,
                            const int* __restrict__ row_start_d, const int* __restrict__ src_csr,
                            const float* __restrict__ rowsum, const float* __restrict__ selfw,
                            float* __restrict__ w_csr,
                            float* __restrict__ dinv, float* __restrict__ swd2) {
    int gid = blockIdx.x * blockDim.x + threadIdx.x;
    int node = gid / 16;
    int t = gid % 16;
    if (node >= N_NODES) return;
    float xd = xn2[(size_t)node * 16 + t];
    int beg = row_start_d[node], end = row_start_d[node + 1];
    float deg2 = 0.f;
    int i = beg;
    for (; i + 1 < end; i += 2) {
        int s0 = src_csr[i], s1 = src_csr[i + 1];
        float a0 = xd * xn2[(size_t)s0 * 16 + t];
        float a1 = xd * xn2[(size_t)s1 * 16 + t];
        #pragma unroll
        for (int m = 8; m >= 1; m >>= 1) { a0 += __shfl_xor(a0, m); a1 += __shfl_xor(a1, m); }
        float w0 = (s0 != node && a0 >= 0.5f) ? a0 / rowsum[s0] : 0.f;
        float w1 = (s1 != node && a1 >= 0.5f) ? a1 / rowsum[s1] : 0.f;
        if (t == 0) { w_csr[i] = w0; w_csr[i + 1] = w1; }
        deg2 += w0 + w1;
    }
    if (i < end) {
        int s0 = src_csr[i];
        float a0 = xd * xn2[(size_t)s0 * 16 + t];
        #pragma unroll
        for (int m = 8; m >= 1; m >>= 1) a0 += __shfl_xor(a0, m);
        float w0 = (s0 != node && a0 >= 0.5f) ? a0 / rowsum[s0] : 0.f;
        if (t == 0) w_csr[i] = w0;
        deg2 += w0;
    }
    if (t == 0) {
        float sw = selfw[node];
        float dv = rsqrtf(deg2 + sw);
        dinv[node] = dv;
        swd2[node] = sw * dv * dv;
    }
}

// ------------- tiled fp32 GEMM: h = x @ W -------------
template<int FIN, int FOUT, int TM, int KC, int RPT, int CPT>
__global__ __launch_bounds__(256) void gemm_tiled(const float* __restrict__ x,
                                                  const float* __restrict__ W,
                                                  float* __restrict__ h) {
    constexpr int COLG = FOUT / CPT;
    static_assert(COLG * (TM / RPT) == 256, "thread mapping");
    __shared__ float xT[KC][TM];
    __shared__ float Wl[KC][FOUT];
    int tid = threadIdx.x;
    int row0 = blockIdx.x * TM;
    int c0 = (tid % COLG) * CPT;
    int r0 = (tid / COLG) * RPT;
    float acc[RPT][CPT];
    #pragma unroll
    for (int r = 0; r < RPT; r++)
        #pragma unroll
        for (int c = 0; c < CPT; c++) acc[r][c] = 0.f;

    for (int kc = 0; kc < FIN; kc += KC) {
        constexpr int SLOTS_PER_ROW = KC / 4;
        constexpr int XQ = TM * KC / (256 * 4);
        #pragma unroll
        for (int j = 0; j < XQ; j++) {
            int idx = tid + j * 256;
            int tr = idx / SLOTS_PER_ROW;
            int tk = (idx % SLOTS_PER_ROW) * 4;
            int grow = row0 + tr;
            float4 v = make_float4(0.f, 0.f, 0.f, 0.f);
            if (grow < N_NODES) v = *(const float4*)(x + (size_t)grow * FIN + kc + tk);
            xT[tk + 0][tr] = v.x; xT[tk + 1][tr] = v.y;
            xT[tk + 2][tr] = v.z; xT[tk + 3][tr] = v.w;
        }
        if constexpr (KC * FOUT >= 1024) {
            constexpr int WQ = KC * FOUT / (256 * 4);
            #pragma unroll
            for (int j = 0; j < WQ; j++) {
                int idx = tid + j * 256;
                int wk = idx / (FOUT / 4);
                int wc = (idx % (FOUT / 4)) * 4;
                *(float4*)&Wl[wk][wc] = *(const float4*)(W + (size_t)(kc + wk) * FOUT + wc);
            }
        } else {
            Wl[tid / FOUT][tid % FOUT] = W[(size_t)(kc + tid / FOUT) * FOUT + tid % FOUT];
        }
        __syncthreads();

        #pragma unroll
        for (int k = 0; k < KC; k++) {
            float a[RPT];
            #pragma unroll
            for (int rr = 0; rr < RPT; rr += 4) {
                float4 xv = *(const float4*)&xT[k][r0 + rr];
                a[rr] = xv.x; a[rr+1] = xv.y; a[rr+2] = xv.z; a[rr+3] = xv.w;
            }
            if constexpr (CPT == 4) {
                float4 wv = *(const float4*)&Wl[k][c0];
                #pragma unroll
                for (int rr = 0; rr < RPT; rr++) {
                    acc[rr][0] += a[rr] * wv.x; acc[rr][1] += a[rr] * wv.y;
                    acc[rr][2] += a[rr] * wv.z; acc[rr][3] += a[rr] * wv.w;
                }
            } else {
                float wv = Wl[k][c0];
                #pragma unroll
                for (int rr = 0; rr < RPT; rr++) acc[rr][0] += a[rr] * wv;
            }
        }
        __syncthreads();
    }

    #pragma unroll
    for (int rr = 0; rr < RPT; rr++) {
        int grow = row0 + r0 + rr;
        if (grow < N_NODES) {
            if constexpr (CPT == 4) {
                float4 o = make_float4(acc[rr][0], acc[rr][1], acc[rr][2], acc[rr][3]);
                *(float4*)(h + (size_t)grow * FOUT + c0) = o;
            } else {
                h[(size_t)grow * FOUT + c0] = acc[rr][0];
            }
        }
    }
}

// ------------- gather conv FOUT=128 (fp32 w); ReLU+bias fused -------------
__global__ void conv_gather128_kernel(const int* __restrict__ row_start,
                                      const int* __restrict__ src_csr,
                                      const float* __restrict__ w_csr,
                                      const float* __restrict__ dinv,
                                      const float* __restrict__ swd2,
                                      const float* __restrict__ h,
                                      const float* __restrict__ b,
                                      float* __restrict__ out) {
    constexpr int TPN = 32;
    int gid = blockIdx.x * blockDim.x + threadIdx.x;
    int node = gid / TPN;
    int t = gid % TPN;
    if (node >= N_NODES) return;
    int beg = row_start[node], end = row_start[node + 1];
    float dv = dinv[node];
    float4 acc = make_float4(0.f, 0.f, 0.f, 0.f);
    for (int base = beg; base < end; base += TPN) {
        int i = base + t;
        float wv = 0.f; int sv = 0;
        if (i < end) {
            wv = w_csr[i];
            sv = src_csr[i];
            if (wv != 0.f) wv *= dinv[sv];       // fold dinv[src]
        }
        int cnt = end - base; if (cnt > TPN) cnt = TPN;
        #pragma unroll
        for (int j = 0; j < TPN; j++) {
            if (j >= cnt) break;
            float w = __shfl(wv, j, TPN);
            int   s = __shfl(sv, j, TPN);
            if (w != 0.f) {
                float coeff = w * dv;
                float4 hv = *(const float4*)(h + (size_t)s * 128 + t * 4);
                acc.x += coeff * hv.x; acc.y += coeff * hv.y;
                acc.z += coeff * hv.z; acc.w += coeff * hv.w;
            }
        }
    }
    float sd = swd2[node];
    float4 hv = *(const float4*)(h + (size_t)node * 128 + t * 4);
    float4 bv = *(const float4*)(b + t * 4);
    acc.x = fmaxf(acc.x + sd * hv.x + bv.x, 0.f);
    acc.y = fmaxf(acc.y + sd * hv.y + bv.y, 0.f);
    acc.z = fmaxf(acc.z + sd * hv.z + bv.z, 0.f);
    acc.w = fmaxf(acc.w + sd * hv.w + bv.w, 0.f);
    *(float4*)(out + (size_t)node * 128 + t * 4) = acc;
}

// ------------- gather conv F=16 (fp32 w); optional bias/relu + normalized fp32 row out -------------
template<bool BIAS_RELU, bool WNORM>
__global__ void conv_gather16_kernel(const int* __restrict__ row_start,
                                     const int* __restrict__ src_csr,
                                     const float* __restrict__ w_csr,
                                     const float* __restrict__ dinv,
                                     const float* __restrict__ swd2,
                                     const float* __restrict__ h,
                                     const float* __restrict__ b,
                                     float* __restrict__ out,
                                     float* __restrict__ xn_out) {
    constexpr int TPN = 16;
    int gid = blockIdx.x * blockDim.x + threadIdx.x;
    int node = gid / TPN;
    int t = gid % TPN;
    if (node >= N_NODES) return;
    int beg = row_start[node], end = row_start[node + 1];
    float dv = dinv[node];
    float acc = 0.f;
    for (int base = beg; base < end; base += TPN) {
        int i = base + t;
        float wv = 0.f; int sv = 0;
        if (i < end) {
            wv = w_csr[i];
            sv = src_csr[i];
            if (wv != 0.f) wv *= dinv[sv];
        }
        int cnt = end - base; if (cnt > TPN) cnt = TPN;
        #pragma unroll
        for (int j = 0; j < TPN; j++) {
            if (j >= cnt) break;
            float w = __shfl(wv, j, TPN);
            int   s = __shfl(sv, j, TPN);
            if (w != 0.f) acc += (w * dv) * h[(size_t)s * 16 + t];
        }
    }
    float v = acc + swd2[node] * h[(size_t)node * 16 + t];
    if (BIAS_RELU) v = fmaxf(v + b[t], 0.f);
    out[(size_t)node * 16 + t] = v;
    if (WNORM) {
        float ss = v * v;
        #pragma unroll
        for (int m = TPN/2; m >= 1; m >>= 1) ss += __shfl_xor(ss, m);
        float n = sqrtf(ss);
        float ni = (n == 0.f) ? 1.f : 1.f / n;
        xn_out[(size_t)node * 16 + t] = v * ni;
    }
}

// ------------- fused: out40 = agg16 @ W3 + b3, then log_softmax. One wave/node. -------------
__global__ void final_kernel(const float* __restrict__ agg16,
                             const float* __restrict__ W3, const float* __restrict__ b3,
                             float* __restrict__ out) {
    __shared__ float Wl[16 * 40];
    __shared__ float bl[40];
    for (int i = threadIdx.x; i < 16 * 40; i += blockDim.x) Wl[i] = W3[i];
    if (threadIdx.x < 40) bl[threadIdx.x] = b3[threadIdx.x];
    __syncthreads();
    int wid = threadIdx.x / 64;
    int lane = threadIdx.x % 64;
    int v = blockIdx.x * 4 + wid;
    if (v >= N_NODES) return;
    const float* ar = agg16 + (size_t)v * 16;
    float o = -INFINITY;
    if (lane < 40) {
        o = bl[lane];
        #pragma unroll
        for (int k = 0; k < 16; k++) o += ar[k] * Wl[k * 40 + lane];
    }
    float m = o;
    #pragma unroll
    for (int s = 32; s >= 1; s >>= 1) m = fmaxf(m, __shfl_xor(m, s));
    float ex = (lane < 40) ? expf(o - m) : 0.f;
    float sum = ex;
    #pragma unroll
    for (int s = 32; s >= 1; s >>= 1) sum += __shfl_xor(sum, s);
    float lse = m + logf(sum);
    if (lane < 40) out[(size_t)v * 40 + lane] = o - lse;
}

// =================== host orchestration ===================
extern "C" void kernel_launch(void* const* d_in, const int* in_sizes, int n_in,
                              void* d_out, int out_size, void* d_ws, size_t ws_size,
                              hipStream_t stream) {
    const float* x0 = (const float*)d_in[0];
    const int* ei   = (const int*)d_in[1];
    const int* src  = ei;
    const int* dst  = ei + N_EDGES;
    const float* W1 = (const float*)d_in[2];
    const float* b1 = (const float*)d_in[3];
    const float* W2 = (const float*)d_in[4];
    const float* b2 = (const float*)d_in[5];
    const float* W3 = (const float*)d_in[6];
    const float* b3 = (const float*)d_in[7];
    float* out = (float*)d_out;

    // workspace ~73 MB. Aliases (disjoint lifetimes):
    //   tmp_s/tmp_d alias xbuf1[0..3.2M) (dead before conv128 writes xbuf1)
    //   xq2 (int8 table, 1.6M slots) / agg16 / xn2 / xbuf2 alias inside h
    //   (xq2 dies before each gemm writes h)
    float* ws     = (float*)d_ws;
    float* xbuf1  = ws;                        // 6,400,000
    unsigned* tmp_s = (unsigned*)xbuf1;        // alias: 1.6M
    unsigned* tmp_d = (unsigned*)xbuf1 + N_EDGES; // alias: 1.6M
    float* h      = xbuf1 + 6400000;           // 6,400,000
    uint2* xq2    = (uint2*)h;                 // alias: h[0..1.6M slots) as int8 rows
    float* agg16  = h;                         // alias
    float* xn2    = h + 800000;                // alias
    float* xbuf2  = h + 1600000;               // alias
    float* w_csr  = h + 6400000;               // 1,600,000 (fp32)
    float* nrminv = w_csr + 1600000;           // 50,000
    float* dinv   = nrminv + 50000;            // 50,000
    float* swd2   = dinv + 50000;              // 50,000
    float* rowsum2 = swd2 + 50000;             // 50,000 (layer 2, fully written)
    float* selfw2  = rowsum2 + 50000;          // 50,000
    int* zr        = (int*)(selfw2 + 50000);   // zero region
    float* rs0     = (float*)zr;               // 50,000
    float* dc0     = rs0 + 50000;
    float* rs1     = dc0 + 50000;
    float* dc1     = rs1 + 50000;
    int* bcnt_s    = (int*)(dc1 + 50000);      // 256
    int* bcnt_d    = bcnt_s + 256;             // 256  (end of zero region)
    int* bbase_s   = bcnt_d + 256;             // 257
    int* bbase_d   = bbase_s + 257;            // 257
    int* bcur_s    = bbase_d + 257;            // 256
    int* bcur_d    = bcur_s + 256;             // 256
    int* row_start_d = bcur_d + 256;           // 50,001
    int* row_start_s = row_start_d + 50001;    // 50,001
    int* src_csr   = row_start_s + 50001;      // 1,600,000 (by-dst payload = src)
    int* dstp_csr  = src_csr + N_EDGES;        // 1,600,000 (by-src payload = dst)

    const int BS = 256;

    // ---- one memset zeroes rowsum/degcnt pairs (L0,L1) + bucket counters ----
    hipMemsetAsync(zr, 0, (200000 + 512) * sizeof(int), stream);

    // ---- CSR build, both directions ----
    bucket_count_kernel<<<(N_EDGES + 8191) / 8192, BS, 0, stream>>>(src, dst, bcnt_s, bcnt_d);
    bucket_scan_kernel<<<1, BS, 0, stream>>>(bcnt_s, bcnt_d, bbase_s, bbase_d,
                                             bcur_s, bcur_d, row_start_s, row_start_d);
    partition2_kernel<<<(N_EDGES + 8191) / 8192, BS, 0, stream>>>(src, dst, bcur_s, bcur_d,
                                                                  tmp_s, tmp_d);
    csr_finalize_kernel<<<NBUCK, BS, 0, stream>>>(tmp_d, bbase_d, row_start_d, src_csr);
    csr_finalize_kernel<<<NBUCK, BS, 0, stream>>>(tmp_s, bbase_s, row_start_s, dstp_csr);

    // ================= Layer 0: 128 -> 128, ReLU =================
    norm_pack_kernel<<<(N_NODES * 16 + BS - 1) / BS, BS, 0, stream>>>(x0, nrminv, xq2);
    sim128_kernel<<<(N_NODES * 16 + BS - 1) / BS, BS, 0, stream>>>(
        x0, nrminv, xq2, row_start_d, src_csr, w_csr, rs0, dc0);
    row_finalize_kernel<<<(N_NODES * 16 + BS - 1) / BS, BS, 0, stream>>>(
        row_start_d, src_csr, rs0, dc0, w_csr, dinv, swd2);
    gemm_tiled<128, 128, 64, 16, 8, 4><<<(N_NODES + 63) / 64, BS, 0, stream>>>(x0, W1, h);
    conv_gather128_kernel<<<(N_NODES * 32 + BS - 1) / BS, BS, 0, stream>>>(
        row_start_d, src_csr, w_csr, dinv, swd2, h, b1, xbuf1);

    // ================= Layer 1: 128 -> 16, ReLU =================
    norm_pack_kernel<<<(N_NODES * 16 + BS - 1) / BS, BS, 0, stream>>>(xbuf1, nrminv, xq2);
    sim128_kernel<<<(N_NODES * 16 + BS - 1) / BS, BS, 0, stream>>>(
        xbuf1, nrminv, xq2, row_start_d, src_csr, w_csr, rs1, dc1);
    row_finalize_kernel<<<(N_NODES * 16 + BS - 1) / BS, BS, 0, stream>>>(
        row_start_d, src_csr, rs1, dc1, w_csr, dinv, swd2);
    gemm_tiled<128, 16, 128, 16, 8, 1><<<(N_NODES + 127) / 128, BS, 0, stream>>>(xbuf1, W2, h);
    conv_gather16_kernel<true, true><<<(N_NODES * 16 + BS - 1) / BS, BS, 0, stream>>>(
        row_start_d, src_csr, w_csr, dinv, swd2, h, b2, xbuf2, xn2);

    // ========== Layer 2: 16 -> 40 (atomic-free two-pass sim, aggregate, fused GEMM+LSM) ====
    simA_kernel<<<(N_NODES * 16 + BS - 1) / BS, BS, 0, stream>>>(
        xn2, row_start_s, dstp_csr, rowsum2, selfw2);
    simB_kernel<<<(N_NODES * 16 + BS - 1) / BS, BS, 0, stream>>>(
        xn2, row_start_d, src_csr, rowsum2, selfw2, w_csr, dinv, swd2);
    conv_gather16_kernel<false, false><<<(N_NODES * 16 + BS - 1) / BS, BS, 0, stream>>>(
        row_start_d, src_csr, w_csr, dinv, swd2, xbuf2, b3 /*unused*/, agg16, nullptr);
    final_kernel<<<(N_NODES + 3) / 4, BS, 0, stream>>>(agg16, W3, b3, out);
}

// Round 11
// 477.693 us; speedup vs baseline: 1.7542x; 1.1032x over previous
//
#include <hip/hip_runtime.h>
#include <math.h>

#define N_NODES 50000
#define N_EDGES 1600000
#define NBUCK ((N_NODES + 255) >> 8)   // 196 buckets of 256 nodes

// ---------------- norm + pack normalized int8 row (F=128) ----------------
// 16 lanes/node, lane t covers elems [t*8, t*8+8); 8 int8 -> uint2 per lane.
// q = rint(127 * x/||x||), |q| <= 127. Filter error bound: sqrt(128)*0.5/127 = 0.0446.
__global__ void norm_pack_kernel(const float* __restrict__ x, float* __restrict__ nrminv,
                                 uint2* __restrict__ xq2) {
    int gid = blockIdx.x * blockDim.x + threadIdx.x;
    int node = gid / 16;
    int t = gid % 16;
    if (node >= N_NODES) return;
    const float4* xr = (const float4*)(x + (size_t)node * 128) + t * 2;
    float4 v0 = xr[0], v1 = xr[1];
    float ss = v0.x*v0.x + v0.y*v0.y + v0.z*v0.z + v0.w*v0.w
             + v1.x*v1.x + v1.y*v1.y + v1.z*v1.z + v1.w*v1.w;
    #pragma unroll
    for (int m = 8; m >= 1; m >>= 1) ss += __shfl_xor(ss, m);
    float n = sqrtf(ss);
    float ni = (n == 0.f) ? 1.f : 1.f / n;
    if (t == 0) nrminv[node] = ni;
    float sc = ni * 127.f;
    int q0 = __float2int_rn(v0.x * sc), q1 = __float2int_rn(v0.y * sc);
    int q2 = __float2int_rn(v0.z * sc), q3 = __float2int_rn(v0.w * sc);
    int q4 = __float2int_rn(v1.x * sc), q5 = __float2int_rn(v1.y * sc);
    int q6 = __float2int_rn(v1.z * sc), q7 = __float2int_rn(v1.w * sc);
    uint2 p;
    p.x = (unsigned)(q0 & 255) | ((unsigned)(q1 & 255) << 8) |
          ((unsigned)(q2 & 255) << 16) | ((unsigned)(q3 & 255) << 24);
    p.y = (unsigned)(q4 & 255) | ((unsigned)(q5 & 255) << 8) |
          ((unsigned)(q6 & 255) << 16) | ((unsigned)(q7 & 255) << 24);
    xq2[(size_t)node * 16 + t] = p;
}

// =================== CSR build, both directions, bucket radix ===================
__global__ __launch_bounds__(256) void bucket_count_kernel(const int* __restrict__ src,
                                                           const int* __restrict__ dst,
                                                           int* __restrict__ bcnt_s,
                                                           int* __restrict__ bcnt_d) {
    __shared__ int cs[NBUCK], cd[NBUCK];
    int e0 = blockIdx.x * 8192;
    int eend = e0 + 8192; if (eend > N_EDGES) eend = N_EDGES;
    for (int i = threadIdx.x; i < NBUCK; i += 256) { cs[i] = 0; cd[i] = 0; }
    __syncthreads();
    for (int e = e0 + threadIdx.x; e < eend; e += 256) {
        atomicAdd(&cs[src[e] >> 8], 1);
        atomicAdd(&cd[dst[e] >> 8], 1);
    }
    __syncthreads();
    for (int i = threadIdx.x; i < NBUCK; i += 256) {
        if (cs[i]) atomicAdd(&bcnt_s[i], cs[i]);
        if (cd[i]) atomicAdd(&bcnt_d[i], cd[i]);
    }
}

__global__ void bucket_scan_kernel(const int* __restrict__ bcnt_s, const int* __restrict__ bcnt_d,
                                   int* __restrict__ bbase_s, int* __restrict__ bbase_d,
                                   int* __restrict__ bcur_s, int* __restrict__ bcur_d,
                                   int* __restrict__ row_start_s, int* __restrict__ row_start_d) {
    __shared__ int lds[256];
    int v = (threadIdx.x < NBUCK) ? bcnt_s[threadIdx.x] : 0;
    lds[threadIdx.x] = v;
    __syncthreads();
    for (int off = 1; off < 256; off <<= 1) {
        int add = (threadIdx.x >= off) ? lds[threadIdx.x - off] : 0;
        __syncthreads();
        lds[threadIdx.x] += add;
        __syncthreads();
    }
    if (threadIdx.x < NBUCK) {
        int e = lds[threadIdx.x] - v;
        bbase_s[threadIdx.x] = e; bcur_s[threadIdx.x] = e;
    }
    if (threadIdx.x == 0) { bbase_s[NBUCK] = N_EDGES; row_start_s[N_NODES] = N_EDGES; }
    __syncthreads();
    int v2 = (threadIdx.x < NBUCK) ? bcnt_d[threadIdx.x] : 0;
    lds[threadIdx.x] = v2;
    __syncthreads();
    for (int off = 1; off < 256; off <<= 1) {
        int add = (threadIdx.x >= off) ? lds[threadIdx.x - off] : 0;
        __syncthreads();
        lds[threadIdx.x] += add;
        __syncthreads();
    }
    if (threadIdx.x < NBUCK) {
        int e = lds[threadIdx.x] - v2;
        bbase_d[threadIdx.x] = e; bcur_d[threadIdx.x] = e;
    }
    if (threadIdx.x == 0) { bbase_d[NBUCK] = N_EDGES; row_start_d[N_NODES] = N_EDGES; }
}

__global__ __launch_bounds__(256) void partition2_kernel(const int* __restrict__ src,
                                                         const int* __restrict__ dst,
                                                         int* __restrict__ bcur_s,
                                                         int* __restrict__ bcur_d,
                                                         unsigned* __restrict__ tmp_s,
                                                         unsigned* __restrict__ tmp_d) {
    __shared__ int cs[NBUCK], cd[NBUCK], bs[NBUCK], bd[NBUCK];
    int e0 = blockIdx.x * 8192;
    int eend = e0 + 8192; if (eend > N_EDGES) eend = N_EDGES;
    for (int i = threadIdx.x; i < NBUCK; i += 256) { cs[i] = 0; cd[i] = 0; }
    __syncthreads();
    for (int e = e0 + threadIdx.x; e < eend; e += 256) {
        atomicAdd(&cs[src[e] >> 8], 1);
        atomicAdd(&cd[dst[e] >> 8], 1);
    }
    __syncthreads();
    for (int i = threadIdx.x; i < NBUCK; i += 256) {
        int c = cs[i]; bs[i] = c ? atomicAdd(&bcur_s[i], c) : 0;
        c = cd[i];     bd[i] = c ? atomicAdd(&bcur_d[i], c) : 0;
    }
    __syncthreads();
    for (int e = e0 + threadIdx.x; e < eend; e += 256) {
        int s = src[e], d = dst[e];
        int ps = atomicAdd(&bs[s >> 8], 1);
        tmp_s[ps] = (unsigned)d | ((unsigned)(s & 255) << 16);
        int pd = atomicAdd(&bd[d >> 8], 1);
        tmp_d[pd] = (unsigned)s | ((unsigned)(d & 255) << 16);
    }
}

__global__ __launch_bounds__(256) void csr_finalize_kernel(const unsigned* __restrict__ tmp,
                                                           const int* __restrict__ bbase,
                                                           int* __restrict__ row_start,
                                                           int* __restrict__ csr_out) {
    __shared__ int cnt[256];
    __shared__ int cur[256];
    int b = blockIdx.x;
    int beg = bbase[b], end = bbase[b + 1];
    cnt[threadIdx.x] = 0;
    __syncthreads();
    for (int j = beg + threadIdx.x; j < end; j += 256)
        atomicAdd(&cnt[tmp[j] >> 16], 1);
    __syncthreads();
    int v = cnt[threadIdx.x];
    cur[threadIdx.x] = v;
    __syncthreads();
    for (int off = 1; off < 256; off <<= 1) {
        int add = (threadIdx.x >= off) ? cur[threadIdx.x - off] : 0;
        __syncthreads();
        cur[threadIdx.x] += add;
        __syncthreads();
    }
    int excl = cur[threadIdx.x] - v;
    int node = (b << 8) + threadIdx.x;
    if (node < N_NODES) row_start[node] = beg + excl;
    __syncthreads();
    cur[threadIdx.x] = beg + excl;
    __syncthreads();
    for (int j = beg + threadIdx.x; j < end; j += 256) {
        unsigned t = tmp[j];
        int pos = atomicAdd(&cur[t >> 16], 1);
        csr_out[pos] = (int)(t & 0xFFFFu);
    }
}

// ------------- two-phase sim, F=128, dst-major: int8 gathers as FILTER
//               (margin 0.05 > 0.0446 bound); exact fp32 recompute on accepts. -------------
__global__ void sim128_kernel(const float* __restrict__ x, const float* __restrict__ nrminv,
                              const uint2* __restrict__ xq2,
                              const int* __restrict__ row_start, const int* __restrict__ src_csr,
                              float* __restrict__ w_csr,
                              float* __restrict__ rowsum, float* __restrict__ degcnt) {
    int gid = blockIdx.x * blockDim.x + threadIdx.x;
    int node = gid / 16;
    int t = gid % 16;
    if (node >= N_NODES) return;
    float xd[8];
    {
        const float4* xr = (const float4*)(x + (size_t)node * 128) + t * 2;
        float4 v0 = xr[0], v1 = xr[1];
        float nd = nrminv[node];
        xd[0]=v0.x*nd; xd[1]=v0.y*nd; xd[2]=v0.z*nd; xd[3]=v0.w*nd;
        xd[4]=v1.x*nd; xd[5]=v1.y*nd; xd[6]=v1.z*nd; xd[7]=v1.w*nd;
    }
    int beg = row_start[node], end = row_start[node + 1];

    // filter threshold pre-scaled by 127: sim_est >= 0.45  <=>  acc >= 57.15
    const float THRQ = 57.15f;

    auto dot8q = [&](uint2 a) -> float {
        int w0 = (int)a.x, w1 = (int)a.y;
        float r;
        r  = xd[0] * (float)((w0 << 24) >> 24);
        r += xd[1] * (float)((w0 << 16) >> 24);
        r += xd[2] * (float)((w0 <<  8) >> 24);
        r += xd[3] * (float)( w0        >> 24);
        r += xd[4] * (float)((w1 << 24) >> 24);
        r += xd[5] * (float)((w1 << 16) >> 24);
        r += xd[6] * (float)((w1 <<  8) >> 24);
        r += xd[7] * (float)( w1        >> 24);
        return r;
    };
    auto exact = [&](int s) -> float {          // group-uniform call
        const float4* xs = (const float4*)(x + (size_t)s * 128) + t * 2;
        float4 u0 = xs[0], u1 = xs[1];
        float r = xd[0]*u0.x + xd[1]*u0.y + xd[2]*u0.z + xd[3]*u0.w
                + xd[4]*u1.x + xd[5]*u1.y + xd[6]*u1.z + xd[7]*u1.w;
        #pragma unroll
        for (int m = 8; m >= 1; m >>= 1) r += __shfl_xor(r, m);
        return r * nrminv[s];
    };

    int i = beg;
    for (; i + 3 < end; i += 4) {
        int ss[4]; uint2 aa[4]; float ac[4];
        #pragma unroll
        for (int k = 0; k < 4; k++) ss[k] = src_csr[i + k];
        #pragma unroll
        for (int k = 0; k < 4; k++) aa[k] = xq2[(size_t)ss[k] * 16 + t];
        #pragma unroll
        for (int k = 0; k < 4; k++) ac[k] = dot8q(aa[k]);
        #pragma unroll
        for (int m = 8; m >= 1; m >>= 1) {
            ac[0] += __shfl_xor(ac[0], m); ac[1] += __shfl_xor(ac[1], m);
            ac[2] += __shfl_xor(ac[2], m); ac[3] += __shfl_xor(ac[3], m);
        }
        float w[4];
        #pragma unroll
        for (int k = 0; k < 4; k++) {
            w[k] = 0.f;
            if (ss[k] != node && ac[k] >= THRQ) {
                float e = exact(ss[k]);
                if (e >= 0.5f) w[k] = e;
            }
        }
        if (t == 0) {
            #pragma unroll
            for (int k = 0; k < 4; k++) {
                w_csr[i + k] = w[k];
                if (w[k] != 0.f) { atomicAdd(&rowsum[ss[k]], w[k]); atomicAdd(&degcnt[ss[k]], 1.f); }
            }
        }
    }
    for (; i < end; i++) {
        int s0 = src_csr[i];
        uint2 a = xq2[(size_t)s0 * 16 + t];
        float a0 = dot8q(a);
        #pragma unroll
        for (int m = 8; m >= 1; m >>= 1) a0 += __shfl_xor(a0, m);
        float w0 = 0.f;
        if (s0 != node && a0 >= THRQ) { float e0 = exact(s0); if (e0 >= 0.5f) w0 = e0; }
        if (t == 0) {
            w_csr[i] = w0;
            if (w0 != 0.f) { atomicAdd(&rowsum[s0], w0); atomicAdd(&degcnt[s0], 1.f); }
        }
    }
}

// ------------- per node: L1-normalize row weights, dinv, selfw*dinv^2 (layers 0/1) -------------
__global__ void row_finalize_kernel(const int* __restrict__ row_start,
                                    const int* __restrict__ src_csr,
                                    const float* __restrict__ rowsum,
                                    const float* __restrict__ degcnt,
                                    float* __restrict__ w_csr,
                                    float* __restrict__ dinv, float* __restrict__ swd2) {
    int gid = blockIdx.x * blockDim.x + threadIdx.x;
    int node = gid / 16;
    int t = gid % 16;
    if (node >= N_NODES) return;
    int beg = row_start[node], end = row_start[node + 1];
    float sum = 0.f;
    for (int i = beg + t; i < end; i += 16) {
        float w = w_csr[i];
        if (w != 0.f) {
            float wn = w / rowsum[src_csr[i]];   // rowsum >= w > 0 here
            w_csr[i] = wn;
            sum += wn;
        }
    }
    #pragma unroll
    for (int m = 8; m >= 1; m >>= 1) sum += __shfl_xor(sum, m);
    if (t == 0) {
        float sw = 1.f / (degcnt[node] + 1.f);
        float dv = rsqrtf(sw + sum);             // deg2 = selfw + sum > 0 always
        dinv[node] = dv;
        swd2[node] = sw * dv * dv;
    }
}

// ------------- layer-2 pass A, src-major, TRANSPOSED: one lane per edge,
//               full 16-dot per lane (no per-edge shuffles), NO atomics -------------
__global__ void simA_kernel(const float* __restrict__ xn2,
                            const int* __restrict__ row_start_s, const int* __restrict__ dstp_csr,
                            float* __restrict__ rowsum, float* __restrict__ selfw) {
    int gid = blockIdx.x * blockDim.x + threadIdx.x;
    int node = gid / 16;
    int t = gid % 16;
    if (node >= N_NODES) return;
    const float4* xr = (const float4*)(xn2 + (size_t)node * 16);
    float4 r0 = xr[0], r1 = xr[1], r2 = xr[2], r3 = xr[3];   // broadcast within group
    int beg = row_start_s[node], end = row_start_s[node + 1];
    float sum = 0.f, cnt = 0.f;
    for (int i = beg + t; i < end; i += 16) {
        int d = dstp_csr[i];
        const float4* xs = (const float4*)(xn2 + (size_t)d * 16);
        float4 s0 = xs[0], s1 = xs[1], s2 = xs[2], s3 = xs[3];
        float a = r0.x*s0.x + r0.y*s0.y + r0.z*s0.z + r0.w*s0.w
                + r1.x*s1.x + r1.y*s1.y + r1.z*s1.z + r1.w*s1.w
                + r2.x*s2.x + r2.y*s2.y + r2.z*s2.z + r2.w*s2.w
                + r3.x*s3.x + r3.y*s3.y + r3.z*s3.z + r3.w*s3.w;
        if (d != node && a >= 0.5f) { sum += a; cnt += 1.f; }
    }
    #pragma unroll
    for (int m = 8; m >= 1; m >>= 1) { sum += __shfl_xor(sum, m); cnt += __shfl_xor(cnt, m); }
    if (t == 0) {
        rowsum[node] = sum;
        selfw[node] = 1.f / (cnt + 1.f);
    }
}

// ------------- layer-2 pass B, dst-major, TRANSPOSED: lane-per-edge sim (bitwise
//               identical dot expression to simA), normalize, coalesced w write,
//               per-row deg2 reduce, NO atomics -------------
__global__ void simB_kernel(const float* __restrict__ xn2,
                            const int* __restrict__ row_start_d, const int* __restrict__ src_csr,
                            const float* __restrict__ rowsum, const float* __restrict__ selfw,
                            float* __restrict__ w_csr,
                            float* __restrict__ dinv, float* __restrict__ swd2) {
    int gid = blockIdx.x * blockDim.x + threadIdx.x;
    int node = gid / 16;
    int t = gid % 16;
    if (node >= N_NODES) return;
    const float4* xr = (const float4*)(xn2 + (size_t)node * 16);
    float4 r0 = xr[0], r1 = xr[1], r2 = xr[2], r3 = xr[3];
    int beg = row_start_d[node], end = row_start_d[node + 1];
    float deg2 = 0.f;
    for (int i = beg + t; i < end; i += 16) {
        int s = src_csr[i];
        const float4* xs = (const float4*)(xn2 + (size_t)s * 16);
        float4 s0 = xs[0], s1 = xs[1], s2 = xs[2], s3 = xs[3];
        float a = r0.x*s0.x + r0.y*s0.y + r0.z*s0.z + r0.w*s0.w
                + r1.x*s1.x + r1.y*s1.y + r1.z*s1.z + r1.w*s1.w
                + r2.x*s2.x + r2.y*s2.y + r2.z*s2.z + r2.w*s2.w
                + r3.x*s3.x + r3.y*s3.y + r3.z*s3.z + r3.w*s3.w;
        float w = (s != node && a >= 0.5f) ? a / rowsum[s] : 0.f;
        w_csr[i] = w;                    // coalesced across lanes
        deg2 += w;
    }
    #pragma unroll
    for (int m = 8; m >= 1; m >>= 1) deg2 += __shfl_xor(deg2, m);
    if (t == 0) {
        float sw = selfw[node];
        float dv = rsqrtf(deg2 + sw);
        dinv[node] = dv;
        swd2[node] = sw * dv * dv;
    }
}

// ------------- tiled fp32 GEMM: h = x @ W -------------
template<int FIN, int FOUT, int TM, int KC, int RPT, int CPT>
__global__ __launch_bounds__(256) void gemm_tiled(const float* __restrict__ x,
                                                  const float* __restrict__ W,
                                                  float* __restrict__ h) {
    constexpr int COLG = FOUT / CPT;
    static_assert(COLG * (TM / RPT) == 256, "thread mapping");
    __shared__ float xT[KC][TM];
    __shared__ float Wl[KC][FOUT];
    int tid = threadIdx.x;
    int row0 = blockIdx.x * TM;
    int c0 = (tid % COLG) * CPT;
    int r0 = (tid / COLG) * RPT;
    float acc[RPT][CPT];
    #pragma unroll
    for (int r = 0; r < RPT; r++)
        #pragma unroll
        for (int c = 0; c < CPT; c++) acc[r][c] = 0.f;

    for (int kc = 0; kc < FIN; kc += KC) {
        constexpr int SLOTS_PER_ROW = KC / 4;
        constexpr int XQ = TM * KC / (256 * 4);
        #pragma unroll
        for (int j = 0; j < XQ; j++) {
            int idx = tid + j * 256;
            int tr = idx / SLOTS_PER_ROW;
            int tk = (idx % SLOTS_PER_ROW) * 4;
            int grow = row0 + tr;
            float4 v = make_float4(0.f, 0.f, 0.f, 0.f);
            if (grow < N_NODES) v = *(const float4*)(x + (size_t)grow * FIN + kc + tk);
            xT[tk + 0][tr] = v.x; xT[tk + 1][tr] = v.y;
            xT[tk + 2][tr] = v.z; xT[tk + 3][tr] = v.w;
        }
        if constexpr (KC * FOUT >= 1024) {
            constexpr int WQ = KC * FOUT / (256 * 4);
            #pragma unroll
            for (int j = 0; j < WQ; j++) {
                int idx = tid + j * 256;
                int wk = idx / (FOUT / 4);
                int wc = (idx % (FOUT / 4)) * 4;
                *(float4*)&Wl[wk][wc] = *(const float4*)(W + (size_t)(kc + wk) * FOUT + wc);
            }
        } else {
            Wl[tid / FOUT][tid % FOUT] = W[(size_t)(kc + tid / FOUT) * FOUT + tid % FOUT];
        }
        __syncthreads();

        #pragma unroll
        for (int k = 0; k < KC; k++) {
            float a[RPT];
            #pragma unroll
            for (int rr = 0; rr < RPT; rr += 4) {
                float4 xv = *(const float4*)&xT[k][r0 + rr];
                a[rr] = xv.x; a[rr+1] = xv.y; a[rr+2] = xv.z; a[rr+3] = xv.w;
            }
            if constexpr (CPT == 4) {
                float4 wv = *(const float4*)&Wl[k][c0];
                #pragma unroll
                for (int rr = 0; rr < RPT; rr++) {
                    acc[rr][0] += a[rr] * wv.x; acc[rr][1] += a[rr] * wv.y;
                    acc[rr][2] += a[rr] * wv.z; acc[rr][3] += a[rr] * wv.w;
                }
            } else {
                float wv = Wl[k][c0];
                #pragma unroll
                for (int rr = 0; rr < RPT; rr++) acc[rr][0] += a[rr] * wv;
            }
        }
        __syncthreads();
    }

    #pragma unroll
    for (int rr = 0; rr < RPT; rr++) {
        int grow = row0 + r0 + rr;
        if (grow < N_NODES) {
            if constexpr (CPT == 4) {
                float4 o = make_float4(acc[rr][0], acc[rr][1], acc[rr][2], acc[rr][3]);
                *(float4*)(h + (size_t)grow * FOUT + c0) = o;
            } else {
                h[(size_t)grow * FOUT + c0] = acc[rr][0];
            }
        }
    }
}

// ------------- gather conv FOUT=128 (fp32 w); ReLU+bias fused -------------
__global__ void conv_gather128_kernel(const int* __restrict__ row_start,
                                      const int* __restrict__ src_csr,
                                      const float* __restrict__ w_csr,
                                      const float* __restrict__ dinv,
                                      const float* __restrict__ swd2,
                                      const float* __restrict__ h,
                                      const float* __restrict__ b,
                                      float* __restrict__ out) {
    constexpr int TPN = 32;
    int gid = blockIdx.x * blockDim.x + threadIdx.x;
    int node = gid / TPN;
    int t = gid % TPN;
    if (node >= N_NODES) return;
    int beg = row_start[node], end = row_start[node + 1];
    float dv = dinv[node];
    float4 acc = make_float4(0.f, 0.f, 0.f, 0.f);
    for (int base = beg; base < end; base += TPN) {
        int i = base + t;
        float wv = 0.f; int sv = 0;
        if (i < end) {
            wv = w_csr[i];
            sv = src_csr[i];
            if (wv != 0.f) wv *= dinv[sv];       // fold dinv[src]
        }
        int cnt = end - base; if (cnt > TPN) cnt = TPN;
        #pragma unroll
        for (int j = 0; j < TPN; j++) {
            if (j >= cnt) break;
            float w = __shfl(wv, j, TPN);
            int   s = __shfl(sv, j, TPN);
            if (w != 0.f) {
                float coeff = w * dv;
                float4 hv = *(const float4*)(h + (size_t)s * 128 + t * 4);
                acc.x += coeff * hv.x; acc.y += coeff * hv.y;
                acc.z += coeff * hv.z; acc.w += coeff * hv.w;
            }
        }
    }
    float sd = swd2[node];
    float4 hv = *(const float4*)(h + (size_t)node * 128 + t * 4);
    float4 bv = *(const float4*)(b + t * 4);
    acc.x = fmaxf(acc.x + sd * hv.x + bv.x, 0.f);
    acc.y = fmaxf(acc.y + sd * hv.y + bv.y, 0.f);
    acc.z = fmaxf(acc.z + sd * hv.z + bv.z, 0.f);
    acc.w = fmaxf(acc.w + sd * hv.w + bv.w, 0.f);
    *(float4*)(out + (size_t)node * 128 + t * 4) = acc;
}

// ------------- gather conv F=16 (fp32 w); optional bias/relu + normalized fp32 row out -------------
template<bool BIAS_RELU, bool WNORM>
__global__ void conv_gather16_kernel(const int* __restrict__ row_start,
                                     const int* __restrict__ src_csr,
                                     const float* __restrict__ w_csr,
                                     const float* __restrict__ dinv,
                                     const float* __restrict__ swd2,
                                     const float* __restrict__ h,
                                     const float* __restrict__ b,
                                     float* __restrict__ out,
                                     float* __restrict__ xn_out) {
    constexpr int TPN = 16;
    int gid = blockIdx.x * blockDim.x + threadIdx.x;
    int node = gid / TPN;
    int t = gid % TPN;
    if (node >= N_NODES) return;
    int beg = row_start[node], end = row_start[node + 1];
    float dv = dinv[node];
    float acc = 0.f;
    for (int base = beg; base < end; base += TPN) {
        int i = base + t;
        float wv = 0.f; int sv = 0;
        if (i < end) {
            wv = w_csr[i];
            sv = src_csr[i];
            if (wv != 0.f) wv *= dinv[sv];
        }
        int cnt = end - base; if (cnt > TPN) cnt = TPN;
        #pragma unroll
        for (int j = 0; j < TPN; j++) {
            if (j >= cnt) break;
            float w = __shfl(wv, j, TPN);
            int   s = __shfl(sv, j, TPN);
            if (w != 0.f) acc += (w * dv) * h[(size_t)s * 16 + t];
        }
    }
    float v = acc + swd2[node] * h[(size_t)node * 16 + t];
    if (BIAS_RELU) v = fmaxf(v + b[t], 0.f);
    out[(size_t)node * 16 + t] = v;
    if (WNORM) {
        float ss = v * v;
        #pragma unroll
        for (int m = TPN/2; m >= 1; m >>= 1) ss += __shfl_xor(ss, m);
        float n = sqrtf(ss);
        float ni = (n == 0.f) ? 1.f : 1.f / n;
        xn_out[(size_t)node * 16 + t] = v * ni;
    }
}

// ------------- fused: out40 = agg16 @ W3 + b3, then log_softmax. One wave/node. -------------
__global__ void final_kernel(const float* __restrict__ agg16,
                             const float* __restrict__ W3, const float* __restrict__ b3,
                             float* __restrict__ out) {
    __shared__ float Wl[16 * 40];
    __shared__ float bl[40];
    for (int i = threadIdx.x; i < 16 * 40; i += blockDim.x) Wl[i] = W3[i];
    if (threadIdx.x < 40) bl[threadIdx.x] = b3[threadIdx.x];
    __syncthreads();
    int wid = threadIdx.x / 64;
    int lane = threadIdx.x % 64;
    int v = blockIdx.x * 4 + wid;
    if (v >= N_NODES) return;
    const float* ar = agg16 + (size_t)v * 16;
    float o = -INFINITY;
    if (lane < 40) {
        o = bl[lane];
        #pragma unroll
        for (int k = 0; k < 16; k++) o += ar[k] * Wl[k * 40 + lane];
    }
    float m = o;
    #pragma unroll
    for (int s = 32; s >= 1; s >>= 1) m = fmaxf(m, __shfl_xor(m, s));
    float ex = (lane < 40) ? expf(o - m) : 0.f;
    float sum = ex;
    #pragma unroll
    for (int s = 32; s >= 1; s >>= 1) sum += __shfl_xor(sum, s);
    float lse = m + logf(sum);
    if (lane < 40) out[(size_t)v * 40 + lane] = o - lse;
}

// =================== host orchestration ===================
extern "C" void kernel_launch(void* const* d_in, const int* in_sizes, int n_in,
                              void* d_out, int out_size, void* d_ws, size_t ws_size,
                              hipStream_t stream) {
    const float* x0 = (const float*)d_in[0];
    const int* ei   = (const int*)d_in[1];
    const int* src  = ei;
    const int* dst  = ei + N_EDGES;
    const float* W1 = (const float*)d_in[2];
    const float* b1 = (const float*)d_in[3];
    const float* W2 = (const float*)d_in[4];
    const float* b2 = (const float*)d_in[5];
    const float* W3 = (const float*)d_in[6];
    const float* b3 = (const float*)d_in[7];
    float* out = (float*)d_out;

    // workspace ~73 MB. Aliases (disjoint lifetimes):
    //   tmp_s/tmp_d alias xbuf1[0..3.2M) (dead before conv128 writes xbuf1)
    //   xq2 (int8 table, 1.6M slots) / agg16 / xn2 / xbuf2 alias inside h
    //   (xq2 dies before each gemm writes h)
    float* ws     = (float*)d_ws;
    float* xbuf1  = ws;                        // 6,400,000
    unsigned* tmp_s = (unsigned*)xbuf1;        // alias: 1.6M
    unsigned* tmp_d = (unsigned*)xbuf1 + N_EDGES; // alias: 1.6M
    float* h      = xbuf1 + 6400000;           // 6,400,000
    uint2* xq2    = (uint2*)h;                 // alias: h[0..1.6M slots) as int8 rows
    float* agg16  = h;                         // alias
    float* xn2    = h + 800000;                // alias
    float* xbuf2  = h + 1600000;               // alias
    float* w_csr  = h + 6400000;               // 1,600,000 (fp32)
    float* nrminv = w_csr + 1600000;           // 50,000
    float* dinv   = nrminv + 50000;            // 50,000
    float* swd2   = dinv + 50000;              // 50,000
    float* rowsum2 = swd2 + 50000;             // 50,000 (layer 2, fully written)
    float* selfw2  = rowsum2 + 50000;          // 50,000
    int* zr        = (int*)(selfw2 + 50000);   // zero region
    float* rs0     = (float*)zr;               // 50,000
    float* dc0     = rs0 + 50000;
    float* rs1     = dc0 + 50000;
    float* dc1     = rs1 + 50000;
    int* bcnt_s    = (int*)(dc1 + 50000);      // 256
    int* bcnt_d    = bcnt_s + 256;             // 256  (end of zero region)
    int* bbase_s   = bcnt_d + 256;             // 257
    int* bbase_d   = bbase_s + 257;            // 257
    int* bcur_s    = bbase_d + 257;            // 256
    int* bcur_d    = bcur_s + 256;             // 256
    int* row_start_d = bcur_d + 256;           // 50,001
    int* row_start_s = row_start_d + 50001;    // 50,001
    int* src_csr   = row_start_s + 50001;      // 1,600,000 (by-dst payload = src)
    int* dstp_csr  = src_csr + N_EDGES;        // 1,600,000 (by-src payload = dst)

    const int BS = 256;

    // ---- one memset zeroes rowsum/degcnt pairs (L0,L1) + bucket counters ----
    hipMemsetAsync(zr, 0, (200000 + 512) * sizeof(int), stream);

    // ---- CSR build, both directions ----
    bucket_count_kernel<<<(N_EDGES + 8191) / 8192, BS, 0, stream>>>(src, dst, bcnt_s, bcnt_d);
    bucket_scan_kernel<<<1, BS, 0, stream>>>(bcnt_s, bcnt_d, bbase_s, bbase_d,
                                             bcur_s, bcur_d, row_start_s, row_start_d);
    partition2_kernel<<<(N_EDGES + 8191) / 8192, BS, 0, stream>>>(src, dst, bcur_s, bcur_d,
                                                                  tmp_s, tmp_d);
    csr_finalize_kernel<<<NBUCK, BS, 0, stream>>>(tmp_d, bbase_d, row_start_d, src_csr);
    csr_finalize_kernel<<<NBUCK, BS, 0, stream>>>(tmp_s, bbase_s, row_start_s, dstp_csr);

    // ================= Layer 0: 128 -> 128, ReLU =================
    norm_pack_kernel<<<(N_NODES * 16 + BS - 1) / BS, BS, 0, stream>>>(x0, nrminv, xq2);
    sim128_kernel<<<(N_NODES * 16 + BS - 1) / BS, BS, 0, stream>>>(
        x0, nrminv, xq2, row_start_d, src_csr, w_csr, rs0, dc0);
    row_finalize_kernel<<<(N_NODES * 16 + BS - 1) / BS, BS, 0, stream>>>(
        row_start_d, src_csr, rs0, dc0, w_csr, dinv, swd2);
    gemm_tiled<128, 128, 64, 16, 8, 4><<<(N_NODES + 63) / 64, BS, 0, stream>>>(x0, W1, h);
    conv_gather128_kernel<<<(N_NODES * 32 + BS - 1) / BS, BS, 0, stream>>>(
        row_start_d, src_csr, w_csr, dinv, swd2, h, b1, xbuf1);

    // ================= Layer 1: 128 -> 16, ReLU =================
    norm_pack_kernel<<<(N_NODES * 16 + BS - 1) / BS, BS, 0, stream>>>(xbuf1, nrminv, xq2);
    sim128_kernel<<<(N_NODES * 16 + BS - 1) / BS, BS, 0, stream>>>(
        xbuf1, nrminv, xq2, row_start_d, src_csr, w_csr, rs1, dc1);
    row_finalize_kernel<<<(N_NODES * 16 + BS - 1) / BS, BS, 0, stream>>>(
        row_start_d, src_csr, rs1, dc1, w_csr, dinv, swd2);
    gemm_tiled<128, 16, 128, 16, 8, 1><<<(N_NODES + 127) / 128, BS, 0, stream>>>(xbuf1, W2, h);
    conv_gather16_kernel<true, true><<<(N_NODES * 16 + BS - 1) / BS, BS, 0, stream>>>(
        row_start_d, src_csr, w_csr, dinv, swd2, h, b2, xbuf2, xn2);

    // ========== Layer 2: 16 -> 40 (atomic-free two-pass sim, aggregate, fused GEMM+LSM) ====
    simA_kernel<<<(N_NODES * 16 + BS - 1) / BS, BS, 0, stream>>>(
        xn2, row_start_s, dstp_csr, rowsum2, selfw2);
    simB_kernel<<<(N_NODES * 16 + BS - 1) / BS, BS, 0, stream>>>(
        xn2, row_start_d, src_csr, rowsum2, selfw2, w_csr, dinv, swd2);
    conv_gather16_kernel<false, false><<<(N_NODES * 16 + BS - 1) / BS, BS, 0, stream>>>(
        row_start_d, src_csr, w_csr, dinv, swd2, xbuf2, b3 /*unused*/, agg16, nullptr);
    final_kernel<<<(N_NODES + 3) / 4, BS, 0, stream>>>(agg16, W3, b3, out);
}

// Round 12
// 477.135 us; speedup vs baseline: 1.7562x; 1.0012x over previous
//
#include <hip/hip_runtime.h>
#include <math.h>

#define N_NODES 50000
#define N_EDGES 1600000
#define NBUCK ((N_NODES + 255) >> 8)   // 196 buckets of 256 nodes

#if defined(__has_builtin)
#if __has_builtin(__builtin_amdgcn_sdot4)
#define HAS_SDOT4 1
#endif
#endif

// ---------------- norm + pack normalized int8 row (F=128) ----------------
// 16 lanes/node, lane t covers elems [t*8, t*8+8); 8 int8 -> uint2 per lane.
// q = rint(127 * x/||x||), |q| <= 127. Mixed-filter bound: sqrt(128)*0.5/127 = 0.0446.
// int8xint8 bound: 2*0.0446 + 128*0.25/127^2 = 0.0911 -> integer threshold 6596.
__global__ void norm_pack_kernel(const float* __restrict__ x, float* __restrict__ nrminv,
                                 uint2* __restrict__ xq2) {
    int gid = blockIdx.x * blockDim.x + threadIdx.x;
    int node = gid / 16;
    int t = gid % 16;
    if (node >= N_NODES) return;
    const float4* xr = (const float4*)(x + (size_t)node * 128) + t * 2;
    float4 v0 = xr[0], v1 = xr[1];
    float ss = v0.x*v0.x + v0.y*v0.y + v0.z*v0.z + v0.w*v0.w
             + v1.x*v1.x + v1.y*v1.y + v1.z*v1.z + v1.w*v1.w;
    #pragma unroll
    for (int m = 8; m >= 1; m >>= 1) ss += __shfl_xor(ss, m);
    float n = sqrtf(ss);
    float ni = (n == 0.f) ? 1.f : 1.f / n;
    if (t == 0) nrminv[node] = ni;
    float sc = ni * 127.f;
    int q0 = __float2int_rn(v0.x * sc), q1 = __float2int_rn(v0.y * sc);
    int q2 = __float2int_rn(v0.z * sc), q3 = __float2int_rn(v0.w * sc);
    int q4 = __float2int_rn(v1.x * sc), q5 = __float2int_rn(v1.y * sc);
    int q6 = __float2int_rn(v1.z * sc), q7 = __float2int_rn(v1.w * sc);
    uint2 p;
    p.x = (unsigned)(q0 & 255) | ((unsigned)(q1 & 255) << 8) |
          ((unsigned)(q2 & 255) << 16) | ((unsigned)(q3 & 255) << 24);
    p.y = (unsigned)(q4 & 255) | ((unsigned)(q5 & 255) << 8) |
          ((unsigned)(q6 & 255) << 16) | ((unsigned)(q7 & 255) << 24);
    xq2[(size_t)node * 16 + t] = p;
}

// =================== CSR build, both directions, bucket radix ===================
__global__ __launch_bounds__(256) void bucket_count_kernel(const int* __restrict__ src,
                                                           const int* __restrict__ dst,
                                                           int* __restrict__ bcnt_s,
                                                           int* __restrict__ bcnt_d) {
    __shared__ int cs[NBUCK], cd[NBUCK];
    int e0 = blockIdx.x * 8192;
    int eend = e0 + 8192; if (eend > N_EDGES) eend = N_EDGES;
    for (int i = threadIdx.x; i < NBUCK; i += 256) { cs[i] = 0; cd[i] = 0; }
    __syncthreads();
    for (int e = e0 + threadIdx.x; e < eend; e += 256) {
        atomicAdd(&cs[src[e] >> 8], 1);
        atomicAdd(&cd[dst[e] >> 8], 1);
    }
    __syncthreads();
    for (int i = threadIdx.x; i < NBUCK; i += 256) {
        if (cs[i]) atomicAdd(&bcnt_s[i], cs[i]);
        if (cd[i]) atomicAdd(&bcnt_d[i], cd[i]);
    }
}

__global__ void bucket_scan_kernel(const int* __restrict__ bcnt_s, const int* __restrict__ bcnt_d,
                                   int* __restrict__ bbase_s, int* __restrict__ bbase_d,
                                   int* __restrict__ bcur_s, int* __restrict__ bcur_d,
                                   int* __restrict__ row_start_s, int* __restrict__ row_start_d) {
    __shared__ int lds[256];
    int v = (threadIdx.x < NBUCK) ? bcnt_s[threadIdx.x] : 0;
    lds[threadIdx.x] = v;
    __syncthreads();
    for (int off = 1; off < 256; off <<= 1) {
        int add = (threadIdx.x >= off) ? lds[threadIdx.x - off] : 0;
        __syncthreads();
        lds[threadIdx.x] += add;
        __syncthreads();
    }
    if (threadIdx.x < NBUCK) {
        int e = lds[threadIdx.x] - v;
        bbase_s[threadIdx.x] = e; bcur_s[threadIdx.x] = e;
    }
    if (threadIdx.x == 0) { bbase_s[NBUCK] = N_EDGES; row_start_s[N_NODES] = N_EDGES; }
    __syncthreads();
    int v2 = (threadIdx.x < NBUCK) ? bcnt_d[threadIdx.x] : 0;
    lds[threadIdx.x] = v2;
    __syncthreads();
    for (int off = 1; off < 256; off <<= 1) {
        int add = (threadIdx.x >= off) ? lds[threadIdx.x - off] : 0;
        __syncthreads();
        lds[threadIdx.x] += add;
        __syncthreads();
    }
    if (threadIdx.x < NBUCK) {
        int e = lds[threadIdx.x] - v2;
        bbase_d[threadIdx.x] = e; bcur_d[threadIdx.x] = e;
    }
    if (threadIdx.x == 0) { bbase_d[NBUCK] = N_EDGES; row_start_d[N_NODES] = N_EDGES; }
}

__global__ __launch_bounds__(256) void partition2_kernel(const int* __restrict__ src,
                                                         const int* __restrict__ dst,
                                                         int* __restrict__ bcur_s,
                                                         int* __restrict__ bcur_d,
                                                         unsigned* __restrict__ tmp_s,
                                                         unsigned* __restrict__ tmp_d) {
    __shared__ int cs[NBUCK], cd[NBUCK], bs[NBUCK], bd[NBUCK];
    int e0 = blockIdx.x * 8192;
    int eend = e0 + 8192; if (eend > N_EDGES) eend = N_EDGES;
    for (int i = threadIdx.x; i < NBUCK; i += 256) { cs[i] = 0; cd[i] = 0; }
    __syncthreads();
    for (int e = e0 + threadIdx.x; e < eend; e += 256) {
        atomicAdd(&cs[src[e] >> 8], 1);
        atomicAdd(&cd[dst[e] >> 8], 1);
    }
    __syncthreads();
    for (int i = threadIdx.x; i < NBUCK; i += 256) {
        int c = cs[i]; bs[i] = c ? atomicAdd(&bcur_s[i], c) : 0;
        c = cd[i];     bd[i] = c ? atomicAdd(&bcur_d[i], c) : 0;
    }
    __syncthreads();
    for (int e = e0 + threadIdx.x; e < eend; e += 256) {
        int s = src[e], d = dst[e];
        int ps = atomicAdd(&bs[s >> 8], 1);
        tmp_s[ps] = (unsigned)d | ((unsigned)(s & 255) << 16);
        int pd = atomicAdd(&bd[d >> 8], 1);
        tmp_d[pd] = (unsigned)s | ((unsigned)(d & 255) << 16);
    }
}

__global__ __launch_bounds__(256) void csr_finalize_kernel(const unsigned* __restrict__ tmp,
                                                           const int* __restrict__ bbase,
                                                           int* __restrict__ row_start,
                                                           int* __restrict__ csr_out) {
    __shared__ int cnt[256];
    __shared__ int cur[256];
    int b = blockIdx.x;
    int beg = bbase[b], end = bbase[b + 1];
    cnt[threadIdx.x] = 0;
    __syncthreads();
    for (int j = beg + threadIdx.x; j < end; j += 256)
        atomicAdd(&cnt[tmp[j] >> 16], 1);
    __syncthreads();
    int v = cnt[threadIdx.x];
    cur[threadIdx.x] = v;
    __syncthreads();
    for (int off = 1; off < 256; off <<= 1) {
        int add = (threadIdx.x >= off) ? cur[threadIdx.x - off] : 0;
        __syncthreads();
        cur[threadIdx.x] += add;
        __syncthreads();
    }
    int excl = cur[threadIdx.x] - v;
    int node = (b << 8) + threadIdx.x;
    if (node < N_NODES) row_start[node] = beg + excl;
    __syncthreads();
    cur[threadIdx.x] = beg + excl;
    __syncthreads();
    for (int j = beg + threadIdx.x; j < end; j += 256) {
        unsigned t = tmp[j];
        int pos = atomicAdd(&cur[t >> 16], 1);
        csr_out[pos] = (int)(t & 0xFFFFu);
    }
}

// ------------- three-stage sim, F=128, dst-major:
//   stage 1: int8 x int8 sdot (A >= 6596, bound 0.0911) — 2 VALU ops/lane/edge
//   stage 2: fp32-dst x decoded-int8 (>= 0.45, bound 0.0446) — registers only
//   stage 3: exact fp32 recompute — supplies the weight (identical accept set to fp32)
__global__ void sim128_kernel(const float* __restrict__ x, const float* __restrict__ nrminv,
                              const uint2* __restrict__ xq2,
                              const int* __restrict__ row_start, const int* __restrict__ src_csr,
                              float* __restrict__ w_csr,
                              float* __restrict__ rowsum, float* __restrict__ degcnt) {
    int gid = blockIdx.x * blockDim.x + threadIdx.x;
    int node = gid / 16;
    int t = gid % 16;
    if (node >= N_NODES) return;
    float xd[8];
    {
        const float4* xr = (const float4*)(x + (size_t)node * 128) + t * 2;
        float4 v0 = xr[0], v1 = xr[1];
        float nd = nrminv[node];
        xd[0]=v0.x*nd; xd[1]=v0.y*nd; xd[2]=v0.z*nd; xd[3]=v0.w*nd;
        xd[4]=v1.x*nd; xd[5]=v1.y*nd; xd[6]=v1.z*nd; xd[7]=v1.w*nd;
    }
#ifdef HAS_SDOT4
    uint2 qd = xq2[(size_t)node * 16 + t];      // dst int8 row (for stage-1)
#endif
    int beg = row_start[node], end = row_start[node + 1];

    // stage-2 threshold pre-scaled by 127: sim_est >= 0.45  <=>  acc >= 57.15
    const float THRQ = 57.15f;

    auto dot8q = [&](uint2 a) -> float {
        int w0 = (int)a.x, w1 = (int)a.y;
        float r;
        r  = xd[0] * (float)((w0 << 24) >> 24);
        r += xd[1] * (float)((w0 << 16) >> 24);
        r += xd[2] * (float)((w0 <<  8) >> 24);
        r += xd[3] * (float)( w0        >> 24);
        r += xd[4] * (float)((w1 << 24) >> 24);
        r += xd[5] * (float)((w1 << 16) >> 24);
        r += xd[6] * (float)((w1 <<  8) >> 24);
        r += xd[7] * (float)( w1        >> 24);
        return r;
    };
    auto exact = [&](int s) -> float {          // group-uniform call
        const float4* xs = (const float4*)(x + (size_t)s * 128) + t * 2;
        float4 u0 = xs[0], u1 = xs[1];
        float r = xd[0]*u0.x + xd[1]*u0.y + xd[2]*u0.z + xd[3]*u0.w
                + xd[4]*u1.x + xd[5]*u1.y + xd[6]*u1.z + xd[7]*u1.w;
        #pragma unroll
        for (int m = 8; m >= 1; m >>= 1) r += __shfl_xor(r, m);
        return r * nrminv[s];
    };
#ifdef HAS_SDOT4
    auto mixed = [&](uint2 a) -> float {        // group-uniform call (stage 2)
        float r = dot8q(a);
        #pragma unroll
        for (int m = 8; m >= 1; m >>= 1) r += __shfl_xor(r, m);
        return r;
    };
#endif

    int i = beg;
    for (; i + 3 < end; i += 4) {
        int ss[4]; uint2 aa[4];
        #pragma unroll
        for (int k = 0; k < 4; k++) ss[k] = src_csr[i + k];
        #pragma unroll
        for (int k = 0; k < 4; k++) aa[k] = xq2[(size_t)ss[k] * 16 + t];
        float w[4];
#ifdef HAS_SDOT4
        int A[4];
        #pragma unroll
        for (int k = 0; k < 4; k++)
            A[k] = __builtin_amdgcn_sdot4((int)qd.x, (int)aa[k].x,
                     __builtin_amdgcn_sdot4((int)qd.y, (int)aa[k].y, 0, false), false);
        #pragma unroll
        for (int m = 8; m >= 1; m >>= 1) {
            A[0] += __shfl_xor(A[0], m); A[1] += __shfl_xor(A[1], m);
            A[2] += __shfl_xor(A[2], m); A[3] += __shfl_xor(A[3], m);
        }
        #pragma unroll
        for (int k = 0; k < 4; k++) {
            w[k] = 0.f;
            if (ss[k] != node && A[k] >= 6596) {
                if (mixed(aa[k]) >= THRQ) {
                    float e = exact(ss[k]);
                    if (e >= 0.5f) w[k] = e;
                }
            }
        }
#else
        float ac[4];
        #pragma unroll
        for (int k = 0; k < 4; k++) ac[k] = dot8q(aa[k]);
        #pragma unroll
        for (int m = 8; m >= 1; m >>= 1) {
            ac[0] += __shfl_xor(ac[0], m); ac[1] += __shfl_xor(ac[1], m);
            ac[2] += __shfl_xor(ac[2], m); ac[3] += __shfl_xor(ac[3], m);
        }
        #pragma unroll
        for (int k = 0; k < 4; k++) {
            w[k] = 0.f;
            if (ss[k] != node && ac[k] >= THRQ) {
                float e = exact(ss[k]);
                if (e >= 0.5f) w[k] = e;
            }
        }
#endif
        if (t == 0) {
            #pragma unroll
            for (int k = 0; k < 4; k++) {
                w_csr[i + k] = w[k];
                if (w[k] != 0.f) { atomicAdd(&rowsum[ss[k]], w[k]); atomicAdd(&degcnt[ss[k]], 1.f); }
            }
        }
    }
    for (; i < end; i++) {
        int s0 = src_csr[i];
        uint2 a = xq2[(size_t)s0 * 16 + t];
        float w0 = 0.f;
#ifdef HAS_SDOT4
        int A0 = __builtin_amdgcn_sdot4((int)qd.x, (int)a.x,
                   __builtin_amdgcn_sdot4((int)qd.y, (int)a.y, 0, false), false);
        #pragma unroll
        for (int m = 8; m >= 1; m >>= 1) A0 += __shfl_xor(A0, m);
        if (s0 != node && A0 >= 6596) {
            if (mixed(a) >= THRQ) {
                float e0 = exact(s0);
                if (e0 >= 0.5f) w0 = e0;
            }
        }
#else
        float a0 = dot8q(a);
        #pragma unroll
        for (int m = 8; m >= 1; m >>= 1) a0 += __shfl_xor(a0, m);
        if (s0 != node && a0 >= THRQ) { float e0 = exact(s0); if (e0 >= 0.5f) w0 = e0; }
#endif
        if (t == 0) {
            w_csr[i] = w0;
            if (w0 != 0.f) { atomicAdd(&rowsum[s0], w0); atomicAdd(&degcnt[s0], 1.f); }
        }
    }
}

// ------------- per node: L1-normalize row weights, dinv, selfw*dinv^2 (layers 0/1) -------------
__global__ void row_finalize_kernel(const int* __restrict__ row_start,
                                    const int* __restrict__ src_csr,
                                    const float* __restrict__ rowsum,
                                    const float* __restrict__ degcnt,
                                    float* __restrict__ w_csr,
                                    float* __restrict__ dinv, float* __restrict__ swd2) {
    int gid = blockIdx.x * blockDim.x + threadIdx.x;
    int node = gid / 16;
    int t = gid % 16;
    if (node >= N_NODES) return;
    int beg = row_start[node], end = row_start[node + 1];
    float sum = 0.f;
    for (int i = beg + t; i < end; i += 16) {
        float w = w_csr[i];
        if (w != 0.f) {
            float wn = w / rowsum[src_csr[i]];   // rowsum >= w > 0 here
            w_csr[i] = wn;
            sum += wn;
        }
    }
    #pragma unroll
    for (int m = 8; m >= 1; m >>= 1) sum += __shfl_xor(sum, m);
    if (t == 0) {
        float sw = 1.f / (degcnt[node] + 1.f);
        float dv = rsqrtf(sw + sum);             // deg2 = selfw + sum > 0 always
        dinv[node] = dv;
        swd2[node] = sw * dv * dv;
    }
}

// ------------- layer-2 pass A, src-major, TRANSPOSED: one lane per edge, NO atomics -------------
__global__ void simA_kernel(const float* __restrict__ xn2,
                            const int* __restrict__ row_start_s, const int* __restrict__ dstp_csr,
                            float* __restrict__ rowsum, float* __restrict__ selfw) {
    int gid = blockIdx.x * blockDim.x + threadIdx.x;
    int node = gid / 16;
    int t = gid % 16;
    if (node >= N_NODES) return;
    const float4* xr = (const float4*)(xn2 + (size_t)node * 16);
    float4 r0 = xr[0], r1 = xr[1], r2 = xr[2], r3 = xr[3];
    int beg = row_start_s[node], end = row_start_s[node + 1];
    float sum = 0.f, cnt = 0.f;
    for (int i = beg + t; i < end; i += 16) {
        int d = dstp_csr[i];
        const float4* xs = (const float4*)(xn2 + (size_t)d * 16);
        float4 s0 = xs[0], s1 = xs[1], s2 = xs[2], s3 = xs[3];
        float a = r0.x*s0.x + r0.y*s0.y + r0.z*s0.z + r0.w*s0.w
                + r1.x*s1.x + r1.y*s1.y + r1.z*s1.z + r1.w*s1.w
                + r2.x*s2.x + r2.y*s2.y + r2.z*s2.z + r2.w*s2.w
                + r3.x*s3.x + r3.y*s3.y + r3.z*s3.z + r3.w*s3.w;
        if (d != node && a >= 0.5f) { sum += a; cnt += 1.f; }
    }
    #pragma unroll
    for (int m = 8; m >= 1; m >>= 1) { sum += __shfl_xor(sum, m); cnt += __shfl_xor(cnt, m); }
    if (t == 0) {
        rowsum[node] = sum;
        selfw[node] = 1.f / (cnt + 1.f);
    }
}

// ------------- layer-2 pass B, dst-major, TRANSPOSED: lane-per-edge sim, NO atomics -------------
__global__ void simB_kernel(const float* __restrict__ xn2,
                            const int* __restrict__ row_start_d, const int* __restrict__ src_csr,
                            const float* __restrict__ rowsum, const float* __restrict__ selfw,
                            float* __restrict__ w_csr,
                            float* __restrict__ dinv, float* __restrict__ swd2) {
    int gid = blockIdx.x * blockDim.x + threadIdx.x;
    int node = gid / 16;
    int t = gid % 16;
    if (node >= N_NODES) return;
    const float4* xr = (const float4*)(xn2 + (size_t)node * 16);
    float4 r0 = xr[0], r1 = xr[1], r2 = xr[2], r3 = xr[3];
    int beg = row_start_d[node], end = row_start_d[node + 1];
    float deg2 = 0.f;
    for (int i = beg + t; i < end; i += 16) {
        int s = src_csr[i];
        const float4* xs = (const float4*)(xn2 + (size_t)s * 16);
        float4 s0 = xs[0], s1 = xs[1], s2 = xs[2], s3 = xs[3];
        float a = r0.x*s0.x + r0.y*s0.y + r0.z*s0.z + r0.w*s0.w
                + r1.x*s1.x + r1.y*s1.y + r1.z*s1.z + r1.w*s1.w
                + r2.x*s2.x + r2.y*s2.y + r2.z*s2.z + r2.w*s2.w
                + r3.x*s3.x + r3.y*s3.y + r3.z*s3.z + r3.w*s3.w;
        float w = (s != node && a >= 0.5f) ? a / rowsum[s] : 0.f;
        w_csr[i] = w;
        deg2 += w;
    }
    #pragma unroll
    for (int m = 8; m >= 1; m >>= 1) deg2 += __shfl_xor(deg2, m);
    if (t == 0) {
        float sw = selfw[node];
        float dv = rsqrtf(deg2 + sw);
        dinv[node] = dv;
        swd2[node] = sw * dv * dv;
    }
}

// ------------- tiled fp32 GEMM: h = x @ W -------------
template<int FIN, int FOUT, int TM, int KC, int RPT, int CPT>
__global__ __launch_bounds__(256) void gemm_tiled(const float* __restrict__ x,
                                                  const float* __restrict__ W,
                                                  float* __restrict__ h) {
    constexpr int COLG = FOUT / CPT;
    static_assert(COLG * (TM / RPT) == 256, "thread mapping");
    __shared__ float xT[KC][TM];
    __shared__ float Wl[KC][FOUT];
    int tid = threadIdx.x;
    int row0 = blockIdx.x * TM;
    int c0 = (tid % COLG) * CPT;
    int r0 = (tid / COLG) * RPT;
    float acc[RPT][CPT];
    #pragma unroll
    for (int r = 0; r < RPT; r++)
        #pragma unroll
        for (int c = 0; c < CPT; c++) acc[r][c] = 0.f;

    for (int kc = 0; kc < FIN; kc += KC) {
        constexpr int SLOTS_PER_ROW = KC / 4;
        constexpr int XQ = TM * KC / (256 * 4);
        #pragma unroll
        for (int j = 0; j < XQ; j++) {
            int idx = tid + j * 256;
            int tr = idx / SLOTS_PER_ROW;
            int tk = (idx % SLOTS_PER_ROW) * 4;
            int grow = row0 + tr;
            float4 v = make_float4(0.f, 0.f, 0.f, 0.f);
            if (grow < N_NODES) v = *(const float4*)(x + (size_t)grow * FIN + kc + tk);
            xT[tk + 0][tr] = v.x; xT[tk + 1][tr] = v.y;
            xT[tk + 2][tr] = v.z; xT[tk + 3][tr] = v.w;
        }
        if constexpr (KC * FOUT >= 1024) {
            constexpr int WQ = KC * FOUT / (256 * 4);
            #pragma unroll
            for (int j = 0; j < WQ; j++) {
                int idx = tid + j * 256;
                int wk = idx / (FOUT / 4);
                int wc = (idx % (FOUT / 4)) * 4;
                *(float4*)&Wl[wk][wc] = *(const float4*)(W + (size_t)(kc + wk) * FOUT + wc);
            }
        } else {
            Wl[tid / FOUT][tid % FOUT] = W[(size_t)(kc + tid / FOUT) * FOUT + tid % FOUT];
        }
        __syncthreads();

        #pragma unroll
        for (int k = 0; k < KC; k++) {
            float a[RPT];
            #pragma unroll
            for (int rr = 0; rr < RPT; rr += 4) {
                float4 xv = *(const float4*)&xT[k][r0 + rr];
                a[rr] = xv.x; a[rr+1] = xv.y; a[rr+2] = xv.z; a[rr+3] = xv.w;
            }
            if constexpr (CPT == 4) {
                float4 wv = *(const float4*)&Wl[k][c0];
                #pragma unroll
                for (int rr = 0; rr < RPT; rr++) {
                    acc[rr][0] += a[rr] * wv.x; acc[rr][1] += a[rr] * wv.y;
                    acc[rr][2] += a[rr] * wv.z; acc[rr][3] += a[rr] * wv.w;
                }
            } else {
                float wv = Wl[k][c0];
                #pragma unroll
                for (int rr = 0; rr < RPT; rr++) acc[rr][0] += a[rr] * wv;
            }
        }
        __syncthreads();
    }

    #pragma unroll
    for (int rr = 0; rr < RPT; rr++) {
        int grow = row0 + r0 + rr;
        if (grow < N_NODES) {
            if constexpr (CPT == 4) {
                float4 o = make_float4(acc[rr][0], acc[rr][1], acc[rr][2], acc[rr][3]);
                *(float4*)(h + (size_t)grow * FOUT + c0) = o;
            } else {
                h[(size_t)grow * FOUT + c0] = acc[rr][0];
            }
        }
    }
}

// ------------- gather conv FOUT=128 (fp32 w); ReLU+bias fused -------------
__global__ void conv_gather128_kernel(const int* __restrict__ row_start,
                                      const int* __restrict__ src_csr,
                                      const float* __restrict__ w_csr,
                                      const float* __restrict__ dinv,
                                      const float* __restrict__ swd2,
                                      const float* __restrict__ h,
                                      const float* __restrict__ b,
                                      float* __restrict__ out) {
    constexpr int TPN = 32;
    int gid = blockIdx.x * blockDim.x + threadIdx.x;
    int node = gid / TPN;
    int t = gid % TPN;
    if (node >= N_NODES) return;
    int beg = row_start[node], end = row_start[node + 1];
    float dv = dinv[node];
    float4 acc = make_float4(0.f, 0.f, 0.f, 0.f);
    for (int base = beg; base < end; base += TPN) {
        int i = base + t;
        float wv = 0.f; int sv = 0;
        if (i < end) {
            wv = w_csr[i];
            sv = src_csr[i];
            if (wv != 0.f) wv *= dinv[sv];       // fold dinv[src]
        }
        int cnt = end - base; if (cnt > TPN) cnt = TPN;
        #pragma unroll
        for (int j = 0; j < TPN; j++) {
            if (j >= cnt) break;
            float w = __shfl(wv, j, TPN);
            int   s = __shfl(sv, j, TPN);
            if (w != 0.f) {
                float coeff = w * dv;
                float4 hv = *(const float4*)(h + (size_t)s * 128 + t * 4);
                acc.x += coeff * hv.x; acc.y += coeff * hv.y;
                acc.z += coeff * hv.z; acc.w += coeff * hv.w;
            }
        }
    }
    float sd = swd2[node];
    float4 hv = *(const float4*)(h + (size_t)node * 128 + t * 4);
    float4 bv = *(const float4*)(b + t * 4);
    acc.x = fmaxf(acc.x + sd * hv.x + bv.x, 0.f);
    acc.y = fmaxf(acc.y + sd * hv.y + bv.y, 0.f);
    acc.z = fmaxf(acc.z + sd * hv.z + bv.z, 0.f);
    acc.w = fmaxf(acc.w + sd * hv.w + bv.w, 0.f);
    *(float4*)(out + (size_t)node * 128 + t * 4) = acc;
}

// ------------- gather conv F=16 (fp32 w); optional bias/relu + normalized fp32 row out -------------
template<bool BIAS_RELU, bool WNORM>
__global__ void conv_gather16_kernel(const int* __restrict__ row_start,
                                     const int* __restrict__ src_csr,
                                     const float* __restrict__ w_csr,
                                     const float* __restrict__ dinv,
                                     const float* __restrict__ swd2,
                                     const float* __restrict__ h,
                                     const float* __restrict__ b,
                                     float* __restrict__ out,
                                     float* __restrict__ xn_out) {
    constexpr int TPN = 16;
    int gid = blockIdx.x * blockDim.x + threadIdx.x;
    int node = gid / TPN;
    int t = gid % TPN;
    if (node >= N_NODES) return;
    int beg = row_start[node], end = row_start[node + 1];
    float dv = dinv[node];
    float acc = 0.f;
    for (int base = beg; base < end; base += TPN) {
        int i = base + t;
        float wv = 0.f; int sv = 0;
        if (i < end) {
            wv = w_csr[i];
            sv = src_csr[i];
            if (wv != 0.f) wv *= dinv[sv];
        }
        int cnt = end - base; if (cnt > TPN) cnt = TPN;
        #pragma unroll
        for (int j = 0; j < TPN; j++) {
            if (j >= cnt) break;
            float w = __shfl(wv, j, TPN);
            int   s = __shfl(sv, j, TPN);
            if (w != 0.f) acc += (w * dv) * h[(size_t)s * 16 + t];
        }
    }
    float v = acc + swd2[node] * h[(size_t)node * 16 + t];
    if (BIAS_RELU) v = fmaxf(v + b[t], 0.f);
    out[(size_t)node * 16 + t] = v;
    if (WNORM) {
        float ss = v * v;
        #pragma unroll
        for (int m = TPN/2; m >= 1; m >>= 1) ss += __shfl_xor(ss, m);
        float n = sqrtf(ss);
        float ni = (n == 0.f) ? 1.f : 1.f / n;
        xn_out[(size_t)node * 16 + t] = v * ni;
    }
}

// ------------- fused: out40 = agg16 @ W3 + b3, then log_softmax. One wave/node. -------------
__global__ void final_kernel(const float* __restrict__ agg16,
                             const float* __restrict__ W3, const float* __restrict__ b3,
                             float* __restrict__ out) {
    __shared__ float Wl[16 * 40];
    __shared__ float bl[40];
    for (int i = threadIdx.x; i < 16 * 40; i += blockDim.x) Wl[i] = W3[i];
    if (threadIdx.x < 40) bl[threadIdx.x] = b3[threadIdx.x];
    __syncthreads();
    int wid = threadIdx.x / 64;
    int lane = threadIdx.x % 64;
    int v = blockIdx.x * 4 + wid;
    if (v >= N_NODES) return;
    const float* ar = agg16 + (size_t)v * 16;
    float o = -INFINITY;
    if (lane < 40) {
        o = bl[lane];
        #pragma unroll
        for (int k = 0; k < 16; k++) o += ar[k] * Wl[k * 40 + lane];
    }
    float m = o;
    #pragma unroll
    for (int s = 32; s >= 1; s >>= 1) m = fmaxf(m, __shfl_xor(m, s));
    float ex = (lane < 40) ? expf(o - m) : 0.f;
    float sum = ex;
    #pragma unroll
    for (int s = 32; s >= 1; s >>= 1) sum += __shfl_xor(sum, s);
    float lse = m + logf(sum);
    if (lane < 40) out[(size_t)v * 40 + lane] = o - lse;
}

// =================== host orchestration ===================
extern "C" void kernel_launch(void* const* d_in, const int* in_sizes, int n_in,
                              void* d_out, int out_size, void* d_ws, size_t ws_size,
                              hipStream_t stream) {
    const float* x0 = (const float*)d_in[0];
    const int* ei   = (const int*)d_in[1];
    const int* src  = ei;
    const int* dst  = ei + N_EDGES;
    const float* W1 = (const float*)d_in[2];
    const float* b1 = (const float*)d_in[3];
    const float* W2 = (const float*)d_in[4];
    const float* b2 = (const float*)d_in[5];
    const float* W3 = (const float*)d_in[6];
    const float* b3 = (const float*)d_in[7];
    float* out = (float*)d_out;

    // workspace ~73 MB. Aliases (disjoint lifetimes):
    //   tmp_s/tmp_d alias xbuf1[0..3.2M) (dead before conv128 writes xbuf1)
    //   xq2 (int8 table, 1.6M slots) / agg16 / xn2 / xbuf2 alias inside h
    float* ws     = (float*)d_ws;
    float* xbuf1  = ws;                        // 6,400,000
    unsigned* tmp_s = (unsigned*)xbuf1;        // alias: 1.6M
    unsigned* tmp_d = (unsigned*)xbuf1 + N_EDGES; // alias: 1.6M
    float* h      = xbuf1 + 6400000;           // 6,400,000
    uint2* xq2    = (uint2*)h;                 // alias: h[0..1.6M slots) as int8 rows
    float* agg16  = h;                         // alias
    float* xn2    = h + 800000;                // alias
    float* xbuf2  = h + 1600000;               // alias
    float* w_csr  = h + 6400000;               // 1,600,000 (fp32)
    float* nrminv = w_csr + 1600000;           // 50,000
    float* dinv   = nrminv + 50000;            // 50,000
    float* swd2   = dinv + 50000;              // 50,000
    float* rowsum2 = swd2 + 50000;             // 50,000 (layer 2, fully written)
    float* selfw2  = rowsum2 + 50000;          // 50,000
    int* zr        = (int*)(selfw2 + 50000);   // zero region
    float* rs0     = (float*)zr;               // 50,000
    float* dc0     = rs0 + 50000;
    float* rs1     = dc0 + 50000;
    float* dc1     = rs1 + 50000;
    int* bcnt_s    = (int*)(dc1 + 50000);      // 256
    int* bcnt_d    = bcnt_s + 256;             // 256  (end of zero region)
    int* bbase_s   = bcnt_d + 256;             // 257
    int* bbase_d   = bbase_s + 257;            // 257
    int* bcur_s    = bbase_d + 257;            // 256
    int* bcur_d    = bcur_s + 256;             // 256
    int* row_start_d = bcur_d + 256;           // 50,001
    int* row_start_s = row_start_d + 50001;    // 50,001
    int* src_csr   = row_start_s + 50001;      // 1,600,000 (by-dst payload = src)
    int* dstp_csr  = src_csr + N_EDGES;        // 1,600,000 (by-src payload = dst)

    const int BS = 256;

    // ---- one memset zeroes rowsum/degcnt pairs (L0,L1) + bucket counters ----
    hipMemsetAsync(zr, 0, (200000 + 512) * sizeof(int), stream);

    // ---- CSR build, both directions ----
    bucket_count_kernel<<<(N_EDGES + 8191) / 8192, BS, 0, stream>>>(src, dst, bcnt_s, bcnt_d);
    bucket_scan_kernel<<<1, BS, 0, stream>>>(bcnt_s, bcnt_d, bbase_s, bbase_d,
                                             bcur_s, bcur_d, row_start_s, row_start_d);
    partition2_kernel<<<(N_EDGES + 8191) / 8192, BS, 0, stream>>>(src, dst, bcur_s, bcur_d,
                                                                  tmp_s, tmp_d);
    csr_finalize_kernel<<<NBUCK, BS, 0, stream>>>(tmp_d, bbase_d, row_start_d, src_csr);
    csr_finalize_kernel<<<NBUCK, BS, 0, stream>>>(tmp_s, bbase_s, row_start_s, dstp_csr);

    // ================= Layer 0: 128 -> 128, ReLU =================
    norm_pack_kernel<<<(N_NODES * 16 + BS - 1) / BS, BS, 0, stream>>>(x0, nrminv, xq2);
    sim128_kernel<<<(N_NODES * 16 + BS - 1) / BS, BS, 0, stream>>>(
        x0, nrminv, xq2, row_start_d, src_csr, w_csr, rs0, dc0);
    row_finalize_kernel<<<(N_NODES * 16 + BS - 1) / BS, BS, 0, stream>>>(
        row_start_d, src_csr, rs0, dc0, w_csr, dinv, swd2);
    gemm_tiled<128, 128, 64, 16, 8, 4><<<(N_NODES + 63) / 64, BS, 0, stream>>>(x0, W1, h);
    conv_gather128_kernel<<<(N_NODES * 32 + BS - 1) / BS, BS, 0, stream>>>(
        row_start_d, src_csr, w_csr, dinv, swd2, h, b1, xbuf1);

    // ================= Layer 1: 128 -> 16, ReLU =================
    norm_pack_kernel<<<(N_NODES * 16 + BS - 1) / BS, BS, 0, stream>>>(xbuf1, nrminv, xq2);
    sim128_kernel<<<(N_NODES * 16 + BS - 1) / BS, BS, 0, stream>>>(
        xbuf1, nrminv, xq2, row_start_d, src_csr, w_csr, rs1, dc1);
    row_finalize_kernel<<<(N_NODES * 16 + BS - 1) / BS, BS, 0, stream>>>(
        row_start_d, src_csr, rs1, dc1, w_csr, dinv, swd2);
    gemm_tiled<128, 16, 128, 16, 8, 1><<<(N_NODES + 127) / 128, BS, 0, stream>>>(xbuf1, W2, h);
    conv_gather16_kernel<true, true><<<(N_NODES * 16 + BS - 1) / BS, BS, 0, stream>>>(
        row_start_d, src_csr, w_csr, dinv, swd2, h, b2, xbuf2, xn2);

    // ========== Layer 2: 16 -> 40 (atomic-free two-pass sim, aggregate, fused GEMM+LSM) ====
    simA_kernel<<<(N_NODES * 16 + BS - 1) / BS, BS, 0, stream>>>(
        xn2, row_start_s, dstp_csr, rowsum2, selfw2);
    simB_kernel<<<(N_NODES * 16 + BS - 1) / BS, BS, 0, stream>>>(
        xn2, row_start_d, src_csr, rowsum2, selfw2, w_csr, dinv, swd2);
    conv_gather16_kernel<false, false><<<(N_NODES * 16 + BS - 1) / BS, BS, 0, stream>>>(
        row_start_d, src_csr, w_csr, dinv, swd2, xbuf2, b3 /*unused*/, agg16, nullptr);
    final_kernel<<<(N_NODES + 3) / 4, BS, 0, stream>>>(agg16, W3, b3, out);
}